// Round 10
// baseline (575.676 us; speedup 1.0000x reference)
//
#include <hip/hip_runtime.h>
#include <math.h>

#define NB 16
#define DIMD 256
#define NHH 8
#define NLAT 64
#define EMAXC 13568
#define NCH2 14            /* chunks of 1024 events (last partial) */
#define EPAD (NCH2*1024)   /* 14336: padded event stride (bytes for fp8 PT/VT) */

typedef float f32x4 __attribute__((ext_vector_type(4)));
typedef __bf16 bf16x8 __attribute__((ext_vector_type(8)));
typedef _Float16 f16t;
typedef __attribute__((ext_vector_type(8))) _Float16 f16x8;
typedef unsigned short u16;
typedef unsigned char u8;
typedef unsigned int u32;
typedef __attribute__((ext_vector_type(4))) unsigned int u32x4;
typedef __attribute__((ext_vector_type(8))) unsigned short u16x8;

/* f16 transposed-weight pool offsets (elements), layout [N][K] */
#define WTO_WOC   0u
#define WTO_W1C   65536u
#define WTO_W2C   327680u
#define WTO_QKV0  589824u
#define WTO_WOS0  786432u
#define WTO_W1S0  851968u
#define WTO_W2S0  1114112u
#define WTO_QKV1  1376256u
#define WTO_WOS1  1572864u
#define WTO_W1S1  1638400u
#define WTO_W2S1  1900544u
#define WTO_BH    2162688u
#define WT_TOTAL  2293760u

static __device__ __forceinline__ float wave_sum(float v){
#pragma unroll
  for (int off = 32; off > 0; off >>= 1) v += __shfl_xor(v, off, 64);
  return v;
}

static __device__ __forceinline__ u16 f2bf(float x){
  unsigned u = __float_as_uint(x);
  u += 0x7fffu + ((u >> 16) & 1u);
  return (u16)(u >> 16);
}

static __device__ __forceinline__ float gelu_tanh(float x){
  float x3 = x*x*x;
  return 0.5f*x*(1.0f + tanhf(0.7978845608028654f*(x + 0.044715f*x3)));
}

static __device__ __forceinline__ float dot4(float4 a, float4 b){
  return a.x*b.x + a.y*b.y + a.z*b.z + a.w*b.w;
}

// Async global->LDS DMA, 16B per lane. LDS dest is wave-uniform base + lane*16.
static __device__ __forceinline__ void gl_lds16(const void* g, void* l){
  __builtin_amdgcn_global_load_lds((const __attribute__((address_space(1))) void*)g,
                                   (__attribute__((address_space(3))) void*)l,
                                   16, 0, 0);
}

__global__ void k_zero(int* cnt){ if ((int)threadIdx.x < NB) cnt[threadIdx.x] = 0; }

// LDS-histogram bucket sort: 16 global atomics per 1024-event block.
__global__ void k_sort(const int* __restrict__ bidx, int* __restrict__ cnt,
                       int* __restrict__ sorted, int E){
  __shared__ int h[NB], base[NB];
  int t = threadIdx.x;
  if (t < NB) h[t] = 0;
  __syncthreads();
  int e0 = blockIdx.x*1024;
  int myb[4], myp[4];
#pragma unroll
  for (int i = 0; i < 4; i++){
    int e = e0 + i*256 + t;
    myb[i] = -1;
    if (e < E){ myb[i] = bidx[e]; myp[i] = atomicAdd(&h[myb[i]], 1); }
  }
  __syncthreads();
  if (t < NB) base[t] = atomicAdd(&cnt[t], h[t]);
  __syncthreads();
#pragma unroll
  for (int i = 0; i < 4; i++){
    if (myb[i] >= 0){
      int p = base[myb[i]] + myp[i];
      if (p < EMAXC) sorted[myb[i]*EMAXC + p] = e0 + i*256 + t;
    }
  }
}

// LayerNorm over rows of 256 (used only for lat_init prep).
__global__ void k_ln(const float* __restrict__ X, float* __restrict__ Y, int rows){
  int wave = threadIdx.x >> 6, lane = threadIdx.x & 63;
  int row = blockIdx.x*4 + wave;
  if (row >= rows) return;
  float4 x = ((const float4*)(X + (size_t)row*DIMD))[lane];
  float s = wave_sum(x.x + x.y + x.z + x.w);
  float m = s * (1.0f/DIMD);
  float d0 = x.x-m, d1 = x.y-m, d2 = x.z-m, d3 = x.w-m;
  float v = wave_sum(d0*d0 + d1*d1 + d2*d2 + d3*d3) * (1.0f/DIMD);
  float rs = rsqrtf(v + 1e-5f);
  ((float4*)(Y + (size_t)row*DIMD))[lane] = make_float4(d0*rs, d1*rs, d2*rs, d3*rs);
}

// lat[row] = lat_init[row % 64]  (row-broadcast residual init)
__global__ void k_init(const float* __restrict__ lat_i, float* __restrict__ lat){
  int r = blockIdx.x, t = threadIdx.x;
  lat[(size_t)r*DIMD + t] = lat_i[(size_t)(r & 63)*DIMD + t];
}

// Small prep GEMM (tiny M): C[M,N] = A[M,K] @ W[K,N]
__global__ __launch_bounds__(256) void k_gemm(
    const float* __restrict__ A, const float* __restrict__ W,
    float* __restrict__ C, int M, int K, int N){
  __shared__ float As[8][1024];
  int t = threadIdx.x;
  int row0 = blockIdx.x*8;
  int col = blockIdx.y*256 + t;
  int kq = K >> 2;
  for (int idx = t; idx < 8*kq; idx += 256){
    int r = idx / kq, kc = idx % kq;
    float4 v = make_float4(0.f,0.f,0.f,0.f);
    if (row0 + r < M) v = ((const float4*)(A + (size_t)(row0+r)*K))[kc];
    ((float4*)&As[r][0])[kc] = v;
  }
  __syncthreads();
  float acc[8] = {0,0,0,0,0,0,0,0};
  for (int k = 0; k < K; k += 4){
    float w0 = W[(size_t)(k+0)*N + col];
    float w1 = W[(size_t)(k+1)*N + col];
    float w2 = W[(size_t)(k+2)*N + col];
    float w3 = W[(size_t)(k+3)*N + col];
#pragma unroll
    for (int r = 0; r < 8; r++){
      float4 a = *((const float4*)&As[r][k]);
      acc[r] += a.x*w0 + a.y*w1 + a.z*w2 + a.w*w3;
    }
  }
#pragma unroll
  for (int r = 0; r < 8; r++){
    int row = row0 + r;
    if (row < M) C[(size_t)row*N + col] = acc[r];
  }
}

// Transpose all latent-chain weights to f16 [N][K] pool (runs once per launch).
// 64x64 LDS-tile transpose; grid (64, 12); out-of-range tiles return.
__global__ __launch_bounds__(256) void k_wt(
    const float* __restrict__ Wo_c, const float* __restrict__ W1_c,
    const float* __restrict__ W2_c, const float* __restrict__ Wqkv_s,
    const float* __restrict__ Wo_s, const float* __restrict__ W1_s,
    const float* __restrict__ W2_s, const float* __restrict__ bh_wkv,
    f16t* __restrict__ WT){
  const int mid = blockIdx.y;
  const float* src; int K, N; unsigned off;
  switch (mid){
    case 0:  src = Wo_c;            K = 256;  N = 256;  off = WTO_WOC;  break;
    case 1:  src = W1_c;            K = 256;  N = 1024; off = WTO_W1C;  break;
    case 2:  src = W2_c;            K = 1024; N = 256;  off = WTO_W2C;  break;
    case 3:  src = Wqkv_s;          K = 256;  N = 768;  off = WTO_QKV0; break;
    case 4:  src = Wo_s;            K = 256;  N = 256;  off = WTO_WOS0; break;
    case 5:  src = W1_s;            K = 256;  N = 1024; off = WTO_W1S0; break;
    case 6:  src = W2_s;            K = 1024; N = 256;  off = WTO_W2S0; break;
    case 7:  src = Wqkv_s + 196608; K = 256;  N = 768;  off = WTO_QKV1; break;
    case 8:  src = Wo_s + 65536;    K = 256;  N = 256;  off = WTO_WOS1; break;
    case 9:  src = W1_s + 262144;   K = 256;  N = 1024; off = WTO_W1S1; break;
    case 10: src = W2_s + 262144;   K = 1024; N = 256;  off = WTO_W2S1; break;
    default: src = bh_wkv;          K = 256;  N = 512;  off = WTO_BH;   break;
  }
  const int ntiles = N >> 6;
  const int tiles = ntiles * (K >> 6);
  if ((int)blockIdx.x >= tiles) return;
  const int kt = blockIdx.x / ntiles, nt = blockIdx.x % ntiles;
  __shared__ float tile[64][65];
  const int t = threadIdx.x;
  const int k0 = kt*64, n0 = nt*64;
#pragma unroll
  for (int i = 0; i < 16; i++){
    int k = i*4 + (t >> 6);
    tile[k][t & 63] = src[(size_t)(k0 + k)*N + n0 + (t & 63)];
  }
  __syncthreads();
  const int n = t >> 2, ks = (t & 3)*16;
  f16t* d = WT + off + (size_t)(n0 + n)*K + k0 + ks;
#pragma unroll
  for (int j = 0; j < 16; j++) d[j] = (f16t)tile[ks + j][n];
}

// MFMA latent-chain GEMM: C[M,N] (+)= A[M,K] @ W, W given as f16 WT[N][K].
// 64x64 tile, BK=64 (halved barrier count vs BK=32), 4 waves; wave w owns rows
// [16w,16w+16). A staged f32->f16 via LDS pitch-72 (write-granule-uniform,
// 2-way reads); B via global_load_lds with 8-chunk XOR swizzle kc=c'^(r&7)
// (involution: inverse on source, forward on read; 2-way = free).
// modes: 0 plain / 1 gelu / 2 atomicAdd; K split over gridDim.z.
// do_ln (K==256, S==1): LayerNorm rows of A, optional affine lnw/lnb.
__global__ __launch_bounds__(256) void k_gemm3(
    const float* __restrict__ A, const f16t* __restrict__ WT, float* __restrict__ C,
    const float* __restrict__ lnw, const float* __restrict__ lnb,
    int M, int K, int N, int mode, int do_ln){
  __shared__ f16t Xs[64][72];
  __shared__ f16t Ws[64][64];
  __shared__ float lnm[64], lnr[64];
  const int t = threadIdx.x;
  const int wv = t >> 6, lane = t & 63;
  const int quad = lane >> 4, lane15 = lane & 15;
  const int m0 = blockIdx.x*64, n0 = blockIdx.y*64;
  const int Kc = K / gridDim.z;
  const int k0b = blockIdx.z*Kc;

  f32x4 acc[4];
#pragma unroll
  for (int j = 0; j < 4; j++) acc[j] = (f32x4){0.f,0.f,0.f,0.f};

  if (do_ln){
    int r = t >> 2, seg = (t & 3)*64;
    const float* Ar = A + (size_t)(m0 + r)*K + seg;
    float s = 0.f, s2 = 0.f;
#pragma unroll
    for (int j = 0; j < 64; j += 4){
      float4 v = *(const float4*)(Ar + j);
      s  += v.x + v.y + v.z + v.w;
      s2 += v.x*v.x + v.y*v.y + v.z*v.z + v.w*v.w;
    }
    s += __shfl_xor(s, 1, 64); s2 += __shfl_xor(s2, 1, 64);
    s += __shfl_xor(s, 2, 64); s2 += __shfl_xor(s2, 2, 64);
    if ((t & 3) == 0){
      float m = s*(1.0f/256.0f);
      float var = s2*(1.0f/256.0f) - m*m;
      lnm[r] = m; lnr[r] = rsqrtf(var + 1e-5f);
    }
    __syncthreads();
  }

  const int ar = t >> 2;                        // A stage row (0..63)
  const int as16 = (t & 3)*16;                  // A stage k-offset (16 f16)
  const int wr = t >> 3;                        // B slot row base (p=0)
  f16t* wdst0 = &Ws[0][0] + (size_t)(wv*64)*8;          // p=0 wave base
  f16t* wdst1 = &Ws[0][0] + (size_t)(256 + wv*64)*8;    // p=1 wave base
  (void)wr;

  for (int k0 = k0b; k0 < k0b + Kc; k0 += 64){
    __syncthreads();                  // prior frag reads done; buffers free
#pragma unroll
    for (int p = 0; p < 2; p++){
      int li = p*256 + t;
      int r = li >> 3;
      int kc = (li & 7) ^ (r & 7);
      gl_lds16(WT + (size_t)(n0 + r)*K + k0 + kc*8, p ? wdst1 : wdst0);
    }
    const float* Arow = A + (size_t)(m0 + ar)*K + k0 + as16;
    float4 v0 = *(const float4*)(Arow + 0);
    float4 v1 = *(const float4*)(Arow + 4);
    float4 v2 = *(const float4*)(Arow + 8);
    float4 v3 = *(const float4*)(Arow + 12);
    if (do_ln){
      float mm = lnm[ar], rs = lnr[ar];
      v0.x=(v0.x-mm)*rs; v0.y=(v0.y-mm)*rs; v0.z=(v0.z-mm)*rs; v0.w=(v0.w-mm)*rs;
      v1.x=(v1.x-mm)*rs; v1.y=(v1.y-mm)*rs; v1.z=(v1.z-mm)*rs; v1.w=(v1.w-mm)*rs;
      v2.x=(v2.x-mm)*rs; v2.y=(v2.y-mm)*rs; v2.z=(v2.z-mm)*rs; v2.w=(v2.w-mm)*rs;
      v3.x=(v3.x-mm)*rs; v3.y=(v3.y-mm)*rs; v3.z=(v3.z-mm)*rs; v3.w=(v3.w-mm)*rs;
      if (lnw){
        int k = k0 + as16;
        v0.x=v0.x*lnw[k+0]+lnb[k+0];  v0.y=v0.y*lnw[k+1]+lnb[k+1];
        v0.z=v0.z*lnw[k+2]+lnb[k+2];  v0.w=v0.w*lnw[k+3]+lnb[k+3];
        v1.x=v1.x*lnw[k+4]+lnb[k+4];  v1.y=v1.y*lnw[k+5]+lnb[k+5];
        v1.z=v1.z*lnw[k+6]+lnb[k+6];  v1.w=v1.w*lnw[k+7]+lnb[k+7];
        v2.x=v2.x*lnw[k+8]+lnb[k+8];  v2.y=v2.y*lnw[k+9]+lnb[k+9];
        v2.z=v2.z*lnw[k+10]+lnb[k+10]; v2.w=v2.w*lnw[k+11]+lnb[k+11];
        v3.x=v3.x*lnw[k+12]+lnb[k+12]; v3.y=v3.y*lnw[k+13]+lnb[k+13];
        v3.z=v3.z*lnw[k+14]+lnb[k+14]; v3.w=v3.w*lnw[k+15]+lnb[k+15];
      }
    }
    f16x8 h0 = {(f16t)v0.x,(f16t)v0.y,(f16t)v0.z,(f16t)v0.w,
                (f16t)v1.x,(f16t)v1.y,(f16t)v1.z,(f16t)v1.w};
    f16x8 h1 = {(f16t)v2.x,(f16t)v2.y,(f16t)v2.z,(f16t)v2.w,
                (f16t)v3.x,(f16t)v3.y,(f16t)v3.z,(f16t)v3.w};
    *(f16x8*)&Xs[ar][as16]     = h0;
    *(f16x8*)&Xs[ar][as16 + 8] = h1;
    __syncthreads();                  // drains vmcnt (DMA) + lgkm (ds_write)
#pragma unroll
    for (int ks = 0; ks < 2; ks++){
      f16x8 a = *(const f16x8*)&Xs[wv*16 + lane15][ks*32 + quad*8];
#pragma unroll
      for (int nt = 0; nt < 4; nt++){
        int ch = (ks*4 + quad) ^ (lane15 & 7);
        f16x8 bw = *(const f16x8*)&Ws[nt*16 + lane15][ch*8];
        acc[nt] = __builtin_amdgcn_mfma_f32_16x16x32_f16(a, bw, acc[nt], 0, 0, 0);
      }
    }
  }
#pragma unroll
  for (int nt = 0; nt < 4; nt++){
    int col = n0 + nt*16 + lane15;
#pragma unroll
    for (int j = 0; j < 4; j++){
      int row = m0 + wv*16 + quad*4 + j;
      float v = acc[nt][j];
      if (mode == 1) v = gelu_tanh(v);
      float* cp = C + (size_t)row*N + col;
      if (mode == 2) atomicAdd(cp, v);
      else *cp = v;
    }
  }
}

// Build Wt[768][256] bf16 (transposed, column-reordered)
__global__ void k_qw(const float* __restrict__ Wkv, const float* __restrict__ qc,
                     u16* __restrict__ Wt){
  int n = blockIdx.x;
  int k = threadIdx.x;
  float v;
  if (n < 256){
    v = Wkv[(size_t)k*512 + 256 + n];
  } else {
    int h = (n - 256) >> 6, l = (n - 256) & 63;
    const float* wk = Wkv + (size_t)k*512 + h*32;
    const float* qr = qc + (size_t)l*256 + h*32;
    float s = 0.f;
#pragma unroll
    for (int dd = 0; dd < 32; dd++) s += wk[dd]*qr[dd];
    v = s*0.1767766952966369f;
  }
  Wt[(size_t)n*256 + k] = f2bf(v);
}

// Gather+LN -> XLN bf16 (group-local), zero pad rows. One wave per event row.
__global__ void k_a0(const int* __restrict__ sorted, const int* __restrict__ cnt,
                     const int* __restrict__ nid, const int* __restrict__ tbin,
                     const int* __restrict__ vval,
                     const float* __restrict__ ne, const float* __restrict__ te,
                     const float* __restrict__ ve, u16* __restrict__ XLN, int b0){
  int wv = threadIdx.x >> 6, lane = threadIdx.x & 63;
  int e = blockIdx.x*4 + wv;
  int bg = blockIdx.y, b = b0 + bg;
  int cn = min(cnt[b], EMAXC);
  ushort4 pk; pk.x = 0; pk.y = 0; pk.z = 0; pk.w = 0;
  if (e < cn){
    int ev = sorted[b*EMAXC + e];
    float4 aa = ((const float4*)(ne + (size_t)nid[ev]*DIMD))[lane];
    float4 bb = ((const float4*)(te + (size_t)tbin[ev]*DIMD))[lane];
    float4 cc = ((const float4*)(ve + (size_t)vval[ev]*DIMD))[lane];
    float x0 = aa.x+bb.x+cc.x, x1 = aa.y+bb.y+cc.y;
    float x2 = aa.z+bb.z+cc.z, x3 = aa.w+bb.w+cc.w;
    float s = wave_sum(x0 + x1 + x2 + x3);
    float m = s*(1.0f/DIMD);
    x0 -= m; x1 -= m; x2 -= m; x3 -= m;
    float v = wave_sum(x0*x0 + x1*x1 + x2*x2 + x3*x3)*(1.0f/DIMD);
    float rs = rsqrtf(v + 1e-5f);
    pk.x = f2bf(x0*rs); pk.y = f2bf(x1*rs); pk.z = f2bf(x2*rs); pk.w = f2bf(x3*rs);
  }
  *(ushort4*)(XLN + ((size_t)bg*EMAXC + e)*DIMD + lane*4) = pk;
}

// Dense MFMA GEMM: [PT|VT] (transposed, fp8 e4m3) = exp?(XLN @ Wt^T).
// 256x128 tile (BM doubled r9: barrier/drain overhead per K-step is constant,
// so per-FLOP overhead halves), BK=32, 512 thr / 8 waves, THREE-buffer
// global_load_lds pipeline with counted vmcnt (T3/T4). Two raw s_barriers per
// step. Chunk XOR-swizzle (r4-verified). Same K-accumulation order as r5-r8
// -> bitwise-identical output. LDS 72KB -> 2 blocks/CU (16 waves/CU).
// grid (6, 53, gb).
__global__ __launch_bounds__(512) void k_a(
    const u16* __restrict__ XLN, const u16* __restrict__ Wt,
    const int* __restrict__ cnt, u8* __restrict__ PT, u8* __restrict__ VT, int b0)
{
  __shared__ union ShMem {
    struct { u16 Xs[3][256][32]; u16 Ws[3][128][32]; } s;
    u8 Tr[128][272];
  } sh;
  const int t = threadIdx.x;
  const int wv = t >> 6, lane = t & 63;
  const int quad = lane >> 4, lane15 = lane & 15;
  const int nidx = blockIdx.x;         // 0..5
  const int rtile = blockIdx.y;        // 0..52
  const int bg = blockIdx.z;
  const int b = b0 + bg;
  const int cn = min(cnt[b], EMAXC);
  const int row0 = rtile * 256;
  if (row0 >= cn) return;
  const int n0 = nidx * 128;
  const int eh = (wv >> 1) * 64, nh = (wv & 1) * 64;

  f32x4 acc[4][4];
#pragma unroll
  for (int i = 0; i < 4; i++)
#pragma unroll
    for (int j = 0; j < 4; j++) acc[i][j] = (f32x4){0.f,0.f,0.f,0.f};

  const u16* Xbase = XLN + ((size_t)bg*EMAXC + row0)*DIMD;
  const u16* Wbase = Wt + (size_t)n0*256;

  // X: 1024 16B-slots (2/thread), W: 512 slots (1/thread); linear LDS dest,
  // inverse chunk-swizzle on the global source.
  auto stage = [&](int buf, int k0){
#pragma unroll
    for (int p = 0; p < 2; p++){
      int li = p*512 + t;
      int r = li >> 2;
      int kc = (li & 3) ^ ((r >> 1) & 3);
      u16* xd = &sh.s.Xs[buf][0][0] + (size_t)(p*512 + wv*64)*8;
      gl_lds16(Xbase + (size_t)r*DIMD + k0 + kc*8, xd);
    }
    {
      int r = t >> 2;
      int kc = (t & 3) ^ ((r >> 1) & 3);
      u16* wd = &sh.s.Ws[buf][0][0] + (size_t)(wv*64)*8;
      gl_lds16(Wbase + (size_t)r*256 + k0 + kc*8, wd);
    }
  };
  const int cswz = quad ^ ((lane15 >> 1) & 3);   // read-side chunk swizzle
  auto compute = [&](int buf){
    bf16x8 a[4], bw[4];
#pragma unroll
    for (int mt = 0; mt < 4; mt++)
      a[mt] = *(const bf16x8*)&sh.s.Xs[buf][eh + mt*16 + lane15][cswz*8];
#pragma unroll
    for (int nt = 0; nt < 4; nt++)
      bw[nt] = *(const bf16x8*)&sh.s.Ws[buf][nh + nt*16 + lane15][cswz*8];
#pragma unroll
    for (int mt = 0; mt < 4; mt++)
#pragma unroll
      for (int nt = 0; nt < 4; nt++)
        acc[mt][nt] = __builtin_amdgcn_mfma_f32_16x16x32_bf16(a[mt], bw[nt], acc[mt][nt], 0, 0, 0);
  };

  stage(0, 0);
  stage(1, 32);
#pragma unroll
  for (int it = 0; it < 8; it++){
    __builtin_amdgcn_s_barrier();              // A: compute(it-1) done; buf (it+2)%3 free
    if (it + 2 < 8) stage((it + 2) % 3, (it + 2)*32);
    if (it <= 5)      asm volatile("s_waitcnt vmcnt(6)" ::: "memory");
    else if (it == 6) asm volatile("s_waitcnt vmcnt(3)" ::: "memory");
    else              asm volatile("s_waitcnt vmcnt(0)" ::: "memory");
    __builtin_amdgcn_s_barrier();              // B: everyone's stage(it) landed
    __builtin_amdgcn_sched_barrier(0);
    compute(it % 3);
  }
  const int is_p = (n0 >= 256);
  __syncthreads();   // buffers dead from here; Tr takes over the storage
#pragma unroll
  for (int mt = 0; mt < 4; mt++){
    int e0 = eh + mt*16 + quad*4;              // 0..255
#pragma unroll
    for (int nt = 0; nt < 4; nt++){
      int c = nh + nt*16 + lane15;             // 0..127
      f32x4 v = acc[mt][nt];
      if (is_p){ v.x = __expf(v.x); v.y = __expf(v.y); v.z = __expf(v.z); v.w = __expf(v.w); }
      int p01 = __builtin_amdgcn_cvt_pk_fp8_f32(v.x, v.y, 0, false);
      int p23 = __builtin_amdgcn_cvt_pk_fp8_f32(v.z, v.w, 0, false);
      unsigned pk = ((unsigned)p01 & 0xFFFFu) | ((unsigned)p23 << 16);
      *(unsigned*)&sh.Tr[c][e0] = pk;
    }
  }
  __syncthreads();
  u8* dst = is_p ? (PT + ((size_t)bg*512 + (n0 - 256))*EPAD)
                 : (VT + ((size_t)bg*256 + n0)*EPAD);
  const int c = t >> 2;                        // 0..127
  const int e64 = (t & 3)*64;
#pragma unroll
  for (int i = 0; i < 4; i++){
    u32x4 val = *(const u32x4*)&sh.Tr[c][e64 + i*16];
    *(u32x4*)(dst + (size_t)c*EPAD + row0 + e64 + i*16) = val;
  }
}

// PV reduction (fp8 MFMA): O^T[dh][l] = sum_e V[dh][e]*P[l][e]; den via ones-MFMA.
// grid (NCH2, 8, gb), 256 thr; each wave owns a 256-event K-slice.
// No main-loop barriers: waves run phase-independent -> s_setprio(1) around the
// MFMA cluster (T5 regime per m191 attn; null only on barrier-lockstep GEMMs).
__global__ __launch_bounds__(256) void k_b(
    const u8* __restrict__ PT, const u8* __restrict__ VT,
    const int* __restrict__ cnt, float* __restrict__ pnum, float* __restrict__ pden, int b0)
{
  __shared__ float red[4][2048];
  __shared__ float redd[4][64];
  const int t = threadIdx.x;
  const int wv = t >> 6, lane = t & 63;
  const int quad = lane >> 4, lane15 = lane & 15;
  const int chunk = blockIdx.x, h = blockIdx.y, bg = blockIdx.z;
  const int b = b0 + bg;
  const int cn = min(cnt[b], EMAXC);
  const u8* PTg = PT + ((size_t)bg*512 + h*64)*EPAD;
  const u8* VTg = VT + ((size_t)bg*256 + h*32)*EPAD;

  f32x4 acc[3][4];
#pragma unroll
  for (int i = 0; i < 3; i++)
#pragma unroll
    for (int j = 0; j < 4; j++) acc[i][j] = (f32x4){0.f,0.f,0.f,0.f};

  const long ones = 0x3838383838383838L;

  const int e0w = chunk*1024 + wv*256;
#pragma unroll 2
  for (int ks = 0; ks < 8; ks++){
    int eb = e0w + ks*32 + quad*8;
    long a0 = *(const long*)(VTg + (size_t)(lane15     )*EPAD + eb);
    long a1 = *(const long*)(VTg + (size_t)(16 + lane15)*EPAD + eb);
    long bp[4];
#pragma unroll
    for (int nt = 0; nt < 4; nt++){
      union { long v; u8 c[8]; } m;
      m.v = *(const long*)(PTg + (size_t)(nt*16 + lane15)*EPAD + eb);
      if (eb + 8 > cn){
#pragma unroll
        for (int j = 0; j < 8; j++) if (eb + j >= cn) m.c[j] = 0;
      }
      bp[nt] = m.v;
    }
    __builtin_amdgcn_s_setprio(1);
#pragma unroll
    for (int nt = 0; nt < 4; nt++){
      acc[0][nt] = __builtin_amdgcn_mfma_f32_16x16x32_fp8_fp8(a0, bp[nt], acc[0][nt], 0, 0, 0);
      acc[1][nt] = __builtin_amdgcn_mfma_f32_16x16x32_fp8_fp8(a1, bp[nt], acc[1][nt], 0, 0, 0);
      acc[2][nt] = __builtin_amdgcn_mfma_f32_16x16x32_fp8_fp8(ones, bp[nt], acc[2][nt], 0, 0, 0);
    }
    __builtin_amdgcn_s_setprio(0);
  }
#pragma unroll
  for (int mt = 0; mt < 2; mt++)
#pragma unroll
    for (int nt = 0; nt < 4; nt++){
      int l = nt*16 + lane15;
#pragma unroll
      for (int j = 0; j < 4; j++)
        red[wv][l*32 + mt*16 + quad*4 + j] = acc[mt][nt][j];
    }
  if (quad == 0){
#pragma unroll
    for (int nt = 0; nt < 4; nt++) redd[wv][nt*16 + lane15] = acc[2][nt][0];
  }
  __syncthreads();
  size_t obase = ((size_t)(b*NHH + h)*NCH2 + chunk);
  for (int i = t; i < 2048; i += 256)
    pnum[obase*2048 + i] = red[0][i] + red[1][i] + red[2][i] + red[3][i];
  if (t < 64)
    pden[obase*64 + t] = redd[0][t] + redd[1][t] + redd[2][t] + redd[3][t];
}

// Reduce partials over chunks, divide, write OC[b][l][h*32+dh]
__global__ void k_red(const float* __restrict__ pnum, const float* __restrict__ pden,
                      float* __restrict__ OC){
  int g = blockIdx.x*256 + threadIdx.x;
  int b = g >> 14, r = g & 16383;
  int h = r >> 11, idx = r & 2047;
  int l = idx >> 5, dh = idx & 31;
  float ns = 0.f, ds = 0.f;
  for (int c = 0; c < NCH2; c++){
    size_t ob = ((size_t)(b*NHH + h)*NCH2 + c);
    ns += pnum[ob*2048 + idx];
    ds += pden[ob*64 + l];
  }
  OC[((size_t)(b*NLAT + l))*DIMD + h*32 + dh] = ns/ds;
}

// Self-attention over 64 latents. grid (NB, NHH, 2): z halves the Q rows so
// 256 blocks cover all CUs. float4 loads; S via register-blocked dot4 with
// broadcast LDS reads; wave-parallel softmax (8 lanes/row, shfl_xor 1/2/4);
// PV float4 over V rows.
__global__ __launch_bounds__(256) void k_attn(const float* __restrict__ qkv,
                                              float* __restrict__ outp){
  int b = blockIdx.x, h = blockIdx.y;
  int r0 = blockIdx.z*32;
  __shared__ float qs[32][33], ks[64][33], vs[64][33];
  __shared__ float S[32][65];
  int t = threadIdx.x;
  {
    int l = t >> 3, d4 = (t & 7)*4;     // qs: 32 rows x 8 float4
    const float* qp = qkv + ((size_t)(b*NLAT + r0 + l))*768 + h*32 + d4;
    *(float4*)&qs[l][d4] = *(const float4*)qp;
  }
#pragma unroll
  for (int i = 0; i < 2; i++){
    int idx = i*256 + t;
    int l = idx >> 3, d4 = (idx & 7)*4; // ks/vs: 64 rows x 8 float4
    const float* kp = qkv + ((size_t)(b*NLAT + l))*768 + h*32 + 256 + d4;
    *(float4*)&ks[l][d4] = *(const float4*)kp;
    *(float4*)&vs[l][d4] = *(const float4*)(kp + 256);
  }
  __syncthreads();
  const float scale = 0.1767766952966369f;
  const int r = t >> 3, g8 = t & 7;
  float4 q0 = *(const float4*)&qs[r][0],  q1 = *(const float4*)&qs[r][4],
         q2 = *(const float4*)&qs[r][8],  q3 = *(const float4*)&qs[r][12],
         q4 = *(const float4*)&qs[r][16], q5 = *(const float4*)&qs[r][20],
         q6 = *(const float4*)&qs[r][24], q7 = *(const float4*)&qs[r][28];
  float sv[8];
#pragma unroll
  for (int j = 0; j < 8; j++){
    const float* kr = &ks[g8*8 + j][0];
    float s = dot4(q0, *(const float4*)(kr+0))  + dot4(q1, *(const float4*)(kr+4))
            + dot4(q2, *(const float4*)(kr+8))  + dot4(q3, *(const float4*)(kr+12))
            + dot4(q4, *(const float4*)(kr+16)) + dot4(q5, *(const float4*)(kr+20))
            + dot4(q6, *(const float4*)(kr+24)) + dot4(q7, *(const float4*)(kr+28));
    sv[j] = s*scale;
  }
  float mx = sv[0];
#pragma unroll
  for (int j = 1; j < 8; j++) mx = fmaxf(mx, sv[j]);
  mx = fmaxf(mx, __shfl_xor(mx, 1, 64));
  mx = fmaxf(mx, __shfl_xor(mx, 2, 64));
  mx = fmaxf(mx, __shfl_xor(mx, 4, 64));
  float sum = 0.f;
#pragma unroll
  for (int j = 0; j < 8; j++){ sv[j] = __expf(sv[j] - mx); sum += sv[j]; }
  sum += __shfl_xor(sum, 1, 64);
  sum += __shfl_xor(sum, 2, 64);
  sum += __shfl_xor(sum, 4, 64);
  float inv = 1.0f/sum;
#pragma unroll
  for (int j = 0; j < 8; j++) S[r][g8*8 + j] = sv[j]*inv;
  __syncthreads();
  const int d0 = g8*4;
  float4 o = make_float4(0.f, 0.f, 0.f, 0.f);
  for (int c = 0; c < 64; c++){
    float p = S[r][c];
    float4 v = *(const float4*)&vs[c][d0];
    o.x += p*v.x; o.y += p*v.y; o.z += p*v.z; o.w += p*v.w;
  }
  *(float4*)(outp + ((size_t)(b*NLAT + r0 + r))*DIMD + h*32 + d0) = o;
}

// Fused heads: blockIdx.y==0 -> behavior decoder attn+proj; ==1 -> spike logits.
// Disjoint output ranges (out[0..31] vs out[32..]), independent inputs.
__global__ void k_heads(const float* __restrict__ qb, const float* __restrict__ kv,
                        const float* __restrict__ wo, const float* __restrict__ lat,
                        const float* __restrict__ spw, const float* __restrict__ spb,
                        float* __restrict__ outp){
  int b = blockIdx.x;
  int t = threadIdx.x;
  if (blockIdx.y == 1){
    __shared__ float m[256];
    float s = 0.f;
    for (int l = 0; l < NLAT; l++) s += lat[((size_t)(b*NLAT + l))*DIMD + t];
    m[t] = s*(1.0f/NLAT);
    __syncthreads();
    if (t < 64){
      float o = spb[t];
      for (int c = 0; c < 256; c++) o += m[c]*spw[c*64 + t];
      outp[32 + b*64 + t] = o;
    }
    return;
  }
  __shared__ float S[16][65];
  __shared__ float O2[2][256];
  __shared__ float red[256];
  const float scale = 0.1767766952966369f;
#pragma unroll
  for (int i = 0; i < 4; i++){
    int idx = t + i*256;
    int row = idx >> 6, c = idx & 63;
    int iq = row >> 3, h = row & 7;
    const float* qp = qb + iq*DIMD + h*32;
    const float* kp = kv + ((size_t)(b*NLAT + c))*512 + h*32;
    float s = 0.f;
#pragma unroll
    for (int d = 0; d < 32; d++) s += qp[d]*kp[d];
    S[row][c] = s*scale;
  }
  __syncthreads();
  if (t < 16){
    float mx = -1e30f;
    for (int c = 0; c < 64; c++) mx = fmaxf(mx, S[t][c]);
    float sum = 0.f;
    for (int c = 0; c < 64; c++){ float p = expf(S[t][c] - mx); S[t][c] = p; sum += p; }
    float inv = 1.0f/sum;
    for (int c = 0; c < 64; c++) S[t][c] *= inv;
  }
  __syncthreads();
#pragma unroll
  for (int i = 0; i < 2; i++){
    int idx = t + i*256;
    int iq = idx >> 8, c2 = idx & 255;
    int h = c2 >> 5, d = c2 & 31;
    float o = 0.f;
    for (int c = 0; c < 64; c++)
      o += S[iq*8 + h][c]*kv[((size_t)(b*NLAT + c))*512 + 256 + h*32 + d];
    O2[iq][c2] = o;
  }
  __syncthreads();
  for (int iq = 0; iq < 2; iq++){
    red[t] = O2[iq][t]*wo[t];
    __syncthreads();
    for (int off = 128; off > 0; off >>= 1){
      if (t < off) red[t] += red[t + off];
      __syncthreads();
    }
    if (t == 0) outp[b*2 + iq] = red[0];
    __syncthreads();
  }
}

extern "C" void kernel_launch(void* const* d_in, const int* in_sizes, int n_in,
                              void* d_out, int out_size, void* d_ws, size_t ws_size,
                              hipStream_t stream){
  const int* nid      = (const int*)d_in[0];
  const int* tbin     = (const int*)d_in[1];
  const int* vval     = (const int*)d_in[2];
  const int* bidx     = (const int*)d_in[3];
  const float* ne     = (const float*)d_in[6];
  const float* te     = (const float*)d_in[7];
  const float* ve     = (const float*)d_in[8];
  const float* lat_i  = (const float*)d_in[9];
  const float* Wq_c   = (const float*)d_in[10];
  const float* Wkv_c  = (const float*)d_in[11];
  const float* Wo_c   = (const float*)d_in[12];
  const float* W1_c   = (const float*)d_in[13];
  const float* W2_c   = (const float*)d_in[14];
  const float* Wqkv_s = (const float*)d_in[15];
  const float* Wo_s   = (const float*)d_in[16];
  const float* W1_s   = (const float*)d_in[17];
  const float* W2_s   = (const float*)d_in[18];
  const float* bh_query = (const float*)d_in[19];
  const float* bh_wq    = (const float*)d_in[20];
  const float* bh_wkv   = (const float*)d_in[21];
  const float* bh_wo    = (const float*)d_in[22];
  const float* bh_ln_w  = (const float*)d_in[23];
  const float* bh_ln_b  = (const float*)d_in[24];
  const float* sp_w     = (const float*)d_in[25];
  const float* sp_b     = (const float*)d_in[26];
  float* out = (float*)d_out;
  int E = in_sizes[0];
  (void)n_in; (void)out_size;

  const size_t MBf = (size_t)1 << 20;
  size_t per_gb = (size_t)18*MBf;
  size_t fixed  = (size_t)31*MBf;
  int gb = 1;
  if      (fixed + 16*per_gb <= ws_size) gb = 16;
  else if (fixed +  8*per_gb <= ws_size) gb = 8;
  else if (fixed +  4*per_gb <= ws_size) gb = 4;
  else if (fixed +  2*per_gb <= ws_size) gb = 2;

  char* wsb = (char*)d_ws;
  size_t o = 0;
  auto alloc = [&](size_t bytes)->char*{
    char* p = wsb + o; o = (o + bytes + 255) & ~(size_t)255; return p;
  };
  int*   cnt    = (int*)  alloc((size_t)NB*4);
  int*   sorted = (int*)  alloc((size_t)NB*EMAXC*4);
  float* tq     = (float*)alloc((size_t)64*256*4);
  float* qc     = (float*)alloc((size_t)64*256*4);
  float* qb     = (float*)alloc((size_t)2*256*4);
  u16*   Wt     = (u16*)  alloc((size_t)768*256*2);
  f16t*  WT     = (f16t*) alloc((size_t)WT_TOTAL*2);
  u16*   XLN    = (u16*)  alloc((size_t)gb*EMAXC*256*2);
  u8*    PT     = (u8*)   alloc((size_t)gb*512*EPAD);
  u8*    VT     = (u8*)   alloc((size_t)gb*256*EPAD);
  float* pnum   = (float*)alloc((size_t)NB*NHH*NCH2*2048*4);
  float* pden   = (float*)alloc((size_t)NB*NHH*NCH2*64*4);
  float* OC     = (float*)alloc((size_t)NB*64*256*4);
  float* lat    = (float*)alloc((size_t)NB*64*256*4);
  float* qkv    = (float*)alloc((size_t)NB*64*768*4);
  float* ffh    = (float*)alloc((size_t)NB*64*1024*4);

  // ---- prep ----
  k_zero<<<1, 64, 0, stream>>>(cnt);
  k_sort<<<(E + 1023)/1024, 256, 0, stream>>>(bidx, cnt, sorted, E);
  k_ln<<<16, 256, 0, stream>>>(lat_i, tq, 64);
  k_gemm<<<dim3(8,1), 256, 0, stream>>>(tq, Wq_c, qc, 64, 256, 256);
  k_qw<<<768, 256, 0, stream>>>(Wkv_c, qc, Wt);
  k_gemm<<<dim3(1,1), 256, 0, stream>>>(bh_query, bh_wq, qb, 2, 256, 256);
  k_wt<<<dim3(64,12), 256, 0, stream>>>(Wo_c, W1_c, W2_c, Wqkv_s, Wo_s, W1_s,
                                        W2_s, bh_wkv, WT);

  // ---- event cross-attention, runtime-sized batch groups ----
  for (int b0 = 0; b0 < NB; b0 += gb){
    k_a0<<<dim3(EMAXC/4, gb), 256, 0, stream>>>(sorted, cnt, nid, tbin, vval,
                                                ne, te, ve, XLN, b0);
    k_a<<<dim3(6, 53, gb), 512, 0, stream>>>(XLN, Wt, cnt, PT, VT, b0);
    k_b<<<dim3(NCH2, NHH, gb), 256, 0, stream>>>(PT, VT, cnt, pnum, pden, b0);
  }
  k_red<<<1024, 256, 0, stream>>>(pnum, pden, OC);

  // ---- latent chain (f16 MFMA GEMMs; LN fused as prologue where K=256) ----
  const int M = NB*NLAT;  // 1024
  k_init<<<M, 256, 0, stream>>>(lat_i, lat);
  k_gemm3<<<dim3(16,4,4), 256, 0, stream>>>(OC, WT + WTO_WOC, lat, nullptr, nullptr,
                                            M, 256, 256, 2, 0);
  k_gemm3<<<dim3(16,16,1), 256, 0, stream>>>(lat, WT + WTO_W1C, ffh, nullptr, nullptr,
                                             M, 256, 1024, 1, 1);
  k_gemm3<<<dim3(16,4,4), 256, 0, stream>>>(ffh, WT + WTO_W2C, lat, nullptr, nullptr,
                                            M, 1024, 256, 2, 0);

  for (int i = 0; i < 2; i++){
    k_gemm3<<<dim3(16,12,1), 256, 0, stream>>>(lat, WT + (i ? WTO_QKV1 : WTO_QKV0), qkv,
                                               nullptr, nullptr, M, 256, 768, 0, 1);
    k_attn<<<dim3(NB, NHH, 2), 256, 0, stream>>>(qkv, ffh);
    k_gemm3<<<dim3(16,4,4), 256, 0, stream>>>(ffh, WT + (i ? WTO_WOS1 : WTO_WOS0), lat,
                                              nullptr, nullptr, M, 256, 256, 2, 0);
    k_gemm3<<<dim3(16,16,1), 256, 0, stream>>>(lat, WT + (i ? WTO_W1S1 : WTO_W1S0), ffh,
                                               nullptr, nullptr, M, 256, 1024, 1, 1);
    k_gemm3<<<dim3(16,4,4), 256, 0, stream>>>(ffh, WT + (i ? WTO_W2S1 : WTO_W2S0), lat,
                                              nullptr, nullptr, M, 1024, 256, 2, 0);
  }

  // ---- heads ----
  k_gemm3<<<dim3(16,8,1), 256, 0, stream>>>(lat, WT + WTO_BH, qkv, bh_ln_w, bh_ln_b,
                                            M, 256, 512, 0, 1);
  k_heads<<<dim3(NB, 2), 256, 0, stream>>>(qb, qkv, bh_wo, lat, sp_w, sp_b, out);
}

// Round 11
// 558.726 us; speedup vs baseline: 1.0303x; 1.0303x over previous
//
#include <hip/hip_runtime.h>
#include <math.h>

#define NB 16
#define DIMD 256
#define NHH 8
#define NLAT 64
#define EMAXC 13568
#define NCH2 14            /* chunks of 1024 events (last partial) */
#define EPAD (NCH2*1024)   /* 14336: padded event stride (bytes for fp8 PT/VT) */

typedef float f32x4 __attribute__((ext_vector_type(4)));
typedef __bf16 bf16x8 __attribute__((ext_vector_type(8)));
typedef _Float16 f16t;
typedef __attribute__((ext_vector_type(8))) _Float16 f16x8;
typedef unsigned short u16;
typedef unsigned char u8;
typedef unsigned int u32;
typedef __attribute__((ext_vector_type(4))) unsigned int u32x4;
typedef __attribute__((ext_vector_type(8))) unsigned short u16x8;

/* f16 transposed-weight pool offsets (elements), layout [N][K] */
#define WTO_WOC   0u
#define WTO_W1C   65536u
#define WTO_W2C   327680u
#define WTO_QKV0  589824u
#define WTO_WOS0  786432u
#define WTO_W1S0  851968u
#define WTO_W2S0  1114112u
#define WTO_QKV1  1376256u
#define WTO_WOS1  1572864u
#define WTO_W1S1  1638400u
#define WTO_W2S1  1900544u
#define WTO_BH    2162688u
#define WT_TOTAL  2293760u

static __device__ __forceinline__ float wave_sum(float v){
#pragma unroll
  for (int off = 32; off > 0; off >>= 1) v += __shfl_xor(v, off, 64);
  return v;
}

static __device__ __forceinline__ u16 f2bf(float x){
  unsigned u = __float_as_uint(x);
  u += 0x7fffu + ((u >> 16) & 1u);
  return (u16)(u >> 16);
}

static __device__ __forceinline__ float gelu_tanh(float x){
  float x3 = x*x*x;
  return 0.5f*x*(1.0f + tanhf(0.7978845608028654f*(x + 0.044715f*x3)));
}

static __device__ __forceinline__ float dot4(float4 a, float4 b){
  return a.x*b.x + a.y*b.y + a.z*b.z + a.w*b.w;
}

// Async global->LDS DMA, 16B per lane. LDS dest is wave-uniform base + lane*16.
static __device__ __forceinline__ void gl_lds16(const void* g, void* l){
  __builtin_amdgcn_global_load_lds((const __attribute__((address_space(1))) void*)g,
                                   (__attribute__((address_space(3))) void*)l,
                                   16, 0, 0);
}

__global__ void k_zero(int* cnt){ if ((int)threadIdx.x < NB) cnt[threadIdx.x] = 0; }

// LDS-histogram bucket sort: 16 global atomics per 1024-event block.
__global__ void k_sort(const int* __restrict__ bidx, int* __restrict__ cnt,
                       int* __restrict__ sorted, int E){
  __shared__ int h[NB], base[NB];
  int t = threadIdx.x;
  if (t < NB) h[t] = 0;
  __syncthreads();
  int e0 = blockIdx.x*1024;
  int myb[4], myp[4];
#pragma unroll
  for (int i = 0; i < 4; i++){
    int e = e0 + i*256 + t;
    myb[i] = -1;
    if (e < E){ myb[i] = bidx[e]; myp[i] = atomicAdd(&h[myb[i]], 1); }
  }
  __syncthreads();
  if (t < NB) base[t] = atomicAdd(&cnt[t], h[t]);
  __syncthreads();
#pragma unroll
  for (int i = 0; i < 4; i++){
    if (myb[i] >= 0){
      int p = base[myb[i]] + myp[i];
      if (p < EMAXC) sorted[myb[i]*EMAXC + p] = e0 + i*256 + t;
    }
  }
}

// LayerNorm over rows of 256 (used only for lat_init prep).
__global__ void k_ln(const float* __restrict__ X, float* __restrict__ Y, int rows){
  int wave = threadIdx.x >> 6, lane = threadIdx.x & 63;
  int row = blockIdx.x*4 + wave;
  if (row >= rows) return;
  float4 x = ((const float4*)(X + (size_t)row*DIMD))[lane];
  float s = wave_sum(x.x + x.y + x.z + x.w);
  float m = s * (1.0f/DIMD);
  float d0 = x.x-m, d1 = x.y-m, d2 = x.z-m, d3 = x.w-m;
  float v = wave_sum(d0*d0 + d1*d1 + d2*d2 + d3*d3) * (1.0f/DIMD);
  float rs = rsqrtf(v + 1e-5f);
  ((float4*)(Y + (size_t)row*DIMD))[lane] = make_float4(d0*rs, d1*rs, d2*rs, d3*rs);
}

// lat[row] = lat_init[row % 64]  (row-broadcast residual init)
__global__ void k_init(const float* __restrict__ lat_i, float* __restrict__ lat){
  int r = blockIdx.x, t = threadIdx.x;
  lat[(size_t)r*DIMD + t] = lat_i[(size_t)(r & 63)*DIMD + t];
}

// Small prep GEMM (tiny M): C[M,N] = A[M,K] @ W[K,N]
__global__ __launch_bounds__(256) void k_gemm(
    const float* __restrict__ A, const float* __restrict__ W,
    float* __restrict__ C, int M, int K, int N){
  __shared__ float As[8][1024];
  int t = threadIdx.x;
  int row0 = blockIdx.x*8;
  int col = blockIdx.y*256 + t;
  int kq = K >> 2;
  for (int idx = t; idx < 8*kq; idx += 256){
    int r = idx / kq, kc = idx % kq;
    float4 v = make_float4(0.f,0.f,0.f,0.f);
    if (row0 + r < M) v = ((const float4*)(A + (size_t)(row0+r)*K))[kc];
    ((float4*)&As[r][0])[kc] = v;
  }
  __syncthreads();
  float acc[8] = {0,0,0,0,0,0,0,0};
  for (int k = 0; k < K; k += 4){
    float w0 = W[(size_t)(k+0)*N + col];
    float w1 = W[(size_t)(k+1)*N + col];
    float w2 = W[(size_t)(k+2)*N + col];
    float w3 = W[(size_t)(k+3)*N + col];
#pragma unroll
    for (int r = 0; r < 8; r++){
      float4 a = *((const float4*)&As[r][k]);
      acc[r] += a.x*w0 + a.y*w1 + a.z*w2 + a.w*w3;
    }
  }
#pragma unroll
  for (int r = 0; r < 8; r++){
    int row = row0 + r;
    if (row < M) C[(size_t)row*N + col] = acc[r];
  }
}

// Transpose all latent-chain weights to f16 [N][K] pool (runs once per launch).
// 64x64 LDS-tile transpose; grid (64, 12); out-of-range tiles return.
__global__ __launch_bounds__(256) void k_wt(
    const float* __restrict__ Wo_c, const float* __restrict__ W1_c,
    const float* __restrict__ W2_c, const float* __restrict__ Wqkv_s,
    const float* __restrict__ Wo_s, const float* __restrict__ W1_s,
    const float* __restrict__ W2_s, const float* __restrict__ bh_wkv,
    f16t* __restrict__ WT){
  const int mid = blockIdx.y;
  const float* src; int K, N; unsigned off;
  switch (mid){
    case 0:  src = Wo_c;            K = 256;  N = 256;  off = WTO_WOC;  break;
    case 1:  src = W1_c;            K = 256;  N = 1024; off = WTO_W1C;  break;
    case 2:  src = W2_c;            K = 1024; N = 256;  off = WTO_W2C;  break;
    case 3:  src = Wqkv_s;          K = 256;  N = 768;  off = WTO_QKV0; break;
    case 4:  src = Wo_s;            K = 256;  N = 256;  off = WTO_WOS0; break;
    case 5:  src = W1_s;            K = 256;  N = 1024; off = WTO_W1S0; break;
    case 6:  src = W2_s;            K = 1024; N = 256;  off = WTO_W2S0; break;
    case 7:  src = Wqkv_s + 196608; K = 256;  N = 768;  off = WTO_QKV1; break;
    case 8:  src = Wo_s + 65536;    K = 256;  N = 256;  off = WTO_WOS1; break;
    case 9:  src = W1_s + 262144;   K = 256;  N = 1024; off = WTO_W1S1; break;
    case 10: src = W2_s + 262144;   K = 1024; N = 256;  off = WTO_W2S1; break;
    default: src = bh_wkv;          K = 256;  N = 512;  off = WTO_BH;   break;
  }
  const int ntiles = N >> 6;
  const int tiles = ntiles * (K >> 6);
  if ((int)blockIdx.x >= tiles) return;
  const int kt = blockIdx.x / ntiles, nt = blockIdx.x % ntiles;
  __shared__ float tile[64][65];
  const int t = threadIdx.x;
  const int k0 = kt*64, n0 = nt*64;
#pragma unroll
  for (int i = 0; i < 16; i++){
    int k = i*4 + (t >> 6);
    tile[k][t & 63] = src[(size_t)(k0 + k)*N + n0 + (t & 63)];
  }
  __syncthreads();
  const int n = t >> 2, ks = (t & 3)*16;
  f16t* d = WT + off + (size_t)(n0 + n)*K + k0 + ks;
#pragma unroll
  for (int j = 0; j < 16; j++) d[j] = (f16t)tile[ks + j][n];
}

// MFMA latent-chain GEMM: C[M,N] (+)= A[M,K] @ W, W given as f16 WT[N][K].
// 64x64 tile, BK=64 (r10-verified: ~-30us vs BK=32 across the chain), 4 waves.
// A staged f32->f16 via LDS pitch-72; B via global_load_lds with 8-chunk XOR
// swizzle kc=c'^(r&7) (involution: inverse on source, forward on read).
// modes: 0 plain / 1 gelu / 2 atomicAdd; K split over gridDim.z.
// do_ln (K==256, S==1): LayerNorm rows of A, optional affine lnw/lnb.
__global__ __launch_bounds__(256) void k_gemm3(
    const float* __restrict__ A, const f16t* __restrict__ WT, float* __restrict__ C,
    const float* __restrict__ lnw, const float* __restrict__ lnb,
    int M, int K, int N, int mode, int do_ln){
  __shared__ f16t Xs[64][72];
  __shared__ f16t Ws[64][64];
  __shared__ float lnm[64], lnr[64];
  const int t = threadIdx.x;
  const int wv = t >> 6, lane = t & 63;
  const int quad = lane >> 4, lane15 = lane & 15;
  const int m0 = blockIdx.x*64, n0 = blockIdx.y*64;
  const int Kc = K / gridDim.z;
  const int k0b = blockIdx.z*Kc;

  f32x4 acc[4];
#pragma unroll
  for (int j = 0; j < 4; j++) acc[j] = (f32x4){0.f,0.f,0.f,0.f};

  if (do_ln){
    int r = t >> 2, seg = (t & 3)*64;
    const float* Ar = A + (size_t)(m0 + r)*K + seg;
    float s = 0.f, s2 = 0.f;
#pragma unroll
    for (int j = 0; j < 64; j += 4){
      float4 v = *(const float4*)(Ar + j);
      s  += v.x + v.y + v.z + v.w;
      s2 += v.x*v.x + v.y*v.y + v.z*v.z + v.w*v.w;
    }
    s += __shfl_xor(s, 1, 64); s2 += __shfl_xor(s2, 1, 64);
    s += __shfl_xor(s, 2, 64); s2 += __shfl_xor(s2, 2, 64);
    if ((t & 3) == 0){
      float m = s*(1.0f/256.0f);
      float var = s2*(1.0f/256.0f) - m*m;
      lnm[r] = m; lnr[r] = rsqrtf(var + 1e-5f);
    }
    __syncthreads();
  }

  const int ar = t >> 2;                        // A stage row (0..63)
  const int as16 = (t & 3)*16;                  // A stage k-offset (16 f16)
  f16t* wdst0 = &Ws[0][0] + (size_t)(wv*64)*8;          // p=0 wave base
  f16t* wdst1 = &Ws[0][0] + (size_t)(256 + wv*64)*8;    // p=1 wave base

  for (int k0 = k0b; k0 < k0b + Kc; k0 += 64){
    __syncthreads();                  // prior frag reads done; buffers free
#pragma unroll
    for (int p = 0; p < 2; p++){
      int li = p*256 + t;
      int r = li >> 3;
      int kc = (li & 7) ^ (r & 7);
      gl_lds16(WT + (size_t)(n0 + r)*K + k0 + kc*8, p ? wdst1 : wdst0);
    }
    const float* Arow = A + (size_t)(m0 + ar)*K + k0 + as16;
    float4 v0 = *(const float4*)(Arow + 0);
    float4 v1 = *(const float4*)(Arow + 4);
    float4 v2 = *(const float4*)(Arow + 8);
    float4 v3 = *(const float4*)(Arow + 12);
    if (do_ln){
      float mm = lnm[ar], rs = lnr[ar];
      v0.x=(v0.x-mm)*rs; v0.y=(v0.y-mm)*rs; v0.z=(v0.z-mm)*rs; v0.w=(v0.w-mm)*rs;
      v1.x=(v1.x-mm)*rs; v1.y=(v1.y-mm)*rs; v1.z=(v1.z-mm)*rs; v1.w=(v1.w-mm)*rs;
      v2.x=(v2.x-mm)*rs; v2.y=(v2.y-mm)*rs; v2.z=(v2.z-mm)*rs; v2.w=(v2.w-mm)*rs;
      v3.x=(v3.x-mm)*rs; v3.y=(v3.y-mm)*rs; v3.z=(v3.z-mm)*rs; v3.w=(v3.w-mm)*rs;
      if (lnw){
        int k = k0 + as16;
        v0.x=v0.x*lnw[k+0]+lnb[k+0];  v0.y=v0.y*lnw[k+1]+lnb[k+1];
        v0.z=v0.z*lnw[k+2]+lnb[k+2];  v0.w=v0.w*lnw[k+3]+lnb[k+3];
        v1.x=v1.x*lnw[k+4]+lnb[k+4];  v1.y=v1.y*lnw[k+5]+lnb[k+5];
        v1.z=v1.z*lnw[k+6]+lnb[k+6];  v1.w=v1.w*lnw[k+7]+lnb[k+7];
        v2.x=v2.x*lnw[k+8]+lnb[k+8];  v2.y=v2.y*lnw[k+9]+lnb[k+9];
        v2.z=v2.z*lnw[k+10]+lnb[k+10]; v2.w=v2.w*lnw[k+11]+lnb[k+11];
        v3.x=v3.x*lnw[k+12]+lnb[k+12]; v3.y=v3.y*lnw[k+13]+lnb[k+13];
        v3.z=v3.z*lnw[k+14]+lnb[k+14]; v3.w=v3.w*lnw[k+15]+lnb[k+15];
      }
    }
    f16x8 h0 = {(f16t)v0.x,(f16t)v0.y,(f16t)v0.z,(f16t)v0.w,
                (f16t)v1.x,(f16t)v1.y,(f16t)v1.z,(f16t)v1.w};
    f16x8 h1 = {(f16t)v2.x,(f16t)v2.y,(f16t)v2.z,(f16t)v2.w,
                (f16t)v3.x,(f16t)v3.y,(f16t)v3.z,(f16t)v3.w};
    *(f16x8*)&Xs[ar][as16]     = h0;
    *(f16x8*)&Xs[ar][as16 + 8] = h1;
    __syncthreads();                  // drains vmcnt (DMA) + lgkm (ds_write)
#pragma unroll
    for (int ks = 0; ks < 2; ks++){
      f16x8 a = *(const f16x8*)&Xs[wv*16 + lane15][ks*32 + quad*8];
#pragma unroll
      for (int nt = 0; nt < 4; nt++){
        int ch = (ks*4 + quad) ^ (lane15 & 7);
        f16x8 bw = *(const f16x8*)&Ws[nt*16 + lane15][ch*8];
        acc[nt] = __builtin_amdgcn_mfma_f32_16x16x32_f16(a, bw, acc[nt], 0, 0, 0);
      }
    }
  }
#pragma unroll
  for (int nt = 0; nt < 4; nt++){
    int col = n0 + nt*16 + lane15;
#pragma unroll
    for (int j = 0; j < 4; j++){
      int row = m0 + wv*16 + quad*4 + j;
      float v = acc[nt][j];
      if (mode == 1) v = gelu_tanh(v);
      float* cp = C + (size_t)row*N + col;
      if (mode == 2) atomicAdd(cp, v);
      else *cp = v;
    }
  }
}

// Build Wt[768][256] bf16 (transposed, column-reordered)
__global__ void k_qw(const float* __restrict__ Wkv, const float* __restrict__ qc,
                     u16* __restrict__ Wt){
  int n = blockIdx.x;
  int k = threadIdx.x;
  float v;
  if (n < 256){
    v = Wkv[(size_t)k*512 + 256 + n];
  } else {
    int h = (n - 256) >> 6, l = (n - 256) & 63;
    const float* wk = Wkv + (size_t)k*512 + h*32;
    const float* qr = qc + (size_t)l*256 + h*32;
    float s = 0.f;
#pragma unroll
    for (int dd = 0; dd < 32; dd++) s += wk[dd]*qr[dd];
    v = s*0.1767766952966369f;
  }
  Wt[(size_t)n*256 + k] = f2bf(v);
}

// Gather+LN -> XLN bf16 (group-local), zero pad rows. One wave per event row.
__global__ void k_a0(const int* __restrict__ sorted, const int* __restrict__ cnt,
                     const int* __restrict__ nid, const int* __restrict__ tbin,
                     const int* __restrict__ vval,
                     const float* __restrict__ ne, const float* __restrict__ te,
                     const float* __restrict__ ve, u16* __restrict__ XLN, int b0){
  int wv = threadIdx.x >> 6, lane = threadIdx.x & 63;
  int e = blockIdx.x*4 + wv;
  int bg = blockIdx.y, b = b0 + bg;
  int cn = min(cnt[b], EMAXC);
  ushort4 pk; pk.x = 0; pk.y = 0; pk.z = 0; pk.w = 0;
  if (e < cn){
    int ev = sorted[b*EMAXC + e];
    float4 aa = ((const float4*)(ne + (size_t)nid[ev]*DIMD))[lane];
    float4 bb = ((const float4*)(te + (size_t)tbin[ev]*DIMD))[lane];
    float4 cc = ((const float4*)(ve + (size_t)vval[ev]*DIMD))[lane];
    float x0 = aa.x+bb.x+cc.x, x1 = aa.y+bb.y+cc.y;
    float x2 = aa.z+bb.z+cc.z, x3 = aa.w+bb.w+cc.w;
    float s = wave_sum(x0 + x1 + x2 + x3);
    float m = s*(1.0f/DIMD);
    x0 -= m; x1 -= m; x2 -= m; x3 -= m;
    float v = wave_sum(x0*x0 + x1*x1 + x2*x2 + x3*x3)*(1.0f/DIMD);
    float rs = rsqrtf(v + 1e-5f);
    pk.x = f2bf(x0*rs); pk.y = f2bf(x1*rs); pk.z = f2bf(x2*rs); pk.w = f2bf(x3*rs);
  }
  *(ushort4*)(XLN + ((size_t)bg*EMAXC + e)*DIMD + lane*4) = pk;
}

// Dense MFMA GEMM: [PT|VT] (transposed, fp8 e4m3) = exp?(XLN @ Wt^T).
// 128x128 tile, BK=32, THREE-buffer global_load_lds pipeline with counted
// vmcnt (T3/T4). Two raw s_barriers per step. Chunk XOR-swizzle (r4-verified,
// conflict-free). NO setprio (r6: -8.7% on lockstep structure).
// GRID LAYOUT IS LOAD-BEARING (r10 lesson): nidx=x>>3, rtile=y*8+(x&7) puts
// the 6 column-tile blocks sharing an X row-panel at blockIdx stride 8 = XCD
// round-robin period -> same per-XCD L2. Flat (6,53) grid spread sharers over
// 6 XCDs: FETCH 26.7->153.7MB, k_a 58->79us. Do not flatten this grid.
// LDS 48KB -> 3 blocks/CU. grid (48, 14, gb).
__global__ __launch_bounds__(256) void k_a(
    const u16* __restrict__ XLN, const u16* __restrict__ Wt,
    const int* __restrict__ cnt, u8* __restrict__ PT, u8* __restrict__ VT, int b0)
{
  __shared__ union ShMem {
    struct { u16 Xs[3][128][32]; u16 Ws[3][128][32]; } s;
    u8 Tr[128][136];
  } sh;
  const int t = threadIdx.x;
  const int wv = t >> 6, lane = t & 63;
  const int quad = lane >> 4, lane15 = lane & 15;
  const int nidx = blockIdx.x >> 3;
  const int rtile = blockIdx.y*8 + (blockIdx.x & 7);
  if (nidx >= 6 || rtile >= EMAXC/128) return;
  const int bg = blockIdx.z;
  const int b = b0 + bg;
  const int cn = min(cnt[b], EMAXC);
  const int row0 = rtile * 128;
  if (row0 >= cn) return;
  const int n0 = nidx * 128;
  const int eh = (wv >> 1) * 64, nh = (wv & 1) * 64;

  f32x4 acc[4][4];
#pragma unroll
  for (int i = 0; i < 4; i++)
#pragma unroll
    for (int j = 0; j < 4; j++) acc[i][j] = (f32x4){0.f,0.f,0.f,0.f};

  const u16* Xbase = XLN + ((size_t)bg*EMAXC + row0)*DIMD;
  const u16* Wbase = Wt + (size_t)n0*256;

  auto stage = [&](int buf, int k0){
#pragma unroll
    for (int p = 0; p < 2; p++){
      int li = p*256 + wv*64 + lane;
      int r = li >> 2;
      int kc = (li & 3) ^ ((r >> 1) & 3);
      u16* xd = &sh.s.Xs[buf][0][0] + (size_t)(p*256 + wv*64)*8;
      u16* wd = &sh.s.Ws[buf][0][0] + (size_t)(p*256 + wv*64)*8;
      gl_lds16(Xbase + (size_t)r*DIMD + k0 + kc*8, xd);
      gl_lds16(Wbase + (size_t)r*256  + k0 + kc*8, wd);
    }
  };
  const int cswz = quad ^ ((lane15 >> 1) & 3);   // read-side chunk swizzle
  auto compute = [&](int buf){
    bf16x8 a[4], bw[4];
#pragma unroll
    for (int mt = 0; mt < 4; mt++)
      a[mt] = *(const bf16x8*)&sh.s.Xs[buf][eh + mt*16 + lane15][cswz*8];
#pragma unroll
    for (int nt = 0; nt < 4; nt++)
      bw[nt] = *(const bf16x8*)&sh.s.Ws[buf][nh + nt*16 + lane15][cswz*8];
#pragma unroll
    for (int mt = 0; mt < 4; mt++)
#pragma unroll
      for (int nt = 0; nt < 4; nt++)
        acc[mt][nt] = __builtin_amdgcn_mfma_f32_16x16x32_bf16(a[mt], bw[nt], acc[mt][nt], 0, 0, 0);
  };

  stage(0, 0);
  stage(1, 32);
#pragma unroll
  for (int it = 0; it < 8; it++){
    __builtin_amdgcn_s_barrier();              // A: compute(it-1) done; buf (it+2)%3 free
    if (it + 2 < 8) stage((it + 2) % 3, (it + 2)*32);
    if (it <= 5)      asm volatile("s_waitcnt vmcnt(8)" ::: "memory");
    else if (it == 6) asm volatile("s_waitcnt vmcnt(4)" ::: "memory");
    else              asm volatile("s_waitcnt vmcnt(0)" ::: "memory");
    __builtin_amdgcn_s_barrier();              // B: everyone's stage(it) landed
    __builtin_amdgcn_sched_barrier(0);
    compute(it % 3);
  }
  const int is_p = (n0 >= 256);
  __syncthreads();   // buffers dead from here; Tr takes over the storage
#pragma unroll
  for (int mt = 0; mt < 4; mt++){
    int e0 = eh + mt*16 + quad*4;
#pragma unroll
    for (int nt = 0; nt < 4; nt++){
      int c = nh + nt*16 + lane15;
      f32x4 v = acc[mt][nt];
      if (is_p){ v.x = __expf(v.x); v.y = __expf(v.y); v.z = __expf(v.z); v.w = __expf(v.w); }
      int p01 = __builtin_amdgcn_cvt_pk_fp8_f32(v.x, v.y, 0, false);
      int p23 = __builtin_amdgcn_cvt_pk_fp8_f32(v.z, v.w, 0, false);
      unsigned pk = ((unsigned)p01 & 0xFFFFu) | ((unsigned)p23 << 16);
      *(unsigned*)&sh.Tr[c][e0] = pk;
    }
  }
  __syncthreads();
  u8* dst = is_p ? (PT + ((size_t)bg*512 + (n0 - 256))*EPAD)
                 : (VT + ((size_t)bg*256 + n0)*EPAD);
  const int chalf = lane >> 5;
  const int e4 = (lane & 31) * 4;
#pragma unroll
  for (int i = 0; i < 16; i++){
    int c = wv*32 + i*2 + chalf;
    unsigned val = *(const unsigned*)&sh.Tr[c][e4];
    *(unsigned*)(dst + (size_t)c*EPAD + row0 + e4) = val;
  }
}

// PV reduction (fp8 MFMA): O^T[dh][l] = sum_e V[dh][e]*P[l][e]; den via ones-MFMA.
// grid (NCH2, 8, gb), 256 thr; each wave owns a 256-event K-slice.
// No main-loop barriers: waves run phase-independent -> s_setprio(1) around the
// MFMA cluster (T5 regime per m191 attn; null only on barrier-lockstep GEMMs).
__global__ __launch_bounds__(256) void k_b(
    const u8* __restrict__ PT, const u8* __restrict__ VT,
    const int* __restrict__ cnt, float* __restrict__ pnum, float* __restrict__ pden, int b0)
{
  __shared__ float red[4][2048];
  __shared__ float redd[4][64];
  const int t = threadIdx.x;
  const int wv = t >> 6, lane = t & 63;
  const int quad = lane >> 4, lane15 = lane & 15;
  const int chunk = blockIdx.x, h = blockIdx.y, bg = blockIdx.z;
  const int b = b0 + bg;
  const int cn = min(cnt[b], EMAXC);
  const u8* PTg = PT + ((size_t)bg*512 + h*64)*EPAD;
  const u8* VTg = VT + ((size_t)bg*256 + h*32)*EPAD;

  f32x4 acc[3][4];
#pragma unroll
  for (int i = 0; i < 3; i++)
#pragma unroll
    for (int j = 0; j < 4; j++) acc[i][j] = (f32x4){0.f,0.f,0.f,0.f};

  const long ones = 0x3838383838383838L;

  const int e0w = chunk*1024 + wv*256;
#pragma unroll 2
  for (int ks = 0; ks < 8; ks++){
    int eb = e0w + ks*32 + quad*8;
    long a0 = *(const long*)(VTg + (size_t)(lane15     )*EPAD + eb);
    long a1 = *(const long*)(VTg + (size_t)(16 + lane15)*EPAD + eb);
    long bp[4];
#pragma unroll
    for (int nt = 0; nt < 4; nt++){
      union { long v; u8 c[8]; } m;
      m.v = *(const long*)(PTg + (size_t)(nt*16 + lane15)*EPAD + eb);
      if (eb + 8 > cn){
#pragma unroll
        for (int j = 0; j < 8; j++) if (eb + j >= cn) m.c[j] = 0;
      }
      bp[nt] = m.v;
    }
    __builtin_amdgcn_s_setprio(1);
#pragma unroll
    for (int nt = 0; nt < 4; nt++){
      acc[0][nt] = __builtin_amdgcn_mfma_f32_16x16x32_fp8_fp8(a0, bp[nt], acc[0][nt], 0, 0, 0);
      acc[1][nt] = __builtin_amdgcn_mfma_f32_16x16x32_fp8_fp8(a1, bp[nt], acc[1][nt], 0, 0, 0);
      acc[2][nt] = __builtin_amdgcn_mfma_f32_16x16x32_fp8_fp8(ones, bp[nt], acc[2][nt], 0, 0, 0);
    }
    __builtin_amdgcn_s_setprio(0);
  }
#pragma unroll
  for (int mt = 0; mt < 2; mt++)
#pragma unroll
    for (int nt = 0; nt < 4; nt++){
      int l = nt*16 + lane15;
#pragma unroll
      for (int j = 0; j < 4; j++)
        red[wv][l*32 + mt*16 + quad*4 + j] = acc[mt][nt][j];
    }
  if (quad == 0){
#pragma unroll
    for (int nt = 0; nt < 4; nt++) redd[wv][nt*16 + lane15] = acc[2][nt][0];
  }
  __syncthreads();
  size_t obase = ((size_t)(b*NHH + h)*NCH2 + chunk);
  for (int i = t; i < 2048; i += 256)
    pnum[obase*2048 + i] = red[0][i] + red[1][i] + red[2][i] + red[3][i];
  if (t < 64)
    pden[obase*64 + t] = redd[0][t] + redd[1][t] + redd[2][t] + redd[3][t];
}

// Reduce partials over chunks, divide, write OC[b][l][h*32+dh]
__global__ void k_red(const float* __restrict__ pnum, const float* __restrict__ pden,
                      float* __restrict__ OC){
  int g = blockIdx.x*256 + threadIdx.x;
  int b = g >> 14, r = g & 16383;
  int h = r >> 11, idx = r & 2047;
  int l = idx >> 5, dh = idx & 31;
  float ns = 0.f, ds = 0.f;
  for (int c = 0; c < NCH2; c++){
    size_t ob = ((size_t)(b*NHH + h)*NCH2 + c);
    ns += pnum[ob*2048 + idx];
    ds += pden[ob*64 + l];
  }
  OC[((size_t)(b*NLAT + l))*DIMD + h*32 + dh] = ns/ds;
}

// Self-attention over 64 latents. grid (NB, NHH, 2): z halves the Q rows so
// 256 blocks cover all CUs. float4 loads; S via register-blocked dot4 with
// broadcast LDS reads; wave-parallel softmax (8 lanes/row, shfl_xor 1/2/4);
// PV float4 over V rows.
__global__ __launch_bounds__(256) void k_attn(const float* __restrict__ qkv,
                                              float* __restrict__ outp){
  int b = blockIdx.x, h = blockIdx.y;
  int r0 = blockIdx.z*32;
  __shared__ float qs[32][33], ks[64][33], vs[64][33];
  __shared__ float S[32][65];
  int t = threadIdx.x;
  {
    int l = t >> 3, d4 = (t & 7)*4;     // qs: 32 rows x 8 float4
    const float* qp = qkv + ((size_t)(b*NLAT + r0 + l))*768 + h*32 + d4;
    *(float4*)&qs[l][d4] = *(const float4*)qp;
  }
#pragma unroll
  for (int i = 0; i < 2; i++){
    int idx = i*256 + t;
    int l = idx >> 3, d4 = (idx & 7)*4; // ks/vs: 64 rows x 8 float4
    const float* kp = qkv + ((size_t)(b*NLAT + l))*768 + h*32 + 256 + d4;
    *(float4*)&ks[l][d4] = *(const float4*)kp;
    *(float4*)&vs[l][d4] = *(const float4*)(kp + 256);
  }
  __syncthreads();
  const float scale = 0.1767766952966369f;
  const int r = t >> 3, g8 = t & 7;
  float4 q0 = *(const float4*)&qs[r][0],  q1 = *(const float4*)&qs[r][4],
         q2 = *(const float4*)&qs[r][8],  q3 = *(const float4*)&qs[r][12],
         q4 = *(const float4*)&qs[r][16], q5 = *(const float4*)&qs[r][20],
         q6 = *(const float4*)&qs[r][24], q7 = *(const float4*)&qs[r][28];
  float sv[8];
#pragma unroll
  for (int j = 0; j < 8; j++){
    const float* kr = &ks[g8*8 + j][0];
    float s = dot4(q0, *(const float4*)(kr+0))  + dot4(q1, *(const float4*)(kr+4))
            + dot4(q2, *(const float4*)(kr+8))  + dot4(q3, *(const float4*)(kr+12))
            + dot4(q4, *(const float4*)(kr+16)) + dot4(q5, *(const float4*)(kr+20))
            + dot4(q6, *(const float4*)(kr+24)) + dot4(q7, *(const float4*)(kr+28));
    sv[j] = s*scale;
  }
  float mx = sv[0];
#pragma unroll
  for (int j = 1; j < 8; j++) mx = fmaxf(mx, sv[j]);
  mx = fmaxf(mx, __shfl_xor(mx, 1, 64));
  mx = fmaxf(mx, __shfl_xor(mx, 2, 64));
  mx = fmaxf(mx, __shfl_xor(mx, 4, 64));
  float sum = 0.f;
#pragma unroll
  for (int j = 0; j < 8; j++){ sv[j] = __expf(sv[j] - mx); sum += sv[j]; }
  sum += __shfl_xor(sum, 1, 64);
  sum += __shfl_xor(sum, 2, 64);
  sum += __shfl_xor(sum, 4, 64);
  float inv = 1.0f/sum;
#pragma unroll
  for (int j = 0; j < 8; j++) S[r][g8*8 + j] = sv[j]*inv;
  __syncthreads();
  const int d0 = g8*4;
  float4 o = make_float4(0.f, 0.f, 0.f, 0.f);
  for (int c = 0; c < 64; c++){
    float p = S[r][c];
    float4 v = *(const float4*)&vs[c][d0];
    o.x += p*v.x; o.y += p*v.y; o.z += p*v.z; o.w += p*v.w;
  }
  *(float4*)(outp + ((size_t)(b*NLAT + r0 + r))*DIMD + h*32 + d0) = o;
}

// Fused heads: blockIdx.y==0 -> behavior decoder attn+proj; ==1 -> spike logits.
// Disjoint output ranges (out[0..31] vs out[32..]), independent inputs.
__global__ void k_heads(const float* __restrict__ qb, const float* __restrict__ kv,
                        const float* __restrict__ wo, const float* __restrict__ lat,
                        const float* __restrict__ spw, const float* __restrict__ spb,
                        float* __restrict__ outp){
  int b = blockIdx.x;
  int t = threadIdx.x;
  if (blockIdx.y == 1){
    __shared__ float m[256];
    float s = 0.f;
    for (int l = 0; l < NLAT; l++) s += lat[((size_t)(b*NLAT + l))*DIMD + t];
    m[t] = s*(1.0f/NLAT);
    __syncthreads();
    if (t < 64){
      float o = spb[t];
      for (int c = 0; c < 256; c++) o += m[c]*spw[c*64 + t];
      outp[32 + b*64 + t] = o;
    }
    return;
  }
  __shared__ float S[16][65];
  __shared__ float O2[2][256];
  __shared__ float red[256];
  const float scale = 0.1767766952966369f;
#pragma unroll
  for (int i = 0; i < 4; i++){
    int idx = t + i*256;
    int row = idx >> 6, c = idx & 63;
    int iq = row >> 3, h = row & 7;
    const float* qp = qb + iq*DIMD + h*32;
    const float* kp = kv + ((size_t)(b*NLAT + c))*512 + h*32;
    float s = 0.f;
#pragma unroll
    for (int d = 0; d < 32; d++) s += qp[d]*kp[d];
    S[row][c] = s*scale;
  }
  __syncthreads();
  if (t < 16){
    float mx = -1e30f;
    for (int c = 0; c < 64; c++) mx = fmaxf(mx, S[t][c]);
    float sum = 0.f;
    for (int c = 0; c < 64; c++){ float p = expf(S[t][c] - mx); S[t][c] = p; sum += p; }
    float inv = 1.0f/sum;
    for (int c = 0; c < 64; c++) S[t][c] *= inv;
  }
  __syncthreads();
#pragma unroll
  for (int i = 0; i < 2; i++){
    int idx = t + i*256;
    int iq = idx >> 8, c2 = idx & 255;
    int h = c2 >> 5, d = c2 & 31;
    float o = 0.f;
    for (int c = 0; c < 64; c++)
      o += S[iq*8 + h][c]*kv[((size_t)(b*NLAT + c))*512 + 256 + h*32 + d];
    O2[iq][c2] = o;
  }
  __syncthreads();
  for (int iq = 0; iq < 2; iq++){
    red[t] = O2[iq][t]*wo[t];
    __syncthreads();
    for (int off = 128; off > 0; off >>= 1){
      if (t < off) red[t] += red[t + off];
      __syncthreads();
    }
    if (t == 0) outp[b*2 + iq] = red[0];
    __syncthreads();
  }
}

extern "C" void kernel_launch(void* const* d_in, const int* in_sizes, int n_in,
                              void* d_out, int out_size, void* d_ws, size_t ws_size,
                              hipStream_t stream){
  const int* nid      = (const int*)d_in[0];
  const int* tbin     = (const int*)d_in[1];
  const int* vval     = (const int*)d_in[2];
  const int* bidx     = (const int*)d_in[3];
  const float* ne     = (const float*)d_in[6];
  const float* te     = (const float*)d_in[7];
  const float* ve     = (const float*)d_in[8];
  const float* lat_i  = (const float*)d_in[9];
  const float* Wq_c   = (const float*)d_in[10];
  const float* Wkv_c  = (const float*)d_in[11];
  const float* Wo_c   = (const float*)d_in[12];
  const float* W1_c   = (const float*)d_in[13];
  const float* W2_c   = (const float*)d_in[14];
  const float* Wqkv_s = (const float*)d_in[15];
  const float* Wo_s   = (const float*)d_in[16];
  const float* W1_s   = (const float*)d_in[17];
  const float* W2_s   = (const float*)d_in[18];
  const float* bh_query = (const float*)d_in[19];
  const float* bh_wq    = (const float*)d_in[20];
  const float* bh_wkv   = (const float*)d_in[21];
  const float* bh_wo    = (const float*)d_in[22];
  const float* bh_ln_w  = (const float*)d_in[23];
  const float* bh_ln_b  = (const float*)d_in[24];
  const float* sp_w     = (const float*)d_in[25];
  const float* sp_b     = (const float*)d_in[26];
  float* out = (float*)d_out;
  int E = in_sizes[0];
  (void)n_in; (void)out_size;

  const size_t MBf = (size_t)1 << 20;
  size_t per_gb = (size_t)18*MBf;
  size_t fixed  = (size_t)31*MBf;
  int gb = 1;
  if      (fixed + 16*per_gb <= ws_size) gb = 16;
  else if (fixed +  8*per_gb <= ws_size) gb = 8;
  else if (fixed +  4*per_gb <= ws_size) gb = 4;
  else if (fixed +  2*per_gb <= ws_size) gb = 2;

  char* wsb = (char*)d_ws;
  size_t o = 0;
  auto alloc = [&](size_t bytes)->char*{
    char* p = wsb + o; o = (o + bytes + 255) & ~(size_t)255; return p;
  };
  int*   cnt    = (int*)  alloc((size_t)NB*4);
  int*   sorted = (int*)  alloc((size_t)NB*EMAXC*4);
  float* tq     = (float*)alloc((size_t)64*256*4);
  float* qc     = (float*)alloc((size_t)64*256*4);
  float* qb     = (float*)alloc((size_t)2*256*4);
  u16*   Wt     = (u16*)  alloc((size_t)768*256*2);
  f16t*  WT     = (f16t*) alloc((size_t)WT_TOTAL*2);
  u16*   XLN    = (u16*)  alloc((size_t)gb*EMAXC*256*2);
  u8*    PT     = (u8*)   alloc((size_t)gb*512*EPAD);
  u8*    VT     = (u8*)   alloc((size_t)gb*256*EPAD);
  float* pnum   = (float*)alloc((size_t)NB*NHH*NCH2*2048*4);
  float* pden   = (float*)alloc((size_t)NB*NHH*NCH2*64*4);
  float* OC     = (float*)alloc((size_t)NB*64*256*4);
  float* lat    = (float*)alloc((size_t)NB*64*256*4);
  float* qkv    = (float*)alloc((size_t)NB*64*768*4);
  float* ffh    = (float*)alloc((size_t)NB*64*1024*4);

  // ---- prep ----
  k_zero<<<1, 64, 0, stream>>>(cnt);
  k_sort<<<(E + 1023)/1024, 256, 0, stream>>>(bidx, cnt, sorted, E);
  k_ln<<<16, 256, 0, stream>>>(lat_i, tq, 64);
  k_gemm<<<dim3(8,1), 256, 0, stream>>>(tq, Wq_c, qc, 64, 256, 256);
  k_qw<<<768, 256, 0, stream>>>(Wkv_c, qc, Wt);
  k_gemm<<<dim3(1,1), 256, 0, stream>>>(bh_query, bh_wq, qb, 2, 256, 256);
  k_wt<<<dim3(64,12), 256, 0, stream>>>(Wo_c, W1_c, W2_c, Wqkv_s, Wo_s, W1_s,
                                        W2_s, bh_wkv, WT);

  // ---- event cross-attention, runtime-sized batch groups ----
  for (int b0 = 0; b0 < NB; b0 += gb){
    k_a0<<<dim3(EMAXC/4, gb), 256, 0, stream>>>(sorted, cnt, nid, tbin, vval,
                                                ne, te, ve, XLN, b0);
    k_a<<<dim3(48, 14, gb), 256, 0, stream>>>(XLN, Wt, cnt, PT, VT, b0);
    k_b<<<dim3(NCH2, NHH, gb), 256, 0, stream>>>(PT, VT, cnt, pnum, pden, b0);
  }
  k_red<<<1024, 256, 0, stream>>>(pnum, pden, OC);

  // ---- latent chain (f16 MFMA GEMMs; LN fused as prologue where K=256) ----
  const int M = NB*NLAT;  // 1024
  k_init<<<M, 256, 0, stream>>>(lat_i, lat);
  k_gemm3<<<dim3(16,4,4), 256, 0, stream>>>(OC, WT + WTO_WOC, lat, nullptr, nullptr,
                                            M, 256, 256, 2, 0);
  k_gemm3<<<dim3(16,16,1), 256, 0, stream>>>(lat, WT + WTO_W1C, ffh, nullptr, nullptr,
                                             M, 256, 1024, 1, 1);
  k_gemm3<<<dim3(16,4,4), 256, 0, stream>>>(ffh, WT + WTO_W2C, lat, nullptr, nullptr,
                                            M, 1024, 256, 2, 0);

  for (int i = 0; i < 2; i++){
    k_gemm3<<<dim3(16,12,1), 256, 0, stream>>>(lat, WT + (i ? WTO_QKV1 : WTO_QKV0), qkv,
                                               nullptr, nullptr, M, 256, 768, 0, 1);
    k_attn<<<dim3(NB, NHH, 2), 256, 0, stream>>>(qkv, ffh);
    k_gemm3<<<dim3(16,4,4), 256, 0, stream>>>(ffh, WT + (i ? WTO_WOS1 : WTO_WOS0), lat,
                                              nullptr, nullptr, M, 256, 256, 2, 0);
    k_gemm3<<<dim3(16,16,1), 256, 0, stream>>>(lat, WT + (i ? WTO_W1S1 : WTO_W1S0), ffh,
                                               nullptr, nullptr, M, 256, 1024, 1, 1);
    k_gemm3<<<dim3(16,4,4), 256, 0, stream>>>(ffh, WT + (i ? WTO_W2S1 : WTO_W2S0), lat,
                                              nullptr, nullptr, M, 1024, 256, 2, 0);
  }

  // ---- heads ----
  k_gemm3<<<dim3(16,8,1), 256, 0, stream>>>(lat, WT + WTO_BH, qkv, bh_ln_w, bh_ln_b,
                                            M, 256, 512, 0, 1);
  k_heads<<<dim3(NB, 2), 256, 0, stream>>>(qb, qkv, bh_wo, lat, sp_w, sp_b, out);
}

// Round 12
// 555.554 us; speedup vs baseline: 1.0362x; 1.0057x over previous
//
#include <hip/hip_runtime.h>
#include <math.h>

#define NB 16
#define DIMD 256
#define NHH 8
#define NLAT 64
#define EMAXC 13568
#define NCH2 14            /* chunks of 1024 events (last partial) */
#define EPAD (NCH2*1024)   /* 14336: padded event stride (bytes for fp8 PT/VT) */

typedef float f32x4 __attribute__((ext_vector_type(4)));
typedef __bf16 bf16x8 __attribute__((ext_vector_type(8)));
typedef _Float16 f16t;
typedef __attribute__((ext_vector_type(8))) _Float16 f16x8;
typedef unsigned short u16;
typedef unsigned char u8;
typedef unsigned int u32;
typedef __attribute__((ext_vector_type(4))) unsigned int u32x4;
typedef __attribute__((ext_vector_type(8))) unsigned short u16x8;

/* f16 transposed-weight pool offsets (elements), layout [N][K] */
#define WTO_WOC   0u
#define WTO_W1C   65536u
#define WTO_W2C   327680u
#define WTO_QKV0  589824u
#define WTO_WOS0  786432u
#define WTO_W1S0  851968u
#define WTO_W2S0  1114112u
#define WTO_QKV1  1376256u
#define WTO_WOS1  1572864u
#define WTO_W1S1  1638400u
#define WTO_W2S1  1900544u
#define WTO_BH    2162688u
#define WT_TOTAL  2293760u

static __device__ __forceinline__ float wave_sum(float v){
#pragma unroll
  for (int off = 32; off > 0; off >>= 1) v += __shfl_xor(v, off, 64);
  return v;
}

static __device__ __forceinline__ u16 f2bf(float x){
  unsigned u = __float_as_uint(x);
  u += 0x7fffu + ((u >> 16) & 1u);
  return (u16)(u >> 16);
}

static __device__ __forceinline__ float gelu_tanh(float x){
  float x3 = x*x*x;
  return 0.5f*x*(1.0f + tanhf(0.7978845608028654f*(x + 0.044715f*x3)));
}

static __device__ __forceinline__ float dot4(float4 a, float4 b){
  return a.x*b.x + a.y*b.y + a.z*b.z + a.w*b.w;
}

// Async global->LDS DMA, 16B per lane. LDS dest is wave-uniform base + lane*16.
static __device__ __forceinline__ void gl_lds16(const void* g, void* l){
  __builtin_amdgcn_global_load_lds((const __attribute__((address_space(1))) void*)g,
                                   (__attribute__((address_space(3))) void*)l,
                                   16, 0, 0);
}

__global__ void k_zero(int* cnt){ if ((int)threadIdx.x < NB) cnt[threadIdx.x] = 0; }

// LDS-histogram bucket sort: 16 global atomics per 1024-event block.
__global__ void k_sort(const int* __restrict__ bidx, int* __restrict__ cnt,
                       int* __restrict__ sorted, int E){
  __shared__ int h[NB], base[NB];
  int t = threadIdx.x;
  if (t < NB) h[t] = 0;
  __syncthreads();
  int e0 = blockIdx.x*1024;
  int myb[4], myp[4];
#pragma unroll
  for (int i = 0; i < 4; i++){
    int e = e0 + i*256 + t;
    myb[i] = -1;
    if (e < E){ myb[i] = bidx[e]; myp[i] = atomicAdd(&h[myb[i]], 1); }
  }
  __syncthreads();
  if (t < NB) base[t] = atomicAdd(&cnt[t], h[t]);
  __syncthreads();
#pragma unroll
  for (int i = 0; i < 4; i++){
    if (myb[i] >= 0){
      int p = base[myb[i]] + myp[i];
      if (p < EMAXC) sorted[myb[i]*EMAXC + p] = e0 + i*256 + t;
    }
  }
}

// LayerNorm over rows of 256 (used only for lat_init prep).
__global__ void k_ln(const float* __restrict__ X, float* __restrict__ Y, int rows){
  int wave = threadIdx.x >> 6, lane = threadIdx.x & 63;
  int row = blockIdx.x*4 + wave;
  if (row >= rows) return;
  float4 x = ((const float4*)(X + (size_t)row*DIMD))[lane];
  float s = wave_sum(x.x + x.y + x.z + x.w);
  float m = s * (1.0f/DIMD);
  float d0 = x.x-m, d1 = x.y-m, d2 = x.z-m, d3 = x.w-m;
  float v = wave_sum(d0*d0 + d1*d1 + d2*d2 + d3*d3) * (1.0f/DIMD);
  float rs = rsqrtf(v + 1e-5f);
  ((float4*)(Y + (size_t)row*DIMD))[lane] = make_float4(d0*rs, d1*rs, d2*rs, d3*rs);
}

// lat[row] = lat_init[row % 64]  (row-broadcast residual init)
__global__ void k_init(const float* __restrict__ lat_i, float* __restrict__ lat){
  int r = blockIdx.x, t = threadIdx.x;
  lat[(size_t)r*DIMD + t] = lat_i[(size_t)(r & 63)*DIMD + t];
}

// Small prep GEMM (tiny M): C[M,N] = A[M,K] @ W[K,N]
__global__ __launch_bounds__(256) void k_gemm(
    const float* __restrict__ A, const float* __restrict__ W,
    float* __restrict__ C, int M, int K, int N){
  __shared__ float As[8][1024];
  int t = threadIdx.x;
  int row0 = blockIdx.x*8;
  int col = blockIdx.y*256 + t;
  int kq = K >> 2;
  for (int idx = t; idx < 8*kq; idx += 256){
    int r = idx / kq, kc = idx % kq;
    float4 v = make_float4(0.f,0.f,0.f,0.f);
    if (row0 + r < M) v = ((const float4*)(A + (size_t)(row0+r)*K))[kc];
    ((float4*)&As[r][0])[kc] = v;
  }
  __syncthreads();
  float acc[8] = {0,0,0,0,0,0,0,0};
  for (int k = 0; k < K; k += 4){
    float w0 = W[(size_t)(k+0)*N + col];
    float w1 = W[(size_t)(k+1)*N + col];
    float w2 = W[(size_t)(k+2)*N + col];
    float w3 = W[(size_t)(k+3)*N + col];
#pragma unroll
    for (int r = 0; r < 8; r++){
      float4 a = *((const float4*)&As[r][k]);
      acc[r] += a.x*w0 + a.y*w1 + a.z*w2 + a.w*w3;
    }
  }
#pragma unroll
  for (int r = 0; r < 8; r++){
    int row = row0 + r;
    if (row < M) C[(size_t)row*N + col] = acc[r];
  }
}

// Transpose all latent-chain weights to f16 [N][K] pool (runs once per launch).
// 64x64 LDS-tile transpose; grid (64, 12); out-of-range tiles return.
__global__ __launch_bounds__(256) void k_wt(
    const float* __restrict__ Wo_c, const float* __restrict__ W1_c,
    const float* __restrict__ W2_c, const float* __restrict__ Wqkv_s,
    const float* __restrict__ Wo_s, const float* __restrict__ W1_s,
    const float* __restrict__ W2_s, const float* __restrict__ bh_wkv,
    f16t* __restrict__ WT){
  const int mid = blockIdx.y;
  const float* src; int K, N; unsigned off;
  switch (mid){
    case 0:  src = Wo_c;            K = 256;  N = 256;  off = WTO_WOC;  break;
    case 1:  src = W1_c;            K = 256;  N = 1024; off = WTO_W1C;  break;
    case 2:  src = W2_c;            K = 1024; N = 256;  off = WTO_W2C;  break;
    case 3:  src = Wqkv_s;          K = 256;  N = 768;  off = WTO_QKV0; break;
    case 4:  src = Wo_s;            K = 256;  N = 256;  off = WTO_WOS0; break;
    case 5:  src = W1_s;            K = 256;  N = 1024; off = WTO_W1S0; break;
    case 6:  src = W2_s;            K = 1024; N = 256;  off = WTO_W2S0; break;
    case 7:  src = Wqkv_s + 196608; K = 256;  N = 768;  off = WTO_QKV1; break;
    case 8:  src = Wo_s + 65536;    K = 256;  N = 256;  off = WTO_WOS1; break;
    case 9:  src = W1_s + 262144;   K = 256;  N = 1024; off = WTO_W1S1; break;
    case 10: src = W2_s + 262144;   K = 1024; N = 256;  off = WTO_W2S1; break;
    default: src = bh_wkv;          K = 256;  N = 512;  off = WTO_BH;   break;
  }
  const int ntiles = N >> 6;
  const int tiles = ntiles * (K >> 6);
  if ((int)blockIdx.x >= tiles) return;
  const int kt = blockIdx.x / ntiles, nt = blockIdx.x % ntiles;
  __shared__ float tile[64][65];
  const int t = threadIdx.x;
  const int k0 = kt*64, n0 = nt*64;
#pragma unroll
  for (int i = 0; i < 16; i++){
    int k = i*4 + (t >> 6);
    tile[k][t & 63] = src[(size_t)(k0 + k)*N + n0 + (t & 63)];
  }
  __syncthreads();
  const int n = t >> 2, ks = (t & 3)*16;
  f16t* d = WT + off + (size_t)(n0 + n)*K + k0 + ks;
#pragma unroll
  for (int j = 0; j < 16; j++) d[j] = (f16t)tile[ks + j][n];
}

// MFMA latent-chain GEMM: C[M,N] (+)= A[M,K] @ W, W given as f16 WT[N][K].
// 64x64 tile, BK=64, 4 waves. A staged f32->f16 via LDS pitch-72; B via
// global_load_lds with 8-chunk XOR swizzle kc=c'^(r&7) (involution).
// modes: 0 plain / 1 gelu / 2 atomicAdd; K split over gridDim.z.
// do_ln (K==256, S==1): LayerNorm rows of A, optional affine lnw/lnb.
__global__ __launch_bounds__(256) void k_gemm3(
    const float* __restrict__ A, const f16t* __restrict__ WT, float* __restrict__ C,
    const float* __restrict__ lnw, const float* __restrict__ lnb,
    int M, int K, int N, int mode, int do_ln){
  __shared__ f16t Xs[64][72];
  __shared__ f16t Ws[64][64];
  __shared__ float lnm[64], lnr[64];
  const int t = threadIdx.x;
  const int wv = t >> 6, lane = t & 63;
  const int quad = lane >> 4, lane15 = lane & 15;
  const int m0 = blockIdx.x*64, n0 = blockIdx.y*64;
  const int Kc = K / gridDim.z;
  const int k0b = blockIdx.z*Kc;

  f32x4 acc[4];
#pragma unroll
  for (int j = 0; j < 4; j++) acc[j] = (f32x4){0.f,0.f,0.f,0.f};

  if (do_ln){
    int r = t >> 2, seg = (t & 3)*64;
    const float* Ar = A + (size_t)(m0 + r)*K + seg;
    float s = 0.f, s2 = 0.f;
#pragma unroll
    for (int j = 0; j < 64; j += 4){
      float4 v = *(const float4*)(Ar + j);
      s  += v.x + v.y + v.z + v.w;
      s2 += v.x*v.x + v.y*v.y + v.z*v.z + v.w*v.w;
    }
    s += __shfl_xor(s, 1, 64); s2 += __shfl_xor(s2, 1, 64);
    s += __shfl_xor(s, 2, 64); s2 += __shfl_xor(s2, 2, 64);
    if ((t & 3) == 0){
      float m = s*(1.0f/256.0f);
      float var = s2*(1.0f/256.0f) - m*m;
      lnm[r] = m; lnr[r] = rsqrtf(var + 1e-5f);
    }
    __syncthreads();
  }

  const int ar = t >> 2;                        // A stage row (0..63)
  const int as16 = (t & 3)*16;                  // A stage k-offset (16 f16)
  f16t* wdst0 = &Ws[0][0] + (size_t)(wv*64)*8;          // p=0 wave base
  f16t* wdst1 = &Ws[0][0] + (size_t)(256 + wv*64)*8;    // p=1 wave base

  for (int k0 = k0b; k0 < k0b + Kc; k0 += 64){
    __syncthreads();                  // prior frag reads done; buffers free
#pragma unroll
    for (int p = 0; p < 2; p++){
      int li = p*256 + t;
      int r = li >> 3;
      int kc = (li & 7) ^ (r & 7);
      gl_lds16(WT + (size_t)(n0 + r)*K + k0 + kc*8, p ? wdst1 : wdst0);
    }
    const float* Arow = A + (size_t)(m0 + ar)*K + k0 + as16;
    float4 v0 = *(const float4*)(Arow + 0);
    float4 v1 = *(const float4*)(Arow + 4);
    float4 v2 = *(const float4*)(Arow + 8);
    float4 v3 = *(const float4*)(Arow + 12);
    if (do_ln){
      float mm = lnm[ar], rs = lnr[ar];
      v0.x=(v0.x-mm)*rs; v0.y=(v0.y-mm)*rs; v0.z=(v0.z-mm)*rs; v0.w=(v0.w-mm)*rs;
      v1.x=(v1.x-mm)*rs; v1.y=(v1.y-mm)*rs; v1.z=(v1.z-mm)*rs; v1.w=(v1.w-mm)*rs;
      v2.x=(v2.x-mm)*rs; v2.y=(v2.y-mm)*rs; v2.z=(v2.z-mm)*rs; v2.w=(v2.w-mm)*rs;
      v3.x=(v3.x-mm)*rs; v3.y=(v3.y-mm)*rs; v3.z=(v3.z-mm)*rs; v3.w=(v3.w-mm)*rs;
      if (lnw){
        int k = k0 + as16;
        v0.x=v0.x*lnw[k+0]+lnb[k+0];  v0.y=v0.y*lnw[k+1]+lnb[k+1];
        v0.z=v0.z*lnw[k+2]+lnb[k+2];  v0.w=v0.w*lnw[k+3]+lnb[k+3];
        v1.x=v1.x*lnw[k+4]+lnb[k+4];  v1.y=v1.y*lnw[k+5]+lnb[k+5];
        v1.z=v1.z*lnw[k+6]+lnb[k+6];  v1.w=v1.w*lnw[k+7]+lnb[k+7];
        v2.x=v2.x*lnw[k+8]+lnb[k+8];  v2.y=v2.y*lnw[k+9]+lnb[k+9];
        v2.z=v2.z*lnw[k+10]+lnb[k+10]; v2.w=v2.w*lnw[k+11]+lnb[k+11];
        v3.x=v3.x*lnw[k+12]+lnb[k+12]; v3.y=v3.y*lnw[k+13]+lnb[k+13];
        v3.z=v3.z*lnw[k+14]+lnb[k+14]; v3.w=v3.w*lnw[k+15]+lnb[k+15];
      }
    }
    f16x8 h0 = {(f16t)v0.x,(f16t)v0.y,(f16t)v0.z,(f16t)v0.w,
                (f16t)v1.x,(f16t)v1.y,(f16t)v1.z,(f16t)v1.w};
    f16x8 h1 = {(f16t)v2.x,(f16t)v2.y,(f16t)v2.z,(f16t)v2.w,
                (f16t)v3.x,(f16t)v3.y,(f16t)v3.z,(f16t)v3.w};
    *(f16x8*)&Xs[ar][as16]     = h0;
    *(f16x8*)&Xs[ar][as16 + 8] = h1;
    __syncthreads();                  // drains vmcnt (DMA) + lgkm (ds_write)
#pragma unroll
    for (int ks = 0; ks < 2; ks++){
      f16x8 a = *(const f16x8*)&Xs[wv*16 + lane15][ks*32 + quad*8];
#pragma unroll
      for (int nt = 0; nt < 4; nt++){
        int ch = (ks*4 + quad) ^ (lane15 & 7);
        f16x8 bw = *(const f16x8*)&Ws[nt*16 + lane15][ch*8];
        acc[nt] = __builtin_amdgcn_mfma_f32_16x16x32_f16(a, bw, acc[nt], 0, 0, 0);
      }
    }
  }
#pragma unroll
  for (int nt = 0; nt < 4; nt++){
    int col = n0 + nt*16 + lane15;
#pragma unroll
    for (int j = 0; j < 4; j++){
      int row = m0 + wv*16 + quad*4 + j;
      float v = acc[nt][j];
      if (mode == 1) v = gelu_tanh(v);
      float* cp = C + (size_t)row*N + col;
      if (mode == 2) atomicAdd(cp, v);
      else *cp = v;
    }
  }
}

// Build Wt[768][256] bf16 (transposed, column-reordered)
__global__ void k_qw(const float* __restrict__ Wkv, const float* __restrict__ qc,
                     u16* __restrict__ Wt){
  int n = blockIdx.x;
  int k = threadIdx.x;
  float v;
  if (n < 256){
    v = Wkv[(size_t)k*512 + 256 + n];
  } else {
    int h = (n - 256) >> 6, l = (n - 256) & 63;
    const float* wk = Wkv + (size_t)k*512 + h*32;
    const float* qr = qc + (size_t)l*256 + h*32;
    float s = 0.f;
#pragma unroll
    for (int dd = 0; dd < 32; dd++) s += wk[dd]*qr[dd];
    v = s*0.1767766952966369f;
  }
  Wt[(size_t)n*256 + k] = f2bf(v);
}

// Gather+LN -> XLN bf16 (group-local), zero pad rows. One wave per event row.
__global__ void k_a0(const int* __restrict__ sorted, const int* __restrict__ cnt,
                     const int* __restrict__ nid, const int* __restrict__ tbin,
                     const int* __restrict__ vval,
                     const float* __restrict__ ne, const float* __restrict__ te,
                     const float* __restrict__ ve, u16* __restrict__ XLN, int b0){
  int wv = threadIdx.x >> 6, lane = threadIdx.x & 63;
  int e = blockIdx.x*4 + wv;
  int bg = blockIdx.y, b = b0 + bg;
  int cn = min(cnt[b], EMAXC);
  ushort4 pk; pk.x = 0; pk.y = 0; pk.z = 0; pk.w = 0;
  if (e < cn){
    int ev = sorted[b*EMAXC + e];
    float4 aa = ((const float4*)(ne + (size_t)nid[ev]*DIMD))[lane];
    float4 bb = ((const float4*)(te + (size_t)tbin[ev]*DIMD))[lane];
    float4 cc = ((const float4*)(ve + (size_t)vval[ev]*DIMD))[lane];
    float x0 = aa.x+bb.x+cc.x, x1 = aa.y+bb.y+cc.y;
    float x2 = aa.z+bb.z+cc.z, x3 = aa.w+bb.w+cc.w;
    float s = wave_sum(x0 + x1 + x2 + x3);
    float m = s*(1.0f/DIMD);
    x0 -= m; x1 -= m; x2 -= m; x3 -= m;
    float v = wave_sum(x0*x0 + x1*x1 + x2*x2 + x3*x3)*(1.0f/DIMD);
    float rs = rsqrtf(v + 1e-5f);
    pk.x = f2bf(x0*rs); pk.y = f2bf(x1*rs); pk.z = f2bf(x2*rs); pk.w = f2bf(x3*rs);
  }
  *(ushort4*)(XLN + ((size_t)bg*EMAXC + e)*DIMD + lane*4) = pk;
}

// Dense MFMA GEMM: [PT|VT] (transposed, fp8 e4m3) = exp?(XLN @ Wt^T).
// 128x128 tile, BK=32. X TRIPLE-buffered (L3 latency needs 2-phase flight),
// W DOUBLE-buffered (Wt is 384KB L2-resident, 1-phase cover suffices):
// LDS 48->40KB -> 4 blocks/CU (r12). Interleaved counted-vmcnt ladder
// (4 ops per X+W stage pair): it0=6, it1..5=4, it6=2, it7=0.
// Chunk XOR-swizzle (r4-verified, conflict-free). NO setprio (r6: -8.7%).
// GRID LAYOUT IS LOAD-BEARING (r10): nidx=x>>3, rtile=(y+ry0)*8+(x&7) keeps
// the 6 column-tile blocks sharing an X row-panel at blockIdx stride 8 = XCD
// round-robin period -> same per-XCD L2. ry0 splits the y-range across two
// dispatches (diagnostic: halves per-dispatch time, exposes mid-tier kernels
// in top-5) without touching the x mapping.
// grid (48, 7, gb) x2 launches (ry0=0,7).
__global__ __launch_bounds__(256) void k_a(
    const u16* __restrict__ XLN, const u16* __restrict__ Wt,
    const int* __restrict__ cnt, u8* __restrict__ PT, u8* __restrict__ VT,
    int b0, int ry0)
{
  __shared__ union ShMem {
    struct { u16 Xs[3][128][32]; u16 Ws[2][128][32]; } s;
    u8 Tr[128][136];
  } sh;
  const int t = threadIdx.x;
  const int wv = t >> 6, lane = t & 63;
  const int quad = lane >> 4, lane15 = lane & 15;
  const int nidx = blockIdx.x >> 3;
  const int rtile = (blockIdx.y + ry0)*8 + (blockIdx.x & 7);
  if (nidx >= 6 || rtile >= EMAXC/128) return;
  const int bg = blockIdx.z;
  const int b = b0 + bg;
  const int cn = min(cnt[b], EMAXC);
  const int row0 = rtile * 128;
  if (row0 >= cn) return;
  const int n0 = nidx * 128;
  const int eh = (wv >> 1) * 64, nh = (wv & 1) * 64;

  f32x4 acc[4][4];
#pragma unroll
  for (int i = 0; i < 4; i++)
#pragma unroll
    for (int j = 0; j < 4; j++) acc[i][j] = (f32x4){0.f,0.f,0.f,0.f};

  const u16* Xbase = XLN + ((size_t)bg*EMAXC + row0)*DIMD;
  const u16* Wbase = Wt + (size_t)n0*256;

  auto stageX = [&](int buf, int k0){
#pragma unroll
    for (int p = 0; p < 2; p++){
      int li = p*256 + wv*64 + lane;
      int r = li >> 2;
      int kc = (li & 3) ^ ((r >> 1) & 3);
      u16* xd = &sh.s.Xs[buf][0][0] + (size_t)(p*256 + wv*64)*8;
      gl_lds16(Xbase + (size_t)r*DIMD + k0 + kc*8, xd);
    }
  };
  auto stageW = [&](int buf, int k0){
#pragma unroll
    for (int p = 0; p < 2; p++){
      int li = p*256 + wv*64 + lane;
      int r = li >> 2;
      int kc = (li & 3) ^ ((r >> 1) & 3);
      u16* wd = &sh.s.Ws[buf][0][0] + (size_t)(p*256 + wv*64)*8;
      gl_lds16(Wbase + (size_t)r*256 + k0 + kc*8, wd);
    }
  };
  const int cswz = quad ^ ((lane15 >> 1) & 3);   // read-side chunk swizzle
  auto compute = [&](int bx, int bw_){
    bf16x8 a[4], bw[4];
#pragma unroll
    for (int mt = 0; mt < 4; mt++)
      a[mt] = *(const bf16x8*)&sh.s.Xs[bx][eh + mt*16 + lane15][cswz*8];
#pragma unroll
    for (int nt = 0; nt < 4; nt++)
      bw[nt] = *(const bf16x8*)&sh.s.Ws[bw_][nh + nt*16 + lane15][cswz*8];
#pragma unroll
    for (int mt = 0; mt < 4; mt++)
#pragma unroll
      for (int nt = 0; nt < 4; nt++)
        acc[mt][nt] = __builtin_amdgcn_mfma_f32_16x16x32_bf16(a[mt], bw[nt], acc[mt][nt], 0, 0, 0);
  };

  // Issue order: X0,W0,X1 | phase it: X(it+2),W(it+1).
  stageX(0, 0);
  stageW(0, 0);
  stageX(1, 32);
#pragma unroll
  for (int it = 0; it < 8; it++){
    __builtin_amdgcn_s_barrier();          // A: compute(it-1) done -> X buf (it+2)%3, W buf (it+1)%2 free
    if (it + 2 < 8) stageX((it + 2) % 3, (it + 2)*32);
    if (it + 1 < 8) stageW((it + 1) & 1, (it + 1)*32);
    if (it == 0)      asm volatile("s_waitcnt vmcnt(6)" ::: "memory");
    else if (it <= 5) asm volatile("s_waitcnt vmcnt(4)" ::: "memory");
    else if (it == 6) asm volatile("s_waitcnt vmcnt(2)" ::: "memory");
    else              asm volatile("s_waitcnt vmcnt(0)" ::: "memory");
    __builtin_amdgcn_s_barrier();          // B: everyone's X(it)+W(it) landed
    __builtin_amdgcn_sched_barrier(0);
    compute(it % 3, it & 1);
  }
  const int is_p = (n0 >= 256);
  __syncthreads();   // buffers dead from here; Tr takes over the storage
#pragma unroll
  for (int mt = 0; mt < 4; mt++){
    int e0 = eh + mt*16 + quad*4;
#pragma unroll
    for (int nt = 0; nt < 4; nt++){
      int c = nh + nt*16 + lane15;
      f32x4 v = acc[mt][nt];
      if (is_p){ v.x = __expf(v.x); v.y = __expf(v.y); v.z = __expf(v.z); v.w = __expf(v.w); }
      int p01 = __builtin_amdgcn_cvt_pk_fp8_f32(v.x, v.y, 0, false);
      int p23 = __builtin_amdgcn_cvt_pk_fp8_f32(v.z, v.w, 0, false);
      unsigned pk = ((unsigned)p01 & 0xFFFFu) | ((unsigned)p23 << 16);
      *(unsigned*)&sh.Tr[c][e0] = pk;
    }
  }
  __syncthreads();
  u8* dst = is_p ? (PT + ((size_t)bg*512 + (n0 - 256))*EPAD)
                 : (VT + ((size_t)bg*256 + n0)*EPAD);
  const int chalf = lane >> 5;
  const int e4 = (lane & 31) * 4;
#pragma unroll
  for (int i = 0; i < 16; i++){
    int c = wv*32 + i*2 + chalf;
    unsigned val = *(const unsigned*)&sh.Tr[c][e4];
    *(unsigned*)(dst + (size_t)c*EPAD + row0 + e4) = val;
  }
}

// PV reduction (fp8 MFMA): O^T[dh][l] = sum_e V[dh][e]*P[l][e]; den via ones-MFMA.
// grid (NCH2, 8, gb), 256 thr; each wave owns a 256-event K-slice.
// No main-loop barriers: waves run phase-independent -> s_setprio(1) around the
// MFMA cluster (T5 regime per m191 attn; null only on barrier-lockstep GEMMs).
__global__ __launch_bounds__(256) void k_b(
    const u8* __restrict__ PT, const u8* __restrict__ VT,
    const int* __restrict__ cnt, float* __restrict__ pnum, float* __restrict__ pden, int b0)
{
  __shared__ float red[4][2048];
  __shared__ float redd[4][64];
  const int t = threadIdx.x;
  const int wv = t >> 6, lane = t & 63;
  const int quad = lane >> 4, lane15 = lane & 15;
  const int chunk = blockIdx.x, h = blockIdx.y, bg = blockIdx.z;
  const int b = b0 + bg;
  const int cn = min(cnt[b], EMAXC);
  const u8* PTg = PT + ((size_t)bg*512 + h*64)*EPAD;
  const u8* VTg = VT + ((size_t)bg*256 + h*32)*EPAD;

  f32x4 acc[3][4];
#pragma unroll
  for (int i = 0; i < 3; i++)
#pragma unroll
    for (int j = 0; j < 4; j++) acc[i][j] = (f32x4){0.f,0.f,0.f,0.f};

  const long ones = 0x3838383838383838L;

  const int e0w = chunk*1024 + wv*256;
#pragma unroll 2
  for (int ks = 0; ks < 8; ks++){
    int eb = e0w + ks*32 + quad*8;
    long a0 = *(const long*)(VTg + (size_t)(lane15     )*EPAD + eb);
    long a1 = *(const long*)(VTg + (size_t)(16 + lane15)*EPAD + eb);
    long bp[4];
#pragma unroll
    for (int nt = 0; nt < 4; nt++){
      union { long v; u8 c[8]; } m;
      m.v = *(const long*)(PTg + (size_t)(nt*16 + lane15)*EPAD + eb);
      if (eb + 8 > cn){
#pragma unroll
        for (int j = 0; j < 8; j++) if (eb + j >= cn) m.c[j] = 0;
      }
      bp[nt] = m.v;
    }
    __builtin_amdgcn_s_setprio(1);
#pragma unroll
    for (int nt = 0; nt < 4; nt++){
      acc[0][nt] = __builtin_amdgcn_mfma_f32_16x16x32_fp8_fp8(a0, bp[nt], acc[0][nt], 0, 0, 0);
      acc[1][nt] = __builtin_amdgcn_mfma_f32_16x16x32_fp8_fp8(a1, bp[nt], acc[1][nt], 0, 0, 0);
      acc[2][nt] = __builtin_amdgcn_mfma_f32_16x16x32_fp8_fp8(ones, bp[nt], acc[2][nt], 0, 0, 0);
    }
    __builtin_amdgcn_s_setprio(0);
  }
#pragma unroll
  for (int mt = 0; mt < 2; mt++)
#pragma unroll
    for (int nt = 0; nt < 4; nt++){
      int l = nt*16 + lane15;
#pragma unroll
      for (int j = 0; j < 4; j++)
        red[wv][l*32 + mt*16 + quad*4 + j] = acc[mt][nt][j];
    }
  if (quad == 0){
#pragma unroll
    for (int nt = 0; nt < 4; nt++) redd[wv][nt*16 + lane15] = acc[2][nt][0];
  }
  __syncthreads();
  size_t obase = ((size_t)(b*NHH + h)*NCH2 + chunk);
  for (int i = t; i < 2048; i += 256)
    pnum[obase*2048 + i] = red[0][i] + red[1][i] + red[2][i] + red[3][i];
  if (t < 64)
    pden[obase*64 + t] = redd[0][t] + redd[1][t] + redd[2][t] + redd[3][t];
}

// Reduce partials over chunks, divide, write OC[b][l][h*32+dh]
__global__ void k_red(const float* __restrict__ pnum, const float* __restrict__ pden,
                      float* __restrict__ OC){
  int g = blockIdx.x*256 + threadIdx.x;
  int b = g >> 14, r = g & 16383;
  int h = r >> 11, idx = r & 2047;
  int l = idx >> 5, dh = idx & 31;
  float ns = 0.f, ds = 0.f;
  for (int c = 0; c < NCH2; c++){
    size_t ob = ((size_t)(b*NHH + h)*NCH2 + c);
    ns += pnum[ob*2048 + idx];
    ds += pden[ob*64 + l];
  }
  OC[((size_t)(b*NLAT + l))*DIMD + h*32 + dh] = ns/ds;
}

// Self-attention over 64 latents. grid (NB, NHH, 2): z halves the Q rows so
// 256 blocks cover all CUs. float4 loads; S via register-blocked dot4 with
// broadcast LDS reads; wave-parallel softmax (8 lanes/row, shfl_xor 1/2/4);
// PV float4 over V rows.
__global__ __launch_bounds__(256) void k_attn(const float* __restrict__ qkv,
                                              float* __restrict__ outp){
  int b = blockIdx.x, h = blockIdx.y;
  int r0 = blockIdx.z*32;
  __shared__ float qs[32][33], ks[64][33], vs[64][33];
  __shared__ float S[32][65];
  int t = threadIdx.x;
  {
    int l = t >> 3, d4 = (t & 7)*4;     // qs: 32 rows x 8 float4
    const float* qp = qkv + ((size_t)(b*NLAT + r0 + l))*768 + h*32 + d4;
    *(float4*)&qs[l][d4] = *(const float4*)qp;
  }
#pragma unroll
  for (int i = 0; i < 2; i++){
    int idx = i*256 + t;
    int l = idx >> 3, d4 = (idx & 7)*4; // ks/vs: 64 rows x 8 float4
    const float* kp = qkv + ((size_t)(b*NLAT + l))*768 + h*32 + 256 + d4;
    *(float4*)&ks[l][d4] = *(const float4*)kp;
    *(float4*)&vs[l][d4] = *(const float4*)(kp + 256);
  }
  __syncthreads();
  const float scale = 0.1767766952966369f;
  const int r = t >> 3, g8 = t & 7;
  float4 q0 = *(const float4*)&qs[r][0],  q1 = *(const float4*)&qs[r][4],
         q2 = *(const float4*)&qs[r][8],  q3 = *(const float4*)&qs[r][12],
         q4 = *(const float4*)&qs[r][16], q5 = *(const float4*)&qs[r][20],
         q6 = *(const float4*)&qs[r][24], q7 = *(const float4*)&qs[r][28];
  float sv[8];
#pragma unroll
  for (int j = 0; j < 8; j++){
    const float* kr = &ks[g8*8 + j][0];
    float s = dot4(q0, *(const float4*)(kr+0))  + dot4(q1, *(const float4*)(kr+4))
            + dot4(q2, *(const float4*)(kr+8))  + dot4(q3, *(const float4*)(kr+12))
            + dot4(q4, *(const float4*)(kr+16)) + dot4(q5, *(const float4*)(kr+20))
            + dot4(q6, *(const float4*)(kr+24)) + dot4(q7, *(const float4*)(kr+28));
    sv[j] = s*scale;
  }
  float mx = sv[0];
#pragma unroll
  for (int j = 1; j < 8; j++) mx = fmaxf(mx, sv[j]);
  mx = fmaxf(mx, __shfl_xor(mx, 1, 64));
  mx = fmaxf(mx, __shfl_xor(mx, 2, 64));
  mx = fmaxf(mx, __shfl_xor(mx, 4, 64));
  float sum = 0.f;
#pragma unroll
  for (int j = 0; j < 8; j++){ sv[j] = __expf(sv[j] - mx); sum += sv[j]; }
  sum += __shfl_xor(sum, 1, 64);
  sum += __shfl_xor(sum, 2, 64);
  sum += __shfl_xor(sum, 4, 64);
  float inv = 1.0f/sum;
#pragma unroll
  for (int j = 0; j < 8; j++) S[r][g8*8 + j] = sv[j]*inv;
  __syncthreads();
  const int d0 = g8*4;
  float4 o = make_float4(0.f, 0.f, 0.f, 0.f);
  for (int c = 0; c < 64; c++){
    float p = S[r][c];
    float4 v = *(const float4*)&vs[c][d0];
    o.x += p*v.x; o.y += p*v.y; o.z += p*v.z; o.w += p*v.w;
  }
  *(float4*)(outp + ((size_t)(b*NLAT + r0 + r))*DIMD + h*32 + d0) = o;
}

// Fused heads: blockIdx.y==0 -> behavior decoder attn+proj; ==1 -> spike logits.
// Disjoint output ranges (out[0..31] vs out[32..]), independent inputs.
__global__ void k_heads(const float* __restrict__ qb, const float* __restrict__ kv,
                        const float* __restrict__ wo, const float* __restrict__ lat,
                        const float* __restrict__ spw, const float* __restrict__ spb,
                        float* __restrict__ outp){
  int b = blockIdx.x;
  int t = threadIdx.x;
  if (blockIdx.y == 1){
    __shared__ float m[256];
    float s = 0.f;
    for (int l = 0; l < NLAT; l++) s += lat[((size_t)(b*NLAT + l))*DIMD + t];
    m[t] = s*(1.0f/NLAT);
    __syncthreads();
    if (t < 64){
      float o = spb[t];
      for (int c = 0; c < 256; c++) o += m[c]*spw[c*64 + t];
      outp[32 + b*64 + t] = o;
    }
    return;
  }
  __shared__ float S[16][65];
  __shared__ float O2[2][256];
  __shared__ float red[256];
  const float scale = 0.1767766952966369f;
#pragma unroll
  for (int i = 0; i < 4; i++){
    int idx = t + i*256;
    int row = idx >> 6, c = idx & 63;
    int iq = row >> 3, h = row & 7;
    const float* qp = qb + iq*DIMD + h*32;
    const float* kp = kv + ((size_t)(b*NLAT + c))*512 + h*32;
    float s = 0.f;
#pragma unroll
    for (int d = 0; d < 32; d++) s += qp[d]*kp[d];
    S[row][c] = s*scale;
  }
  __syncthreads();
  if (t < 16){
    float mx = -1e30f;
    for (int c = 0; c < 64; c++) mx = fmaxf(mx, S[t][c]);
    float sum = 0.f;
    for (int c = 0; c < 64; c++){ float p = expf(S[t][c] - mx); S[t][c] = p; sum += p; }
    float inv = 1.0f/sum;
    for (int c = 0; c < 64; c++) S[t][c] *= inv;
  }
  __syncthreads();
#pragma unroll
  for (int i = 0; i < 2; i++){
    int idx = t + i*256;
    int iq = idx >> 8, c2 = idx & 255;
    int h = c2 >> 5, d = c2 & 31;
    float o = 0.f;
    for (int c = 0; c < 64; c++)
      o += S[iq*8 + h][c]*kv[((size_t)(b*NLAT + c))*512 + 256 + h*32 + d];
    O2[iq][c2] = o;
  }
  __syncthreads();
  for (int iq = 0; iq < 2; iq++){
    red[t] = O2[iq][t]*wo[t];
    __syncthreads();
    for (int off = 128; off > 0; off >>= 1){
      if (t < off) red[t] += red[t + off];
      __syncthreads();
    }
    if (t == 0) outp[b*2 + iq] = red[0];
    __syncthreads();
  }
}

extern "C" void kernel_launch(void* const* d_in, const int* in_sizes, int n_in,
                              void* d_out, int out_size, void* d_ws, size_t ws_size,
                              hipStream_t stream){
  const int* nid      = (const int*)d_in[0];
  const int* tbin     = (const int*)d_in[1];
  const int* vval     = (const int*)d_in[2];
  const int* bidx     = (const int*)d_in[3];
  const float* ne     = (const float*)d_in[6];
  const float* te     = (const float*)d_in[7];
  const float* ve     = (const float*)d_in[8];
  const float* lat_i  = (const float*)d_in[9];
  const float* Wq_c   = (const float*)d_in[10];
  const float* Wkv_c  = (const float*)d_in[11];
  const float* Wo_c   = (const float*)d_in[12];
  const float* W1_c   = (const float*)d_in[13];
  const float* W2_c   = (const float*)d_in[14];
  const float* Wqkv_s = (const float*)d_in[15];
  const float* Wo_s   = (const float*)d_in[16];
  const float* W1_s   = (const float*)d_in[17];
  const float* W2_s   = (const float*)d_in[18];
  const float* bh_query = (const float*)d_in[19];
  const float* bh_wq    = (const float*)d_in[20];
  const float* bh_wkv   = (const float*)d_in[21];
  const float* bh_wo    = (const float*)d_in[22];
  const float* bh_ln_w  = (const float*)d_in[23];
  const float* bh_ln_b  = (const float*)d_in[24];
  const float* sp_w     = (const float*)d_in[25];
  const float* sp_b     = (const float*)d_in[26];
  float* out = (float*)d_out;
  int E = in_sizes[0];
  (void)n_in; (void)out_size;

  const size_t MBf = (size_t)1 << 20;
  size_t per_gb = (size_t)18*MBf;
  size_t fixed  = (size_t)31*MBf;
  int gb = 1;
  if      (fixed + 16*per_gb <= ws_size) gb = 16;
  else if (fixed +  8*per_gb <= ws_size) gb = 8;
  else if (fixed +  4*per_gb <= ws_size) gb = 4;
  else if (fixed +  2*per_gb <= ws_size) gb = 2;

  char* wsb = (char*)d_ws;
  size_t o = 0;
  auto alloc = [&](size_t bytes)->char*{
    char* p = wsb + o; o = (o + bytes + 255) & ~(size_t)255; return p;
  };
  int*   cnt    = (int*)  alloc((size_t)NB*4);
  int*   sorted = (int*)  alloc((size_t)NB*EMAXC*4);
  float* tq     = (float*)alloc((size_t)64*256*4);
  float* qc     = (float*)alloc((size_t)64*256*4);
  float* qb     = (float*)alloc((size_t)2*256*4);
  u16*   Wt     = (u16*)  alloc((size_t)768*256*2);
  f16t*  WT     = (f16t*) alloc((size_t)WT_TOTAL*2);
  u16*   XLN    = (u16*)  alloc((size_t)gb*EMAXC*256*2);
  u8*    PT     = (u8*)   alloc((size_t)gb*512*EPAD);
  u8*    VT     = (u8*)   alloc((size_t)gb*256*EPAD);
  float* pnum   = (float*)alloc((size_t)NB*NHH*NCH2*2048*4);
  float* pden   = (float*)alloc((size_t)NB*NHH*NCH2*64*4);
  float* OC     = (float*)alloc((size_t)NB*64*256*4);
  float* lat    = (float*)alloc((size_t)NB*64*256*4);
  float* qkv    = (float*)alloc((size_t)NB*64*768*4);
  float* ffh    = (float*)alloc((size_t)NB*64*1024*4);

  // ---- prep ----
  k_zero<<<1, 64, 0, stream>>>(cnt);
  k_sort<<<(E + 1023)/1024, 256, 0, stream>>>(bidx, cnt, sorted, E);
  k_ln<<<16, 256, 0, stream>>>(lat_i, tq, 64);
  k_gemm<<<dim3(8,1), 256, 0, stream>>>(tq, Wq_c, qc, 64, 256, 256);
  k_qw<<<768, 256, 0, stream>>>(Wkv_c, qc, Wt);
  k_gemm<<<dim3(1,1), 256, 0, stream>>>(bh_query, bh_wq, qb, 2, 256, 256);
  k_wt<<<dim3(64,12), 256, 0, stream>>>(Wo_c, W1_c, W2_c, Wqkv_s, Wo_s, W1_s,
                                        W2_s, bh_wkv, WT);

  // ---- event cross-attention, runtime-sized batch groups ----
  for (int b0 = 0; b0 < NB; b0 += gb){
    k_a0<<<dim3(EMAXC/4, gb), 256, 0, stream>>>(sorted, cnt, nid, tbin, vval,
                                                ne, te, ve, XLN, b0);
    k_a<<<dim3(48, 7, gb), 256, 0, stream>>>(XLN, Wt, cnt, PT, VT, b0, 0);
    k_a<<<dim3(48, 7, gb), 256, 0, stream>>>(XLN, Wt, cnt, PT, VT, b0, 7);
    k_b<<<dim3(NCH2, NHH, gb), 256, 0, stream>>>(PT, VT, cnt, pnum, pden, b0);
  }
  k_red<<<1024, 256, 0, stream>>>(pnum, pden, OC);

  // ---- latent chain (f16 MFMA GEMMs; LN fused as prologue where K=256) ----
  const int M = NB*NLAT;  // 1024
  k_init<<<M, 256, 0, stream>>>(lat_i, lat);
  k_gemm3<<<dim3(16,4,4), 256, 0, stream>>>(OC, WT + WTO_WOC, lat, nullptr, nullptr,
                                            M, 256, 256, 2, 0);
  k_gemm3<<<dim3(16,16,1), 256, 0, stream>>>(lat, WT + WTO_W1C, ffh, nullptr, nullptr,
                                             M, 256, 1024, 1, 1);
  k_gemm3<<<dim3(16,4,4), 256, 0, stream>>>(ffh, WT + WTO_W2C, lat, nullptr, nullptr,
                                            M, 1024, 256, 2, 0);

  for (int i = 0; i < 2; i++){
    k_gemm3<<<dim3(16,12,1), 256, 0, stream>>>(lat, WT + (i ? WTO_QKV1 : WTO_QKV0), qkv,
                                               nullptr, nullptr, M, 256, 768, 0, 1);
    k_attn<<<dim3(NB, NHH, 2), 256, 0, stream>>>(qkv, ffh);
    k_gemm3<<<dim3(16,4,4), 256, 0, stream>>>(ffh, WT + (i ? WTO_WOS1 : WTO_WOS0), lat,
                                              nullptr, nullptr, M, 256, 256, 2, 0);
    k_gemm3<<<dim3(16,16,1), 256, 0, stream>>>(lat, WT + (i ? WTO_W1S1 : WTO_W1S0), ffh,
                                               nullptr, nullptr, M, 256, 1024, 1, 1);
    k_gemm3<<<dim3(16,4,4), 256, 0, stream>>>(ffh, WT + (i ? WTO_W2S1 : WTO_W2S0), lat,
                                              nullptr, nullptr, M, 1024, 256, 2, 0);
  }

  // ---- heads ----
  k_gemm3<<<dim3(16,8,1), 256, 0, stream>>>(lat, WT + WTO_BH, qkv, bh_ln_w, bh_ln_b,
                                            M, 256, 512, 0, 1);
  k_heads<<<dim3(NB, 2), 256, 0, stream>>>(qb, qkv, bh_wo, lat, sp_w, sp_b, out);
}

// Round 13
// 528.035 us; speedup vs baseline: 1.0902x; 1.0521x over previous
//
#include <hip/hip_runtime.h>
#include <math.h>

#define NB 16
#define DIMD 256
#define NHH 8
#define NLAT 64
#define EMAXC 13568
#define NCH2 14            /* chunks of 1024 events (last partial) */
#define EPAD (NCH2*1024)   /* 14336: padded event stride (bytes for fp8 PT/VT) */

typedef float f32x4 __attribute__((ext_vector_type(4)));
typedef __bf16 bf16x8 __attribute__((ext_vector_type(8)));
typedef _Float16 f16t;
typedef __attribute__((ext_vector_type(8))) _Float16 f16x8;
typedef unsigned short u16;
typedef unsigned char u8;
typedef unsigned int u32;
typedef __attribute__((ext_vector_type(4))) unsigned int u32x4;
typedef __attribute__((ext_vector_type(8))) unsigned short u16x8;
typedef __attribute__((ext_vector_type(2))) long longx2;

/* f16 transposed-weight pool offsets (elements), layout [N][K] */
#define WTO_WOC   0u
#define WTO_W1C   65536u
#define WTO_W2C   327680u
#define WTO_QKV0  589824u
#define WTO_WOS0  786432u
#define WTO_W1S0  851968u
#define WTO_W2S0  1114112u
#define WTO_QKV1  1376256u
#define WTO_WOS1  1572864u
#define WTO_W1S1  1638400u
#define WTO_W2S1  1900544u
#define WTO_BH    2162688u
#define WT_TOTAL  2293760u

static __device__ __forceinline__ float wave_sum(float v){
#pragma unroll
  for (int off = 32; off > 0; off >>= 1) v += __shfl_xor(v, off, 64);
  return v;
}

static __device__ __forceinline__ u16 f2bf(float x){
  unsigned u = __float_as_uint(x);
  u += 0x7fffu + ((u >> 16) & 1u);
  return (u16)(u >> 16);
}

static __device__ __forceinline__ float gelu_tanh(float x){
  float x3 = x*x*x;
  return 0.5f*x*(1.0f + tanhf(0.7978845608028654f*(x + 0.044715f*x3)));
}

static __device__ __forceinline__ float dot4(float4 a, float4 b){
  return a.x*b.x + a.y*b.y + a.z*b.z + a.w*b.w;
}

// Async global->LDS DMA, 16B per lane. LDS dest is wave-uniform base + lane*16.
static __device__ __forceinline__ void gl_lds16(const void* g, void* l){
  __builtin_amdgcn_global_load_lds((const __attribute__((address_space(1))) void*)g,
                                   (__attribute__((address_space(3))) void*)l,
                                   16, 0, 0);
}

__global__ void k_zero(int* cnt){ if ((int)threadIdx.x < NB) cnt[threadIdx.x] = 0; }

// LDS-histogram bucket sort: 16 global atomics per 1024-event block.
__global__ void k_sort(const int* __restrict__ bidx, int* __restrict__ cnt,
                       int* __restrict__ sorted, int E){
  __shared__ int h[NB], base[NB];
  int t = threadIdx.x;
  if (t < NB) h[t] = 0;
  __syncthreads();
  int e0 = blockIdx.x*1024;
  int myb[4], myp[4];
#pragma unroll
  for (int i = 0; i < 4; i++){
    int e = e0 + i*256 + t;
    myb[i] = -1;
    if (e < E){ myb[i] = bidx[e]; myp[i] = atomicAdd(&h[myb[i]], 1); }
  }
  __syncthreads();
  if (t < NB) base[t] = atomicAdd(&cnt[t], h[t]);
  __syncthreads();
#pragma unroll
  for (int i = 0; i < 4; i++){
    if (myb[i] >= 0){
      int p = base[myb[i]] + myp[i];
      if (p < EMAXC) sorted[myb[i]*EMAXC + p] = e0 + i*256 + t;
    }
  }
}

// LayerNorm over rows of 256 (used only for lat_init prep).
__global__ void k_ln(const float* __restrict__ X, float* __restrict__ Y, int rows){
  int wave = threadIdx.x >> 6, lane = threadIdx.x & 63;
  int row = blockIdx.x*4 + wave;
  if (row >= rows) return;
  float4 x = ((const float4*)(X + (size_t)row*DIMD))[lane];
  float s = wave_sum(x.x + x.y + x.z + x.w);
  float m = s * (1.0f/DIMD);
  float d0 = x.x-m, d1 = x.y-m, d2 = x.z-m, d3 = x.w-m;
  float v = wave_sum(d0*d0 + d1*d1 + d2*d2 + d3*d3) * (1.0f/DIMD);
  float rs = rsqrtf(v + 1e-5f);
  ((float4*)(Y + (size_t)row*DIMD))[lane] = make_float4(d0*rs, d1*rs, d2*rs, d3*rs);
}

// lat[row] = lat_init[row % 64]  (row-broadcast residual init)
__global__ void k_init(const float* __restrict__ lat_i, float* __restrict__ lat){
  int r = blockIdx.x, t = threadIdx.x;
  lat[(size_t)r*DIMD + t] = lat_i[(size_t)(r & 63)*DIMD + t];
}

// Small prep GEMM (tiny M): C[M,N] = A[M,K] @ W[K,N]
__global__ __launch_bounds__(256) void k_gemm(
    const float* __restrict__ A, const float* __restrict__ W,
    float* __restrict__ C, int M, int K, int N){
  __shared__ float As[8][1024];
  int t = threadIdx.x;
  int row0 = blockIdx.x*8;
  int col = blockIdx.y*256 + t;
  int kq = K >> 2;
  for (int idx = t; idx < 8*kq; idx += 256){
    int r = idx / kq, kc = idx % kq;
    float4 v = make_float4(0.f,0.f,0.f,0.f);
    if (row0 + r < M) v = ((const float4*)(A + (size_t)(row0+r)*K))[kc];
    ((float4*)&As[r][0])[kc] = v;
  }
  __syncthreads();
  float acc[8] = {0,0,0,0,0,0,0,0};
  for (int k = 0; k < K; k += 4){
    float w0 = W[(size_t)(k+0)*N + col];
    float w1 = W[(size_t)(k+1)*N + col];
    float w2 = W[(size_t)(k+2)*N + col];
    float w3 = W[(size_t)(k+3)*N + col];
#pragma unroll
    for (int r = 0; r < 8; r++){
      float4 a = *((const float4*)&As[r][k]);
      acc[r] += a.x*w0 + a.y*w1 + a.z*w2 + a.w*w3;
    }
  }
#pragma unroll
  for (int r = 0; r < 8; r++){
    int row = row0 + r;
    if (row < M) C[(size_t)row*N + col] = acc[r];
  }
}

// Transpose all latent-chain weights to f16 [N][K] pool (runs once per launch).
// 64x64 LDS-tile transpose; grid (64, 12); out-of-range tiles return.
__global__ __launch_bounds__(256) void k_wt(
    const float* __restrict__ Wo_c, const float* __restrict__ W1_c,
    const float* __restrict__ W2_c, const float* __restrict__ Wqkv_s,
    const float* __restrict__ Wo_s, const float* __restrict__ W1_s,
    const float* __restrict__ W2_s, const float* __restrict__ bh_wkv,
    f16t* __restrict__ WT){
  const int mid = blockIdx.y;
  const float* src; int K, N; unsigned off;
  switch (mid){
    case 0:  src = Wo_c;            K = 256;  N = 256;  off = WTO_WOC;  break;
    case 1:  src = W1_c;            K = 256;  N = 1024; off = WTO_W1C;  break;
    case 2:  src = W2_c;            K = 1024; N = 256;  off = WTO_W2C;  break;
    case 3:  src = Wqkv_s;          K = 256;  N = 768;  off = WTO_QKV0; break;
    case 4:  src = Wo_s;            K = 256;  N = 256;  off = WTO_WOS0; break;
    case 5:  src = W1_s;            K = 256;  N = 1024; off = WTO_W1S0; break;
    case 6:  src = W2_s;            K = 1024; N = 256;  off = WTO_W2S0; break;
    case 7:  src = Wqkv_s + 196608; K = 256;  N = 768;  off = WTO_QKV1; break;
    case 8:  src = Wo_s + 65536;    K = 256;  N = 256;  off = WTO_WOS1; break;
    case 9:  src = W1_s + 262144;   K = 256;  N = 1024; off = WTO_W1S1; break;
    case 10: src = W2_s + 262144;   K = 1024; N = 256;  off = WTO_W2S1; break;
    default: src = bh_wkv;          K = 256;  N = 512;  off = WTO_BH;   break;
  }
  const int ntiles = N >> 6;
  const int tiles = ntiles * (K >> 6);
  if ((int)blockIdx.x >= tiles) return;
  const int kt = blockIdx.x / ntiles, nt = blockIdx.x % ntiles;
  __shared__ float tile[64][65];
  const int t = threadIdx.x;
  const int k0 = kt*64, n0 = nt*64;
#pragma unroll
  for (int i = 0; i < 16; i++){
    int k = i*4 + (t >> 6);
    tile[k][t & 63] = src[(size_t)(k0 + k)*N + n0 + (t & 63)];
  }
  __syncthreads();
  const int n = t >> 2, ks = (t & 3)*16;
  f16t* d = WT + off + (size_t)(n0 + n)*K + k0 + ks;
#pragma unroll
  for (int j = 0; j < 16; j++) d[j] = (f16t)tile[ks + j][n];
}

// MFMA latent-chain GEMM: C[M,N] (+)= A[M,K] @ W, W given as f16 WT[N][K].
// 64x64 tile, BK=64, 4 waves. A staged f32->f16 via LDS pitch-72; B via
// global_load_lds with 8-chunk XOR swizzle kc=c'^(r&7) (involution).
// modes: 0 plain / 1 gelu / 2 atomicAdd; K split over gridDim.z.
// do_ln (K==256, S==1): LayerNorm rows of A, optional affine lnw/lnb.
__global__ __launch_bounds__(256) void k_gemm3(
    const float* __restrict__ A, const f16t* __restrict__ WT, float* __restrict__ C,
    const float* __restrict__ lnw, const float* __restrict__ lnb,
    int M, int K, int N, int mode, int do_ln){
  __shared__ f16t Xs[64][72];
  __shared__ f16t Ws[64][64];
  __shared__ float lnm[64], lnr[64];
  const int t = threadIdx.x;
  const int wv = t >> 6, lane = t & 63;
  const int quad = lane >> 4, lane15 = lane & 15;
  const int m0 = blockIdx.x*64, n0 = blockIdx.y*64;
  const int Kc = K / gridDim.z;
  const int k0b = blockIdx.z*Kc;

  f32x4 acc[4];
#pragma unroll
  for (int j = 0; j < 4; j++) acc[j] = (f32x4){0.f,0.f,0.f,0.f};

  if (do_ln){
    int r = t >> 2, seg = (t & 3)*64;
    const float* Ar = A + (size_t)(m0 + r)*K + seg;
    float s = 0.f, s2 = 0.f;
#pragma unroll
    for (int j = 0; j < 64; j += 4){
      float4 v = *(const float4*)(Ar + j);
      s  += v.x + v.y + v.z + v.w;
      s2 += v.x*v.x + v.y*v.y + v.z*v.z + v.w*v.w;
    }
    s += __shfl_xor(s, 1, 64); s2 += __shfl_xor(s2, 1, 64);
    s += __shfl_xor(s, 2, 64); s2 += __shfl_xor(s2, 2, 64);
    if ((t & 3) == 0){
      float m = s*(1.0f/256.0f);
      float var = s2*(1.0f/256.0f) - m*m;
      lnm[r] = m; lnr[r] = rsqrtf(var + 1e-5f);
    }
    __syncthreads();
  }

  const int ar = t >> 2;                        // A stage row (0..63)
  const int as16 = (t & 3)*16;                  // A stage k-offset (16 f16)
  f16t* wdst0 = &Ws[0][0] + (size_t)(wv*64)*8;          // p=0 wave base
  f16t* wdst1 = &Ws[0][0] + (size_t)(256 + wv*64)*8;    // p=1 wave base

  for (int k0 = k0b; k0 < k0b + Kc; k0 += 64){
    __syncthreads();                  // prior frag reads done; buffers free
#pragma unroll
    for (int p = 0; p < 2; p++){
      int li = p*256 + t;
      int r = li >> 3;
      int kc = (li & 7) ^ (r & 7);
      gl_lds16(WT + (size_t)(n0 + r)*K + k0 + kc*8, p ? wdst1 : wdst0);
    }
    const float* Arow = A + (size_t)(m0 + ar)*K + k0 + as16;
    float4 v0 = *(const float4*)(Arow + 0);
    float4 v1 = *(const float4*)(Arow + 4);
    float4 v2 = *(const float4*)(Arow + 8);
    float4 v3 = *(const float4*)(Arow + 12);
    if (do_ln){
      float mm = lnm[ar], rs = lnr[ar];
      v0.x=(v0.x-mm)*rs; v0.y=(v0.y-mm)*rs; v0.z=(v0.z-mm)*rs; v0.w=(v0.w-mm)*rs;
      v1.x=(v1.x-mm)*rs; v1.y=(v1.y-mm)*rs; v1.z=(v1.z-mm)*rs; v1.w=(v1.w-mm)*rs;
      v2.x=(v2.x-mm)*rs; v2.y=(v2.y-mm)*rs; v2.z=(v2.z-mm)*rs; v2.w=(v2.w-mm)*rs;
      v3.x=(v3.x-mm)*rs; v3.y=(v3.y-mm)*rs; v3.z=(v3.z-mm)*rs; v3.w=(v3.w-mm)*rs;
      if (lnw){
        int k = k0 + as16;
        v0.x=v0.x*lnw[k+0]+lnb[k+0];  v0.y=v0.y*lnw[k+1]+lnb[k+1];
        v0.z=v0.z*lnw[k+2]+lnb[k+2];  v0.w=v0.w*lnw[k+3]+lnb[k+3];
        v1.x=v1.x*lnw[k+4]+lnb[k+4];  v1.y=v1.y*lnw[k+5]+lnb[k+5];
        v1.z=v1.z*lnw[k+6]+lnb[k+6];  v1.w=v1.w*lnw[k+7]+lnb[k+7];
        v2.x=v2.x*lnw[k+8]+lnb[k+8];  v2.y=v2.y*lnw[k+9]+lnb[k+9];
        v2.z=v2.z*lnw[k+10]+lnb[k+10]; v2.w=v2.w*lnw[k+11]+lnb[k+11];
        v3.x=v3.x*lnw[k+12]+lnb[k+12]; v3.y=v3.y*lnw[k+13]+lnb[k+13];
        v3.z=v3.z*lnw[k+14]+lnb[k+14]; v3.w=v3.w*lnw[k+15]+lnb[k+15];
      }
    }
    f16x8 h0 = {(f16t)v0.x,(f16t)v0.y,(f16t)v0.z,(f16t)v0.w,
                (f16t)v1.x,(f16t)v1.y,(f16t)v1.z,(f16t)v1.w};
    f16x8 h1 = {(f16t)v2.x,(f16t)v2.y,(f16t)v2.z,(f16t)v2.w,
                (f16t)v3.x,(f16t)v3.y,(f16t)v3.z,(f16t)v3.w};
    *(f16x8*)&Xs[ar][as16]     = h0;
    *(f16x8*)&Xs[ar][as16 + 8] = h1;
    __syncthreads();                  // drains vmcnt (DMA) + lgkm (ds_write)
#pragma unroll
    for (int ks = 0; ks < 2; ks++){
      f16x8 a = *(const f16x8*)&Xs[wv*16 + lane15][ks*32 + quad*8];
#pragma unroll
      for (int nt = 0; nt < 4; nt++){
        int ch = (ks*4 + quad) ^ (lane15 & 7);
        f16x8 bw = *(const f16x8*)&Ws[nt*16 + lane15][ch*8];
        acc[nt] = __builtin_amdgcn_mfma_f32_16x16x32_f16(a, bw, acc[nt], 0, 0, 0);
      }
    }
  }
#pragma unroll
  for (int nt = 0; nt < 4; nt++){
    int col = n0 + nt*16 + lane15;
#pragma unroll
    for (int j = 0; j < 4; j++){
      int row = m0 + wv*16 + quad*4 + j;
      float v = acc[nt][j];
      if (mode == 1) v = gelu_tanh(v);
      float* cp = C + (size_t)row*N + col;
      if (mode == 2) atomicAdd(cp, v);
      else *cp = v;
    }
  }
}

// Build Wt[768][256] bf16 (transposed, column-reordered)
__global__ void k_qw(const float* __restrict__ Wkv, const float* __restrict__ qc,
                     u16* __restrict__ Wt){
  int n = blockIdx.x;
  int k = threadIdx.x;
  float v;
  if (n < 256){
    v = Wkv[(size_t)k*512 + 256 + n];
  } else {
    int h = (n - 256) >> 6, l = (n - 256) & 63;
    const float* wk = Wkv + (size_t)k*512 + h*32;
    const float* qr = qc + (size_t)l*256 + h*32;
    float s = 0.f;
#pragma unroll
    for (int dd = 0; dd < 32; dd++) s += wk[dd]*qr[dd];
    v = s*0.1767766952966369f;
  }
  Wt[(size_t)n*256 + k] = f2bf(v);
}

// Gather+LN -> XLN bf16 (group-local), zero pad rows. One wave per event row.
__global__ void k_a0(const int* __restrict__ sorted, const int* __restrict__ cnt,
                     const int* __restrict__ nid, const int* __restrict__ tbin,
                     const int* __restrict__ vval,
                     const float* __restrict__ ne, const float* __restrict__ te,
                     const float* __restrict__ ve, u16* __restrict__ XLN, int b0){
  int wv = threadIdx.x >> 6, lane = threadIdx.x & 63;
  int e = blockIdx.x*4 + wv;
  int bg = blockIdx.y, b = b0 + bg;
  int cn = min(cnt[b], EMAXC);
  ushort4 pk; pk.x = 0; pk.y = 0; pk.z = 0; pk.w = 0;
  if (e < cn){
    int ev = sorted[b*EMAXC + e];
    float4 aa = ((const float4*)(ne + (size_t)nid[ev]*DIMD))[lane];
    float4 bb = ((const float4*)(te + (size_t)tbin[ev]*DIMD))[lane];
    float4 cc = ((const float4*)(ve + (size_t)vval[ev]*DIMD))[lane];
    float x0 = aa.x+bb.x+cc.x, x1 = aa.y+bb.y+cc.y;
    float x2 = aa.z+bb.z+cc.z, x3 = aa.w+bb.w+cc.w;
    float s = wave_sum(x0 + x1 + x2 + x3);
    float m = s*(1.0f/DIMD);
    x0 -= m; x1 -= m; x2 -= m; x3 -= m;
    float v = wave_sum(x0*x0 + x1*x1 + x2*x2 + x3*x3)*(1.0f/DIMD);
    float rs = rsqrtf(v + 1e-5f);
    pk.x = f2bf(x0*rs); pk.y = f2bf(x1*rs); pk.z = f2bf(x2*rs); pk.w = f2bf(x3*rs);
  }
  *(ushort4*)(XLN + ((size_t)bg*EMAXC + e)*DIMD + lane*4) = pk;
}

// Dense MFMA GEMM: [PT|VT] (transposed, fp8 e4m3) = exp?(XLN @ Wt^T).
// 128x128 tile, BK=32. X TRIPLE-buffered, W DOUBLE-buffered (Wt is 384KB
// L2-resident, 1-phase cover suffices): LDS 40KB -> 4 blocks/CU (r12).
// Interleaved counted-vmcnt ladder: it0=6, it1..5=4, it6=2, it7=0.
// Chunk XOR-swizzle (r4-verified, conflict-free). NO setprio (r6: -8.7%).
// GRID LAYOUT IS LOAD-BEARING (r10): nidx=x>>3, rtile=(y+ry0)*8+(x&7) keeps
// the 6 column-tile blocks sharing an X row-panel at blockIdx stride 8 = XCD
// round-robin period -> same per-XCD L2. Flat grid cost 6x FETCH (r10).
// Single dispatch (r13): grid (48, 14, gb), ry0=0.
__global__ __launch_bounds__(256) void k_a(
    const u16* __restrict__ XLN, const u16* __restrict__ Wt,
    const int* __restrict__ cnt, u8* __restrict__ PT, u8* __restrict__ VT,
    int b0, int ry0)
{
  __shared__ union ShMem {
    struct { u16 Xs[3][128][32]; u16 Ws[2][128][32]; } s;
    u8 Tr[128][136];
  } sh;
  const int t = threadIdx.x;
  const int wv = t >> 6, lane = t & 63;
  const int quad = lane >> 4, lane15 = lane & 15;
  const int nidx = blockIdx.x >> 3;
  const int rtile = (blockIdx.y + ry0)*8 + (blockIdx.x & 7);
  if (nidx >= 6 || rtile >= EMAXC/128) return;
  const int bg = blockIdx.z;
  const int b = b0 + bg;
  const int cn = min(cnt[b], EMAXC);
  const int row0 = rtile * 128;
  if (row0 >= cn) return;
  const int n0 = nidx * 128;
  const int eh = (wv >> 1) * 64, nh = (wv & 1) * 64;

  f32x4 acc[4][4];
#pragma unroll
  for (int i = 0; i < 4; i++)
#pragma unroll
    for (int j = 0; j < 4; j++) acc[i][j] = (f32x4){0.f,0.f,0.f,0.f};

  const u16* Xbase = XLN + ((size_t)bg*EMAXC + row0)*DIMD;
  const u16* Wbase = Wt + (size_t)n0*256;

  auto stageX = [&](int buf, int k0){
#pragma unroll
    for (int p = 0; p < 2; p++){
      int li = p*256 + wv*64 + lane;
      int r = li >> 2;
      int kc = (li & 3) ^ ((r >> 1) & 3);
      u16* xd = &sh.s.Xs[buf][0][0] + (size_t)(p*256 + wv*64)*8;
      gl_lds16(Xbase + (size_t)r*DIMD + k0 + kc*8, xd);
    }
  };
  auto stageW = [&](int buf, int k0){
#pragma unroll
    for (int p = 0; p < 2; p++){
      int li = p*256 + wv*64 + lane;
      int r = li >> 2;
      int kc = (li & 3) ^ ((r >> 1) & 3);
      u16* wd = &sh.s.Ws[buf][0][0] + (size_t)(p*256 + wv*64)*8;
      gl_lds16(Wbase + (size_t)r*256 + k0 + kc*8, wd);
    }
  };
  const int cswz = quad ^ ((lane15 >> 1) & 3);   // read-side chunk swizzle
  auto compute = [&](int bx, int bw_){
    bf16x8 a[4], bw[4];
#pragma unroll
    for (int mt = 0; mt < 4; mt++)
      a[mt] = *(const bf16x8*)&sh.s.Xs[bx][eh + mt*16 + lane15][cswz*8];
#pragma unroll
    for (int nt = 0; nt < 4; nt++)
      bw[nt] = *(const bf16x8*)&sh.s.Ws[bw_][nh + nt*16 + lane15][cswz*8];
#pragma unroll
    for (int mt = 0; mt < 4; mt++)
#pragma unroll
      for (int nt = 0; nt < 4; nt++)
        acc[mt][nt] = __builtin_amdgcn_mfma_f32_16x16x32_bf16(a[mt], bw[nt], acc[mt][nt], 0, 0, 0);
  };

  // Issue order: X0,W0,X1 | phase it: X(it+2),W(it+1).
  stageX(0, 0);
  stageW(0, 0);
  stageX(1, 32);
#pragma unroll
  for (int it = 0; it < 8; it++){
    __builtin_amdgcn_s_barrier();          // A: compute(it-1) done -> X buf (it+2)%3, W buf (it+1)%2 free
    if (it + 2 < 8) stageX((it + 2) % 3, (it + 2)*32);
    if (it + 1 < 8) stageW((it + 1) & 1, (it + 1)*32);
    if (it == 0)      asm volatile("s_waitcnt vmcnt(6)" ::: "memory");
    else if (it <= 5) asm volatile("s_waitcnt vmcnt(4)" ::: "memory");
    else if (it == 6) asm volatile("s_waitcnt vmcnt(2)" ::: "memory");
    else              asm volatile("s_waitcnt vmcnt(0)" ::: "memory");
    __builtin_amdgcn_s_barrier();          // B: everyone's X(it)+W(it) landed
    __builtin_amdgcn_sched_barrier(0);
    compute(it % 3, it & 1);
  }
  const int is_p = (n0 >= 256);
  __syncthreads();   // buffers dead from here; Tr takes over the storage
#pragma unroll
  for (int mt = 0; mt < 4; mt++){
    int e0 = eh + mt*16 + quad*4;
#pragma unroll
    for (int nt = 0; nt < 4; nt++){
      int c = nh + nt*16 + lane15;
      f32x4 v = acc[mt][nt];
      if (is_p){ v.x = __expf(v.x); v.y = __expf(v.y); v.z = __expf(v.z); v.w = __expf(v.w); }
      int p01 = __builtin_amdgcn_cvt_pk_fp8_f32(v.x, v.y, 0, false);
      int p23 = __builtin_amdgcn_cvt_pk_fp8_f32(v.z, v.w, 0, false);
      unsigned pk = ((unsigned)p01 & 0xFFFFu) | ((unsigned)p23 << 16);
      *(unsigned*)&sh.Tr[c][e0] = pk;
    }
  }
  __syncthreads();
  u8* dst = is_p ? (PT + ((size_t)bg*512 + (n0 - 256))*EPAD)
                 : (VT + ((size_t)bg*256 + n0)*EPAD);
  const int chalf = lane >> 5;
  const int e4 = (lane & 31) * 4;
#pragma unroll
  for (int i = 0; i < 16; i++){
    int c = wv*32 + i*2 + chalf;
    unsigned val = *(const unsigned*)&sh.Tr[c][e4];
    *(unsigned*)(dst + (size_t)c*EPAD + row0 + e4) = val;
  }
}

// PV reduction (fp8 MFMA): O^T[dh][l] = sum_e V[dh][e]*P[l][e]; den via ones-MFMA.
// grid (NCH2, 8, gb), 256 thr; each wave owns a 256-event K-slice.
// r13: 16B-per-lane loads (longx2) — PV/den are event-order-invariant, so the
// lo/hi 8B halves feed two MFMA K-blocks; halves VMEM instruction count
// (was 6x8B loads per 12 MFMAs; now 6x16B per 24). Tail mask on P only.
// No main-loop barriers: phase-diverse waves -> s_setprio around MFMA (T5).
__global__ __launch_bounds__(256) void k_b(
    const u8* __restrict__ PT, const u8* __restrict__ VT,
    const int* __restrict__ cnt, float* __restrict__ pnum, float* __restrict__ pden, int b0)
{
  __shared__ float red[4][2048];
  __shared__ float redd[4][64];
  const int t = threadIdx.x;
  const int wv = t >> 6, lane = t & 63;
  const int quad = lane >> 4, lane15 = lane & 15;
  const int chunk = blockIdx.x, h = blockIdx.y, bg = blockIdx.z;
  const int b = b0 + bg;
  const int cn = min(cnt[b], EMAXC);
  const u8* PTg = PT + ((size_t)bg*512 + h*64)*EPAD;
  const u8* VTg = VT + ((size_t)bg*256 + h*32)*EPAD;

  f32x4 acc[3][4];
#pragma unroll
  for (int i = 0; i < 3; i++)
#pragma unroll
    for (int j = 0; j < 4; j++) acc[i][j] = (f32x4){0.f,0.f,0.f,0.f};

  const long ones = 0x3838383838383838L;

  const int e0w = chunk*1024 + wv*256;
#pragma unroll
  for (int ks = 0; ks < 4; ks++){
    int eb = e0w + ks*64 + quad*16;
    longx2 a0 = *(const longx2*)(VTg + (size_t)(lane15     )*EPAD + eb);
    longx2 a1 = *(const longx2*)(VTg + (size_t)(16 + lane15)*EPAD + eb);
    longx2 bp[4];
#pragma unroll
    for (int nt = 0; nt < 4; nt++){
      union { longx2 v; u8 c[16]; } m;
      m.v = *(const longx2*)(PTg + (size_t)(nt*16 + lane15)*EPAD + eb);
      if (eb + 16 > cn){
#pragma unroll
        for (int j = 0; j < 16; j++) if (eb + j >= cn) m.c[j] = 0;
      }
      bp[nt] = m.v;
    }
    __builtin_amdgcn_s_setprio(1);
#pragma unroll
    for (int nt = 0; nt < 4; nt++){
      acc[0][nt] = __builtin_amdgcn_mfma_f32_16x16x32_fp8_fp8(a0[0], bp[nt][0], acc[0][nt], 0, 0, 0);
      acc[1][nt] = __builtin_amdgcn_mfma_f32_16x16x32_fp8_fp8(a1[0], bp[nt][0], acc[1][nt], 0, 0, 0);
      acc[2][nt] = __builtin_amdgcn_mfma_f32_16x16x32_fp8_fp8(ones,  bp[nt][0], acc[2][nt], 0, 0, 0);
    }
#pragma unroll
    for (int nt = 0; nt < 4; nt++){
      acc[0][nt] = __builtin_amdgcn_mfma_f32_16x16x32_fp8_fp8(a0[1], bp[nt][1], acc[0][nt], 0, 0, 0);
      acc[1][nt] = __builtin_amdgcn_mfma_f32_16x16x32_fp8_fp8(a1[1], bp[nt][1], acc[1][nt], 0, 0, 0);
      acc[2][nt] = __builtin_amdgcn_mfma_f32_16x16x32_fp8_fp8(ones,  bp[nt][1], acc[2][nt], 0, 0, 0);
    }
    __builtin_amdgcn_s_setprio(0);
  }
#pragma unroll
  for (int mt = 0; mt < 2; mt++)
#pragma unroll
    for (int nt = 0; nt < 4; nt++){
      int l = nt*16 + lane15;
#pragma unroll
      for (int j = 0; j < 4; j++)
        red[wv][l*32 + mt*16 + quad*4 + j] = acc[mt][nt][j];
    }
  if (quad == 0){
#pragma unroll
    for (int nt = 0; nt < 4; nt++) redd[wv][nt*16 + lane15] = acc[2][nt][0];
  }
  __syncthreads();
  size_t obase = ((size_t)(b*NHH + h)*NCH2 + chunk);
  for (int i = t; i < 2048; i += 256)
    pnum[obase*2048 + i] = red[0][i] + red[1][i] + red[2][i] + red[3][i];
  if (t < 64)
    pden[obase*64 + t] = redd[0][t] + redd[1][t] + redd[2][t] + redd[3][t];
}

// Reduce partials over chunks, divide, write OC[b][l][h*32+dh]
__global__ void k_red(const float* __restrict__ pnum, const float* __restrict__ pden,
                      float* __restrict__ OC){
  int g = blockIdx.x*256 + threadIdx.x;
  int b = g >> 14, r = g & 16383;
  int h = r >> 11, idx = r & 2047;
  int l = idx >> 5, dh = idx & 31;
  float ns = 0.f, ds = 0.f;
  for (int c = 0; c < NCH2; c++){
    size_t ob = ((size_t)(b*NHH + h)*NCH2 + c);
    ns += pnum[ob*2048 + idx];
    ds += pden[ob*64 + l];
  }
  OC[((size_t)(b*NLAT + l))*DIMD + h*32 + dh] = ns/ds;
}

// Self-attention over 64 latents. grid (NB, NHH, 2): z halves the Q rows so
// 256 blocks cover all CUs. float4 loads; S via register-blocked dot4 with
// broadcast LDS reads; wave-parallel softmax (8 lanes/row, shfl_xor 1/2/4);
// PV float4 over V rows.
__global__ __launch_bounds__(256) void k_attn(const float* __restrict__ qkv,
                                              float* __restrict__ outp){
  int b = blockIdx.x, h = blockIdx.y;
  int r0 = blockIdx.z*32;
  __shared__ float qs[32][33], ks[64][33], vs[64][33];
  __shared__ float S[32][65];
  int t = threadIdx.x;
  {
    int l = t >> 3, d4 = (t & 7)*4;     // qs: 32 rows x 8 float4
    const float* qp = qkv + ((size_t)(b*NLAT + r0 + l))*768 + h*32 + d4;
    *(float4*)&qs[l][d4] = *(const float4*)qp;
  }
#pragma unroll
  for (int i = 0; i < 2; i++){
    int idx = i*256 + t;
    int l = idx >> 3, d4 = (idx & 7)*4; // ks/vs: 64 rows x 8 float4
    const float* kp = qkv + ((size_t)(b*NLAT + l))*768 + h*32 + 256 + d4;
    *(float4*)&ks[l][d4] = *(const float4*)kp;
    *(float4*)&vs[l][d4] = *(const float4*)(kp + 256);
  }
  __syncthreads();
  const float scale = 0.1767766952966369f;
  const int r = t >> 3, g8 = t & 7;
  float4 q0 = *(const float4*)&qs[r][0],  q1 = *(const float4*)&qs[r][4],
         q2 = *(const float4*)&qs[r][8],  q3 = *(const float4*)&qs[r][12],
         q4 = *(const float4*)&qs[r][16], q5 = *(const float4*)&qs[r][20],
         q6 = *(const float4*)&qs[r][24], q7 = *(const float4*)&qs[r][28];
  float sv[8];
#pragma unroll
  for (int j = 0; j < 8; j++){
    const float* kr = &ks[g8*8 + j][0];
    float s = dot4(q0, *(const float4*)(kr+0))  + dot4(q1, *(const float4*)(kr+4))
            + dot4(q2, *(const float4*)(kr+8))  + dot4(q3, *(const float4*)(kr+12))
            + dot4(q4, *(const float4*)(kr+16)) + dot4(q5, *(const float4*)(kr+20))
            + dot4(q6, *(const float4*)(kr+24)) + dot4(q7, *(const float4*)(kr+28));
    sv[j] = s*scale;
  }
  float mx = sv[0];
#pragma unroll
  for (int j = 1; j < 8; j++) mx = fmaxf(mx, sv[j]);
  mx = fmaxf(mx, __shfl_xor(mx, 1, 64));
  mx = fmaxf(mx, __shfl_xor(mx, 2, 64));
  mx = fmaxf(mx, __shfl_xor(mx, 4, 64));
  float sum = 0.f;
#pragma unroll
  for (int j = 0; j < 8; j++){ sv[j] = __expf(sv[j] - mx); sum += sv[j]; }
  sum += __shfl_xor(sum, 1, 64);
  sum += __shfl_xor(sum, 2, 64);
  sum += __shfl_xor(sum, 4, 64);
  float inv = 1.0f/sum;
#pragma unroll
  for (int j = 0; j < 8; j++) S[r][g8*8 + j] = sv[j]*inv;
  __syncthreads();
  const int d0 = g8*4;
  float4 o = make_float4(0.f, 0.f, 0.f, 0.f);
  for (int c = 0; c < 64; c++){
    float p = S[r][c];
    float4 v = *(const float4*)&vs[c][d0];
    o.x += p*v.x; o.y += p*v.y; o.z += p*v.z; o.w += p*v.w;
  }
  *(float4*)(outp + ((size_t)(b*NLAT + r0 + r))*DIMD + h*32 + d0) = o;
}

// Fused heads: blockIdx.y==0 -> behavior decoder attn+proj; ==1 -> spike logits.
// Disjoint output ranges (out[0..31] vs out[32..]), independent inputs.
__global__ void k_heads(const float* __restrict__ qb, const float* __restrict__ kv,
                        const float* __restrict__ wo, const float* __restrict__ lat,
                        const float* __restrict__ spw, const float* __restrict__ spb,
                        float* __restrict__ outp){
  int b = blockIdx.x;
  int t = threadIdx.x;
  if (blockIdx.y == 1){
    __shared__ float m[256];
    float s = 0.f;
    for (int l = 0; l < NLAT; l++) s += lat[((size_t)(b*NLAT + l))*DIMD + t];
    m[t] = s*(1.0f/NLAT);
    __syncthreads();
    if (t < 64){
      float o = spb[t];
      for (int c = 0; c < 256; c++) o += m[c]*spw[c*64 + t];
      outp[32 + b*64 + t] = o;
    }
    return;
  }
  __shared__ float S[16][65];
  __shared__ float O2[2][256];
  __shared__ float red[256];
  const float scale = 0.1767766952966369f;
#pragma unroll
  for (int i = 0; i < 4; i++){
    int idx = t + i*256;
    int row = idx >> 6, c = idx & 63;
    int iq = row >> 3, h = row & 7;
    const float* qp = qb + iq*DIMD + h*32;
    const float* kp = kv + ((size_t)(b*NLAT + c))*512 + h*32;
    float s = 0.f;
#pragma unroll
    for (int d = 0; d < 32; d++) s += qp[d]*kp[d];
    S[row][c] = s*scale;
  }
  __syncthreads();
  if (t < 16){
    float mx = -1e30f;
    for (int c = 0; c < 64; c++) mx = fmaxf(mx, S[t][c]);
    float sum = 0.f;
    for (int c = 0; c < 64; c++){ float p = expf(S[t][c] - mx); S[t][c] = p; sum += p; }
    float inv = 1.0f/sum;
    for (int c = 0; c < 64; c++) S[t][c] *= inv;
  }
  __syncthreads();
#pragma unroll
  for (int i = 0; i < 2; i++){
    int idx = t + i*256;
    int iq = idx >> 8, c2 = idx & 255;
    int h = c2 >> 5, d = c2 & 31;
    float o = 0.f;
    for (int c = 0; c < 64; c++)
      o += S[iq*8 + h][c]*kv[((size_t)(b*NLAT + c))*512 + 256 + h*32 + d];
    O2[iq][c2] = o;
  }
  __syncthreads();
  for (int iq = 0; iq < 2; iq++){
    red[t] = O2[iq][t]*wo[t];
    __syncthreads();
    for (int off = 128; off > 0; off >>= 1){
      if (t < off) red[t] += red[t + off];
      __syncthreads();
    }
    if (t == 0) outp[b*2 + iq] = red[0];
    __syncthreads();
  }
}

extern "C" void kernel_launch(void* const* d_in, const int* in_sizes, int n_in,
                              void* d_out, int out_size, void* d_ws, size_t ws_size,
                              hipStream_t stream){
  const int* nid      = (const int*)d_in[0];
  const int* tbin     = (const int*)d_in[1];
  const int* vval     = (const int*)d_in[2];
  const int* bidx     = (const int*)d_in[3];
  const float* ne     = (const float*)d_in[6];
  const float* te     = (const float*)d_in[7];
  const float* ve     = (const float*)d_in[8];
  const float* lat_i  = (const float*)d_in[9];
  const float* Wq_c   = (const float*)d_in[10];
  const float* Wkv_c  = (const float*)d_in[11];
  const float* Wo_c   = (const float*)d_in[12];
  const float* W1_c   = (const float*)d_in[13];
  const float* W2_c   = (const float*)d_in[14];
  const float* Wqkv_s = (const float*)d_in[15];
  const float* Wo_s   = (const float*)d_in[16];
  const float* W1_s   = (const float*)d_in[17];
  const float* W2_s   = (const float*)d_in[18];
  const float* bh_query = (const float*)d_in[19];
  const float* bh_wq    = (const float*)d_in[20];
  const float* bh_wkv   = (const float*)d_in[21];
  const float* bh_wo    = (const float*)d_in[22];
  const float* bh_ln_w  = (const float*)d_in[23];
  const float* bh_ln_b  = (const float*)d_in[24];
  const float* sp_w     = (const float*)d_in[25];
  const float* sp_b     = (const float*)d_in[26];
  float* out = (float*)d_out;
  int E = in_sizes[0];
  (void)n_in; (void)out_size;

  const size_t MBf = (size_t)1 << 20;
  size_t per_gb = (size_t)18*MBf;
  size_t fixed  = (size_t)31*MBf;
  int gb = 1;
  if      (fixed + 16*per_gb <= ws_size) gb = 16;
  else if (fixed +  8*per_gb <= ws_size) gb = 8;
  else if (fixed +  4*per_gb <= ws_size) gb = 4;
  else if (fixed +  2*per_gb <= ws_size) gb = 2;

  char* wsb = (char*)d_ws;
  size_t o = 0;
  auto alloc = [&](size_t bytes)->char*{
    char* p = wsb + o; o = (o + bytes + 255) & ~(size_t)255; return p;
  };
  int*   cnt    = (int*)  alloc((size_t)NB*4);
  int*   sorted = (int*)  alloc((size_t)NB*EMAXC*4);
  float* tq     = (float*)alloc((size_t)64*256*4);
  float* qc     = (float*)alloc((size_t)64*256*4);
  float* qb     = (float*)alloc((size_t)2*256*4);
  u16*   Wt     = (u16*)  alloc((size_t)768*256*2);
  f16t*  WT     = (f16t*) alloc((size_t)WT_TOTAL*2);
  u16*   XLN    = (u16*)  alloc((size_t)gb*EMAXC*256*2);
  u8*    PT     = (u8*)   alloc((size_t)gb*512*EPAD);
  u8*    VT     = (u8*)   alloc((size_t)gb*256*EPAD);
  float* pnum   = (float*)alloc((size_t)NB*NHH*NCH2*2048*4);
  float* pden   = (float*)alloc((size_t)NB*NHH*NCH2*64*4);
  float* OC     = (float*)alloc((size_t)NB*64*256*4);
  float* lat    = (float*)alloc((size_t)NB*64*256*4);
  float* qkv    = (float*)alloc((size_t)NB*64*768*4);
  float* ffh    = (float*)alloc((size_t)NB*64*1024*4);

  // ---- prep ----
  k_zero<<<1, 64, 0, stream>>>(cnt);
  k_sort<<<(E + 1023)/1024, 256, 0, stream>>>(bidx, cnt, sorted, E);
  k_ln<<<16, 256, 0, stream>>>(lat_i, tq, 64);
  k_gemm<<<dim3(8,1), 256, 0, stream>>>(tq, Wq_c, qc, 64, 256, 256);
  k_qw<<<768, 256, 0, stream>>>(Wkv_c, qc, Wt);
  k_gemm<<<dim3(1,1), 256, 0, stream>>>(bh_query, bh_wq, qb, 2, 256, 256);
  k_wt<<<dim3(64,12), 256, 0, stream>>>(Wo_c, W1_c, W2_c, Wqkv_s, Wo_s, W1_s,
                                        W2_s, bh_wkv, WT);

  // ---- event cross-attention, runtime-sized batch groups ----
  for (int b0 = 0; b0 < NB; b0 += gb){
    k_a0<<<dim3(EMAXC/4, gb), 256, 0, stream>>>(sorted, cnt, nid, tbin, vval,
                                                ne, te, ve, XLN, b0);
    k_a<<<dim3(48, 14, gb), 256, 0, stream>>>(XLN, Wt, cnt, PT, VT, b0, 0);
    k_b<<<dim3(NCH2, NHH, gb), 256, 0, stream>>>(PT, VT, cnt, pnum, pden, b0);
  }
  k_red<<<1024, 256, 0, stream>>>(pnum, pden, OC);

  // ---- latent chain (f16 MFMA GEMMs; LN fused as prologue where K=256) ----
  const int M = NB*NLAT;  // 1024
  k_init<<<M, 256, 0, stream>>>(lat_i, lat);
  k_gemm3<<<dim3(16,4,4), 256, 0, stream>>>(OC, WT + WTO_WOC, lat, nullptr, nullptr,
                                            M, 256, 256, 2, 0);
  k_gemm3<<<dim3(16,16,1), 256, 0, stream>>>(lat, WT + WTO_W1C, ffh, nullptr, nullptr,
                                             M, 256, 1024, 1, 1);
  k_gemm3<<<dim3(16,4,4), 256, 0, stream>>>(ffh, WT + WTO_W2C, lat, nullptr, nullptr,
                                            M, 1024, 256, 2, 0);

  for (int i = 0; i < 2; i++){
    k_gemm3<<<dim3(16,12,1), 256, 0, stream>>>(lat, WT + (i ? WTO_QKV1 : WTO_QKV0), qkv,
                                               nullptr, nullptr, M, 256, 768, 0, 1);
    k_attn<<<dim3(NB, NHH, 2), 256, 0, stream>>>(qkv, ffh);
    k_gemm3<<<dim3(16,4,4), 256, 0, stream>>>(ffh, WT + (i ? WTO_WOS1 : WTO_WOS0), lat,
                                              nullptr, nullptr, M, 256, 256, 2, 0);
    k_gemm3<<<dim3(16,16,1), 256, 0, stream>>>(lat, WT + (i ? WTO_W1S1 : WTO_W1S0), ffh,
                                               nullptr, nullptr, M, 256, 1024, 1, 1);
    k_gemm3<<<dim3(16,4,4), 256, 0, stream>>>(ffh, WT + (i ? WTO_W2S1 : WTO_W2S0), lat,
                                              nullptr, nullptr, M, 1024, 256, 2, 0);
  }

  // ---- heads ----
  k_gemm3<<<dim3(16,8,1), 256, 0, stream>>>(lat, WT + WTO_BH, qkv, bh_ln_w, bh_ln_b,
                                            M, 256, 512, 0, 1);
  k_heads<<<dim3(NB, 2), 256, 0, stream>>>(qb, qkv, bh_wo, lat, sp_w, sp_b, out);
}

// Round 14
// 522.488 us; speedup vs baseline: 1.1018x; 1.0106x over previous
//
#include <hip/hip_runtime.h>
#include <math.h>

#define NB 16
#define DIMD 256
#define NHH 8
#define NLAT 64
#define EMAXC 13568
#define NCH2 14            /* chunks of 1024 events (last partial) */
#define EPAD (NCH2*1024)   /* 14336: padded event stride (bytes for fp8 PT/VT) */

typedef float f32x4 __attribute__((ext_vector_type(4)));
typedef __bf16 bf16x8 __attribute__((ext_vector_type(8)));
typedef _Float16 f16t;
typedef __attribute__((ext_vector_type(8))) _Float16 f16x8;
typedef unsigned short u16;
typedef unsigned char u8;
typedef unsigned int u32;
typedef __attribute__((ext_vector_type(4))) unsigned int u32x4;
typedef __attribute__((ext_vector_type(8))) unsigned short u16x8;
typedef __attribute__((ext_vector_type(2))) long longx2;

/* f16 transposed-weight pool offsets (elements), layout [N][K] */
#define WTO_WOC   0u
#define WTO_W1C   65536u
#define WTO_W2C   327680u
#define WTO_QKV0  589824u
#define WTO_WOS0  786432u
#define WTO_W1S0  851968u
#define WTO_W2S0  1114112u
#define WTO_QKV1  1376256u
#define WTO_WOS1  1572864u
#define WTO_W1S1  1638400u
#define WTO_W2S1  1900544u
#define WTO_BH    2162688u
#define WT_TOTAL  2293760u

static __device__ __forceinline__ float wave_sum(float v){
#pragma unroll
  for (int off = 32; off > 0; off >>= 1) v += __shfl_xor(v, off, 64);
  return v;
}

static __device__ __forceinline__ u16 f2bf(float x){
  unsigned u = __float_as_uint(x);
  u += 0x7fffu + ((u >> 16) & 1u);
  return (u16)(u >> 16);
}

static __device__ __forceinline__ float gelu_tanh(float x){
  float x3 = x*x*x;
  return 0.5f*x*(1.0f + tanhf(0.7978845608028654f*(x + 0.044715f*x3)));
}

static __device__ __forceinline__ float dot4(float4 a, float4 b){
  return a.x*b.x + a.y*b.y + a.z*b.z + a.w*b.w;
}

// Async global->LDS DMA, 16B per lane. LDS dest is wave-uniform base + lane*16.
static __device__ __forceinline__ void gl_lds16(const void* g, void* l){
  __builtin_amdgcn_global_load_lds((const __attribute__((address_space(1))) void*)g,
                                   (__attribute__((address_space(3))) void*)l,
                                   16, 0, 0);
}

__global__ void k_zero(int* cnt){ if ((int)threadIdx.x < NB) cnt[threadIdx.x] = 0; }

// LDS-histogram bucket sort: 16 global atomics per 1024-event block.
__global__ void k_sort(const int* __restrict__ bidx, int* __restrict__ cnt,
                       int* __restrict__ sorted, int E){
  __shared__ int h[NB], base[NB];
  int t = threadIdx.x;
  if (t < NB) h[t] = 0;
  __syncthreads();
  int e0 = blockIdx.x*1024;
  int myb[4], myp[4];
#pragma unroll
  for (int i = 0; i < 4; i++){
    int e = e0 + i*256 + t;
    myb[i] = -1;
    if (e < E){ myb[i] = bidx[e]; myp[i] = atomicAdd(&h[myb[i]], 1); }
  }
  __syncthreads();
  if (t < NB) base[t] = atomicAdd(&cnt[t], h[t]);
  __syncthreads();
#pragma unroll
  for (int i = 0; i < 4; i++){
    if (myb[i] >= 0){
      int p = base[myb[i]] + myp[i];
      if (p < EMAXC) sorted[myb[i]*EMAXC + p] = e0 + i*256 + t;
    }
  }
}

// LayerNorm over rows of 256 (used only for lat_init prep).
__global__ void k_ln(const float* __restrict__ X, float* __restrict__ Y, int rows){
  int wave = threadIdx.x >> 6, lane = threadIdx.x & 63;
  int row = blockIdx.x*4 + wave;
  if (row >= rows) return;
  float4 x = ((const float4*)(X + (size_t)row*DIMD))[lane];
  float s = wave_sum(x.x + x.y + x.z + x.w);
  float m = s * (1.0f/DIMD);
  float d0 = x.x-m, d1 = x.y-m, d2 = x.z-m, d3 = x.w-m;
  float v = wave_sum(d0*d0 + d1*d1 + d2*d2 + d3*d3) * (1.0f/DIMD);
  float rs = rsqrtf(v + 1e-5f);
  ((float4*)(Y + (size_t)row*DIMD))[lane] = make_float4(d0*rs, d1*rs, d2*rs, d3*rs);
}

// lat[row] = lat_init[row % 64]  (row-broadcast residual init)
__global__ void k_init(const float* __restrict__ lat_i, float* __restrict__ lat){
  int r = blockIdx.x, t = threadIdx.x;
  lat[(size_t)r*DIMD + t] = lat_i[(size_t)(r & 63)*DIMD + t];
}

// Small prep GEMM (tiny M): C[M,N] = A[M,K] @ W[K,N]
__global__ __launch_bounds__(256) void k_gemm(
    const float* __restrict__ A, const float* __restrict__ W,
    float* __restrict__ C, int M, int K, int N){
  __shared__ float As[8][1024];
  int t = threadIdx.x;
  int row0 = blockIdx.x*8;
  int col = blockIdx.y*256 + t;
  int kq = K >> 2;
  for (int idx = t; idx < 8*kq; idx += 256){
    int r = idx / kq, kc = idx % kq;
    float4 v = make_float4(0.f,0.f,0.f,0.f);
    if (row0 + r < M) v = ((const float4*)(A + (size_t)(row0+r)*K))[kc];
    ((float4*)&As[r][0])[kc] = v;
  }
  __syncthreads();
  float acc[8] = {0,0,0,0,0,0,0,0};
  for (int k = 0; k < K; k += 4){
    float w0 = W[(size_t)(k+0)*N + col];
    float w1 = W[(size_t)(k+1)*N + col];
    float w2 = W[(size_t)(k+2)*N + col];
    float w3 = W[(size_t)(k+3)*N + col];
#pragma unroll
    for (int r = 0; r < 8; r++){
      float4 a = *((const float4*)&As[r][k]);
      acc[r] += a.x*w0 + a.y*w1 + a.z*w2 + a.w*w3;
    }
  }
#pragma unroll
  for (int r = 0; r < 8; r++){
    int row = row0 + r;
    if (row < M) C[(size_t)row*N + col] = acc[r];
  }
}

// Transpose all latent-chain weights to f16 [N][K] pool (runs once per launch).
// 64x64 LDS-tile transpose; grid (64, 12); out-of-range tiles return.
__global__ __launch_bounds__(256) void k_wt(
    const float* __restrict__ Wo_c, const float* __restrict__ W1_c,
    const float* __restrict__ W2_c, const float* __restrict__ Wqkv_s,
    const float* __restrict__ Wo_s, const float* __restrict__ W1_s,
    const float* __restrict__ W2_s, const float* __restrict__ bh_wkv,
    f16t* __restrict__ WT){
  const int mid = blockIdx.y;
  const float* src; int K, N; unsigned off;
  switch (mid){
    case 0:  src = Wo_c;            K = 256;  N = 256;  off = WTO_WOC;  break;
    case 1:  src = W1_c;            K = 256;  N = 1024; off = WTO_W1C;  break;
    case 2:  src = W2_c;            K = 1024; N = 256;  off = WTO_W2C;  break;
    case 3:  src = Wqkv_s;          K = 256;  N = 768;  off = WTO_QKV0; break;
    case 4:  src = Wo_s;            K = 256;  N = 256;  off = WTO_WOS0; break;
    case 5:  src = W1_s;            K = 256;  N = 1024; off = WTO_W1S0; break;
    case 6:  src = W2_s;            K = 1024; N = 256;  off = WTO_W2S0; break;
    case 7:  src = Wqkv_s + 196608; K = 256;  N = 768;  off = WTO_QKV1; break;
    case 8:  src = Wo_s + 65536;    K = 256;  N = 256;  off = WTO_WOS1; break;
    case 9:  src = W1_s + 262144;   K = 256;  N = 1024; off = WTO_W1S1; break;
    case 10: src = W2_s + 262144;   K = 1024; N = 256;  off = WTO_W2S1; break;
    default: src = bh_wkv;          K = 256;  N = 512;  off = WTO_BH;   break;
  }
  const int ntiles = N >> 6;
  const int tiles = ntiles * (K >> 6);
  if ((int)blockIdx.x >= tiles) return;
  const int kt = blockIdx.x / ntiles, nt = blockIdx.x % ntiles;
  __shared__ float tile[64][65];
  const int t = threadIdx.x;
  const int k0 = kt*64, n0 = nt*64;
#pragma unroll
  for (int i = 0; i < 16; i++){
    int k = i*4 + (t >> 6);
    tile[k][t & 63] = src[(size_t)(k0 + k)*N + n0 + (t & 63)];
  }
  __syncthreads();
  const int n = t >> 2, ks = (t & 3)*16;
  f16t* d = WT + off + (size_t)(n0 + n)*K + k0 + ks;
#pragma unroll
  for (int j = 0; j < 16; j++) d[j] = (f16t)tile[ks + j][n];
}

// MFMA latent-chain GEMM: C[M,N] (+)= A[M,K] @ W, W given as f16 WT[N][K].
// 64x64 tile, BK=64, 4 waves. A staged f32->f16 via LDS pitch-72; B via
// global_load_lds with 8-chunk XOR swizzle kc=c'^(r&7) (involution).
// modes: 0 plain / 1 gelu / 2 atomicAdd; K split over gridDim.z.
// do_ln (K==256, S==1): LayerNorm rows of A, optional affine lnw/lnb.
__global__ __launch_bounds__(256) void k_gemm3(
    const float* __restrict__ A, const f16t* __restrict__ WT, float* __restrict__ C,
    const float* __restrict__ lnw, const float* __restrict__ lnb,
    int M, int K, int N, int mode, int do_ln){
  __shared__ f16t Xs[64][72];
  __shared__ f16t Ws[64][64];
  __shared__ float lnm[64], lnr[64];
  const int t = threadIdx.x;
  const int wv = t >> 6, lane = t & 63;
  const int quad = lane >> 4, lane15 = lane & 15;
  const int m0 = blockIdx.x*64, n0 = blockIdx.y*64;
  const int Kc = K / gridDim.z;
  const int k0b = blockIdx.z*Kc;

  f32x4 acc[4];
#pragma unroll
  for (int j = 0; j < 4; j++) acc[j] = (f32x4){0.f,0.f,0.f,0.f};

  if (do_ln){
    int r = t >> 2, seg = (t & 3)*64;
    const float* Ar = A + (size_t)(m0 + r)*K + seg;
    float s = 0.f, s2 = 0.f;
#pragma unroll
    for (int j = 0; j < 64; j += 4){
      float4 v = *(const float4*)(Ar + j);
      s  += v.x + v.y + v.z + v.w;
      s2 += v.x*v.x + v.y*v.y + v.z*v.z + v.w*v.w;
    }
    s += __shfl_xor(s, 1, 64); s2 += __shfl_xor(s2, 1, 64);
    s += __shfl_xor(s, 2, 64); s2 += __shfl_xor(s2, 2, 64);
    if ((t & 3) == 0){
      float m = s*(1.0f/256.0f);
      float var = s2*(1.0f/256.0f) - m*m;
      lnm[r] = m; lnr[r] = rsqrtf(var + 1e-5f);
    }
    __syncthreads();
  }

  const int ar = t >> 2;                        // A stage row (0..63)
  const int as16 = (t & 3)*16;                  // A stage k-offset (16 f16)
  f16t* wdst0 = &Ws[0][0] + (size_t)(wv*64)*8;          // p=0 wave base
  f16t* wdst1 = &Ws[0][0] + (size_t)(256 + wv*64)*8;    // p=1 wave base

  for (int k0 = k0b; k0 < k0b + Kc; k0 += 64){
    __syncthreads();                  // prior frag reads done; buffers free
#pragma unroll
    for (int p = 0; p < 2; p++){
      int li = p*256 + t;
      int r = li >> 3;
      int kc = (li & 7) ^ (r & 7);
      gl_lds16(WT + (size_t)(n0 + r)*K + k0 + kc*8, p ? wdst1 : wdst0);
    }
    const float* Arow = A + (size_t)(m0 + ar)*K + k0 + as16;
    float4 v0 = *(const float4*)(Arow + 0);
    float4 v1 = *(const float4*)(Arow + 4);
    float4 v2 = *(const float4*)(Arow + 8);
    float4 v3 = *(const float4*)(Arow + 12);
    if (do_ln){
      float mm = lnm[ar], rs = lnr[ar];
      v0.x=(v0.x-mm)*rs; v0.y=(v0.y-mm)*rs; v0.z=(v0.z-mm)*rs; v0.w=(v0.w-mm)*rs;
      v1.x=(v1.x-mm)*rs; v1.y=(v1.y-mm)*rs; v1.z=(v1.z-mm)*rs; v1.w=(v1.w-mm)*rs;
      v2.x=(v2.x-mm)*rs; v2.y=(v2.y-mm)*rs; v2.z=(v2.z-mm)*rs; v2.w=(v2.w-mm)*rs;
      v3.x=(v3.x-mm)*rs; v3.y=(v3.y-mm)*rs; v3.z=(v3.z-mm)*rs; v3.w=(v3.w-mm)*rs;
      if (lnw){
        int k = k0 + as16;
        v0.x=v0.x*lnw[k+0]+lnb[k+0];  v0.y=v0.y*lnw[k+1]+lnb[k+1];
        v0.z=v0.z*lnw[k+2]+lnb[k+2];  v0.w=v0.w*lnw[k+3]+lnb[k+3];
        v1.x=v1.x*lnw[k+4]+lnb[k+4];  v1.y=v1.y*lnw[k+5]+lnb[k+5];
        v1.z=v1.z*lnw[k+6]+lnb[k+6];  v1.w=v1.w*lnw[k+7]+lnb[k+7];
        v2.x=v2.x*lnw[k+8]+lnb[k+8];  v2.y=v2.y*lnw[k+9]+lnb[k+9];
        v2.z=v2.z*lnw[k+10]+lnb[k+10]; v2.w=v2.w*lnw[k+11]+lnb[k+11];
        v3.x=v3.x*lnw[k+12]+lnb[k+12]; v3.y=v3.y*lnw[k+13]+lnb[k+13];
        v3.z=v3.z*lnw[k+14]+lnb[k+14]; v3.w=v3.w*lnw[k+15]+lnb[k+15];
      }
    }
    f16x8 h0 = {(f16t)v0.x,(f16t)v0.y,(f16t)v0.z,(f16t)v0.w,
                (f16t)v1.x,(f16t)v1.y,(f16t)v1.z,(f16t)v1.w};
    f16x8 h1 = {(f16t)v2.x,(f16t)v2.y,(f16t)v2.z,(f16t)v2.w,
                (f16t)v3.x,(f16t)v3.y,(f16t)v3.z,(f16t)v3.w};
    *(f16x8*)&Xs[ar][as16]     = h0;
    *(f16x8*)&Xs[ar][as16 + 8] = h1;
    __syncthreads();                  // drains vmcnt (DMA) + lgkm (ds_write)
#pragma unroll
    for (int ks = 0; ks < 2; ks++){
      f16x8 a = *(const f16x8*)&Xs[wv*16 + lane15][ks*32 + quad*8];
#pragma unroll
      for (int nt = 0; nt < 4; nt++){
        int ch = (ks*4 + quad) ^ (lane15 & 7);
        f16x8 bw = *(const f16x8*)&Ws[nt*16 + lane15][ch*8];
        acc[nt] = __builtin_amdgcn_mfma_f32_16x16x32_f16(a, bw, acc[nt], 0, 0, 0);
      }
    }
  }
#pragma unroll
  for (int nt = 0; nt < 4; nt++){
    int col = n0 + nt*16 + lane15;
#pragma unroll
    for (int j = 0; j < 4; j++){
      int row = m0 + wv*16 + quad*4 + j;
      float v = acc[nt][j];
      if (mode == 1) v = gelu_tanh(v);
      float* cp = C + (size_t)row*N + col;
      if (mode == 2) atomicAdd(cp, v);
      else *cp = v;
    }
  }
}

// Build Wt[768][256] bf16 (transposed, column-reordered)
__global__ void k_qw(const float* __restrict__ Wkv, const float* __restrict__ qc,
                     u16* __restrict__ Wt){
  int n = blockIdx.x;
  int k = threadIdx.x;
  float v;
  if (n < 256){
    v = Wkv[(size_t)k*512 + 256 + n];
  } else {
    int h = (n - 256) >> 6, l = (n - 256) & 63;
    const float* wk = Wkv + (size_t)k*512 + h*32;
    const float* qr = qc + (size_t)l*256 + h*32;
    float s = 0.f;
#pragma unroll
    for (int dd = 0; dd < 32; dd++) s += wk[dd]*qr[dd];
    v = s*0.1767766952966369f;
  }
  Wt[(size_t)n*256 + k] = f2bf(v);
}

// Gather+LN -> XLN bf16 (group-local), zero pad rows. One wave per event row.
__global__ void k_a0(const int* __restrict__ sorted, const int* __restrict__ cnt,
                     const int* __restrict__ nid, const int* __restrict__ tbin,
                     const int* __restrict__ vval,
                     const float* __restrict__ ne, const float* __restrict__ te,
                     const float* __restrict__ ve, u16* __restrict__ XLN, int b0){
  int wv = threadIdx.x >> 6, lane = threadIdx.x & 63;
  int e = blockIdx.x*4 + wv;
  int bg = blockIdx.y, b = b0 + bg;
  int cn = min(cnt[b], EMAXC);
  ushort4 pk; pk.x = 0; pk.y = 0; pk.z = 0; pk.w = 0;
  if (e < cn){
    int ev = sorted[b*EMAXC + e];
    float4 aa = ((const float4*)(ne + (size_t)nid[ev]*DIMD))[lane];
    float4 bb = ((const float4*)(te + (size_t)tbin[ev]*DIMD))[lane];
    float4 cc = ((const float4*)(ve + (size_t)vval[ev]*DIMD))[lane];
    float x0 = aa.x+bb.x+cc.x, x1 = aa.y+bb.y+cc.y;
    float x2 = aa.z+bb.z+cc.z, x3 = aa.w+bb.w+cc.w;
    float s = wave_sum(x0 + x1 + x2 + x3);
    float m = s*(1.0f/DIMD);
    x0 -= m; x1 -= m; x2 -= m; x3 -= m;
    float v = wave_sum(x0*x0 + x1*x1 + x2*x2 + x3*x3)*(1.0f/DIMD);
    float rs = rsqrtf(v + 1e-5f);
    pk.x = f2bf(x0*rs); pk.y = f2bf(x1*rs); pk.z = f2bf(x2*rs); pk.w = f2bf(x3*rs);
  }
  *(ushort4*)(XLN + ((size_t)bg*EMAXC + e)*DIMD + lane*4) = pk;
}

// Dense MFMA GEMM: [PT|VT] (transposed, fp8 e4m3) = exp?(XLN @ Wt^T).
// 128x128 tile, BK=32, THREE-buffer (X and W both) global_load_lds pipeline
// with counted vmcnt (T3/T4): joint X+W stage (4 ops), vmcnt(8) retires
// exactly stage(it) with stage(it+1), stage(it+2) in flight. r13's split
// X-triple/W-double 40KB variant retired X(it+2) one phase early via the
// shared counter -> +1us; reverted to this r11-verified scheme (56.5us).
// Chunk XOR-swizzle (r4-verified, conflict-free). NO setprio (r6: -8.7%).
// GRID LAYOUT IS LOAD-BEARING (r10): nidx=x>>3, rtile=y*8+(x&7) keeps the 6
// column-tile blocks sharing an X row-panel at blockIdx stride 8 = XCD
// round-robin period -> same per-XCD L2. Flat grid cost 6x FETCH (r10).
// LDS 48KB -> 3 blocks/CU. grid (48, 14, gb).
__global__ __launch_bounds__(256) void k_a(
    const u16* __restrict__ XLN, const u16* __restrict__ Wt,
    const int* __restrict__ cnt, u8* __restrict__ PT, u8* __restrict__ VT, int b0)
{
  __shared__ union ShMem {
    struct { u16 Xs[3][128][32]; u16 Ws[3][128][32]; } s;
    u8 Tr[128][136];
  } sh;
  const int t = threadIdx.x;
  const int wv = t >> 6, lane = t & 63;
  const int quad = lane >> 4, lane15 = lane & 15;
  const int nidx = blockIdx.x >> 3;
  const int rtile = blockIdx.y*8 + (blockIdx.x & 7);
  if (nidx >= 6 || rtile >= EMAXC/128) return;
  const int bg = blockIdx.z;
  const int b = b0 + bg;
  const int cn = min(cnt[b], EMAXC);
  const int row0 = rtile * 128;
  if (row0 >= cn) return;
  const int n0 = nidx * 128;
  const int eh = (wv >> 1) * 64, nh = (wv & 1) * 64;

  f32x4 acc[4][4];
#pragma unroll
  for (int i = 0; i < 4; i++)
#pragma unroll
    for (int j = 0; j < 4; j++) acc[i][j] = (f32x4){0.f,0.f,0.f,0.f};

  const u16* Xbase = XLN + ((size_t)bg*EMAXC + row0)*DIMD;
  const u16* Wbase = Wt + (size_t)n0*256;

  auto stage = [&](int buf, int k0){
#pragma unroll
    for (int p = 0; p < 2; p++){
      int li = p*256 + wv*64 + lane;
      int r = li >> 2;
      int kc = (li & 3) ^ ((r >> 1) & 3);
      u16* xd = &sh.s.Xs[buf][0][0] + (size_t)(p*256 + wv*64)*8;
      u16* wd = &sh.s.Ws[buf][0][0] + (size_t)(p*256 + wv*64)*8;
      gl_lds16(Xbase + (size_t)r*DIMD + k0 + kc*8, xd);
      gl_lds16(Wbase + (size_t)r*256  + k0 + kc*8, wd);
    }
  };
  const int cswz = quad ^ ((lane15 >> 1) & 3);   // read-side chunk swizzle
  auto compute = [&](int buf){
    bf16x8 a[4], bw[4];
#pragma unroll
    for (int mt = 0; mt < 4; mt++)
      a[mt] = *(const bf16x8*)&sh.s.Xs[buf][eh + mt*16 + lane15][cswz*8];
#pragma unroll
    for (int nt = 0; nt < 4; nt++)
      bw[nt] = *(const bf16x8*)&sh.s.Ws[buf][nh + nt*16 + lane15][cswz*8];
#pragma unroll
    for (int mt = 0; mt < 4; mt++)
#pragma unroll
      for (int nt = 0; nt < 4; nt++)
        acc[mt][nt] = __builtin_amdgcn_mfma_f32_16x16x32_bf16(a[mt], bw[nt], acc[mt][nt], 0, 0, 0);
  };

  stage(0, 0);
  stage(1, 32);
#pragma unroll
  for (int it = 0; it < 8; it++){
    __builtin_amdgcn_s_barrier();              // A: compute(it-1) done; buf (it+2)%3 free
    if (it + 2 < 8) stage((it + 2) % 3, (it + 2)*32);
    if (it <= 5)      asm volatile("s_waitcnt vmcnt(8)" ::: "memory");
    else if (it == 6) asm volatile("s_waitcnt vmcnt(4)" ::: "memory");
    else              asm volatile("s_waitcnt vmcnt(0)" ::: "memory");
    __builtin_amdgcn_s_barrier();              // B: everyone's stage(it) landed
    __builtin_amdgcn_sched_barrier(0);
    compute(it % 3);
  }
  const int is_p = (n0 >= 256);
  __syncthreads();   // buffers dead from here; Tr takes over the storage
#pragma unroll
  for (int mt = 0; mt < 4; mt++){
    int e0 = eh + mt*16 + quad*4;
#pragma unroll
    for (int nt = 0; nt < 4; nt++){
      int c = nh + nt*16 + lane15;
      f32x4 v = acc[mt][nt];
      if (is_p){ v.x = __expf(v.x); v.y = __expf(v.y); v.z = __expf(v.z); v.w = __expf(v.w); }
      int p01 = __builtin_amdgcn_cvt_pk_fp8_f32(v.x, v.y, 0, false);
      int p23 = __builtin_amdgcn_cvt_pk_fp8_f32(v.z, v.w, 0, false);
      unsigned pk = ((unsigned)p01 & 0xFFFFu) | ((unsigned)p23 << 16);
      *(unsigned*)&sh.Tr[c][e0] = pk;
    }
  }
  __syncthreads();
  u8* dst = is_p ? (PT + ((size_t)bg*512 + (n0 - 256))*EPAD)
                 : (VT + ((size_t)bg*256 + n0)*EPAD);
  const int chalf = lane >> 5;
  const int e4 = (lane & 31) * 4;
#pragma unroll
  for (int i = 0; i < 16; i++){
    int c = wv*32 + i*2 + chalf;
    unsigned val = *(const unsigned*)&sh.Tr[c][e4];
    *(unsigned*)(dst + (size_t)c*EPAD + row0 + e4) = val;
  }
}

// PV reduction (fp8 MFMA): O^T[dh][l] = sum_e V[dh][e]*P[l][e]; den via ones-MFMA.
// grid (NCH2, 8, gb), 256 thr; each wave owns a 256-event K-slice.
// 16B-per-lane loads (longx2, r13: -25us): PV/den are event-order-invariant,
// so the lo/hi 8B halves feed two MFMA K-blocks; halves VMEM instruction
// count. Tail mask on P only. No main-loop barriers: phase-diverse waves ->
// s_setprio around MFMA (T5).
__global__ __launch_bounds__(256) void k_b(
    const u8* __restrict__ PT, const u8* __restrict__ VT,
    const int* __restrict__ cnt, float* __restrict__ pnum, float* __restrict__ pden, int b0)
{
  __shared__ float red[4][2048];
  __shared__ float redd[4][64];
  const int t = threadIdx.x;
  const int wv = t >> 6, lane = t & 63;
  const int quad = lane >> 4, lane15 = lane & 15;
  const int chunk = blockIdx.x, h = blockIdx.y, bg = blockIdx.z;
  const int b = b0 + bg;
  const int cn = min(cnt[b], EMAXC);
  const u8* PTg = PT + ((size_t)bg*512 + h*64)*EPAD;
  const u8* VTg = VT + ((size_t)bg*256 + h*32)*EPAD;

  f32x4 acc[3][4];
#pragma unroll
  for (int i = 0; i < 3; i++)
#pragma unroll
    for (int j = 0; j < 4; j++) acc[i][j] = (f32x4){0.f,0.f,0.f,0.f};

  const long ones = 0x3838383838383838L;

  const int e0w = chunk*1024 + wv*256;
#pragma unroll
  for (int ks = 0; ks < 4; ks++){
    int eb = e0w + ks*64 + quad*16;
    longx2 a0 = *(const longx2*)(VTg + (size_t)(lane15     )*EPAD + eb);
    longx2 a1 = *(const longx2*)(VTg + (size_t)(16 + lane15)*EPAD + eb);
    longx2 bp[4];
#pragma unroll
    for (int nt = 0; nt < 4; nt++){
      union { longx2 v; u8 c[16]; } m;
      m.v = *(const longx2*)(PTg + (size_t)(nt*16 + lane15)*EPAD + eb);
      if (eb + 16 > cn){
#pragma unroll
        for (int j = 0; j < 16; j++) if (eb + j >= cn) m.c[j] = 0;
      }
      bp[nt] = m.v;
    }
    __builtin_amdgcn_s_setprio(1);
#pragma unroll
    for (int nt = 0; nt < 4; nt++){
      acc[0][nt] = __builtin_amdgcn_mfma_f32_16x16x32_fp8_fp8(a0[0], bp[nt][0], acc[0][nt], 0, 0, 0);
      acc[1][nt] = __builtin_amdgcn_mfma_f32_16x16x32_fp8_fp8(a1[0], bp[nt][0], acc[1][nt], 0, 0, 0);
      acc[2][nt] = __builtin_amdgcn_mfma_f32_16x16x32_fp8_fp8(ones,  bp[nt][0], acc[2][nt], 0, 0, 0);
    }
#pragma unroll
    for (int nt = 0; nt < 4; nt++){
      acc[0][nt] = __builtin_amdgcn_mfma_f32_16x16x32_fp8_fp8(a0[1], bp[nt][1], acc[0][nt], 0, 0, 0);
      acc[1][nt] = __builtin_amdgcn_mfma_f32_16x16x32_fp8_fp8(a1[1], bp[nt][1], acc[1][nt], 0, 0, 0);
      acc[2][nt] = __builtin_amdgcn_mfma_f32_16x16x32_fp8_fp8(ones,  bp[nt][1], acc[2][nt], 0, 0, 0);
    }
    __builtin_amdgcn_s_setprio(0);
  }
#pragma unroll
  for (int mt = 0; mt < 2; mt++)
#pragma unroll
    for (int nt = 0; nt < 4; nt++){
      int l = nt*16 + lane15;
#pragma unroll
      for (int j = 0; j < 4; j++)
        red[wv][l*32 + mt*16 + quad*4 + j] = acc[mt][nt][j];
    }
  if (quad == 0){
#pragma unroll
    for (int nt = 0; nt < 4; nt++) redd[wv][nt*16 + lane15] = acc[2][nt][0];
  }
  __syncthreads();
  size_t obase = ((size_t)(b*NHH + h)*NCH2 + chunk);
  for (int i = t; i < 2048; i += 256)
    pnum[obase*2048 + i] = red[0][i] + red[1][i] + red[2][i] + red[3][i];
  if (t < 64)
    pden[obase*64 + t] = redd[0][t] + redd[1][t] + redd[2][t] + redd[3][t];
}

// Reduce partials over chunks, divide, write OC[b][l][h*32+dh]
__global__ void k_red(const float* __restrict__ pnum, const float* __restrict__ pden,
                      float* __restrict__ OC){
  int g = blockIdx.x*256 + threadIdx.x;
  int b = g >> 14, r = g & 16383;
  int h = r >> 11, idx = r & 2047;
  int l = idx >> 5, dh = idx & 31;
  float ns = 0.f, ds = 0.f;
  for (int c = 0; c < NCH2; c++){
    size_t ob = ((size_t)(b*NHH + h)*NCH2 + c);
    ns += pnum[ob*2048 + idx];
    ds += pden[ob*64 + l];
  }
  OC[((size_t)(b*NLAT + l))*DIMD + h*32 + dh] = ns/ds;
}

// Self-attention over 64 latents. grid (NB, NHH, 2): z halves the Q rows so
// 256 blocks cover all CUs. float4 loads; S via register-blocked dot4 with
// broadcast LDS reads; wave-parallel softmax (8 lanes/row, shfl_xor 1/2/4);
// PV float4 over V rows.
__global__ __launch_bounds__(256) void k_attn(const float* __restrict__ qkv,
                                              float* __restrict__ outp){
  int b = blockIdx.x, h = blockIdx.y;
  int r0 = blockIdx.z*32;
  __shared__ float qs[32][33], ks[64][33], vs[64][33];
  __shared__ float S[32][65];
  int t = threadIdx.x;
  {
    int l = t >> 3, d4 = (t & 7)*4;     // qs: 32 rows x 8 float4
    const float* qp = qkv + ((size_t)(b*NLAT + r0 + l))*768 + h*32 + d4;
    *(float4*)&qs[l][d4] = *(const float4*)qp;
  }
#pragma unroll
  for (int i = 0; i < 2; i++){
    int idx = i*256 + t;
    int l = idx >> 3, d4 = (idx & 7)*4; // ks/vs: 64 rows x 8 float4
    const float* kp = qkv + ((size_t)(b*NLAT + l))*768 + h*32 + 256 + d4;
    *(float4*)&ks[l][d4] = *(const float4*)kp;
    *(float4*)&vs[l][d4] = *(const float4*)(kp + 256);
  }
  __syncthreads();
  const float scale = 0.1767766952966369f;
  const int r = t >> 3, g8 = t & 7;
  float4 q0 = *(const float4*)&qs[r][0],  q1 = *(const float4*)&qs[r][4],
         q2 = *(const float4*)&qs[r][8],  q3 = *(const float4*)&qs[r][12],
         q4 = *(const float4*)&qs[r][16], q5 = *(const float4*)&qs[r][20],
         q6 = *(const float4*)&qs[r][24], q7 = *(const float4*)&qs[r][28];
  float sv[8];
#pragma unroll
  for (int j = 0; j < 8; j++){
    const float* kr = &ks[g8*8 + j][0];
    float s = dot4(q0, *(const float4*)(kr+0))  + dot4(q1, *(const float4*)(kr+4))
            + dot4(q2, *(const float4*)(kr+8))  + dot4(q3, *(const float4*)(kr+12))
            + dot4(q4, *(const float4*)(kr+16)) + dot4(q5, *(const float4*)(kr+20))
            + dot4(q6, *(const float4*)(kr+24)) + dot4(q7, *(const float4*)(kr+28));
    sv[j] = s*scale;
  }
  float mx = sv[0];
#pragma unroll
  for (int j = 1; j < 8; j++) mx = fmaxf(mx, sv[j]);
  mx = fmaxf(mx, __shfl_xor(mx, 1, 64));
  mx = fmaxf(mx, __shfl_xor(mx, 2, 64));
  mx = fmaxf(mx, __shfl_xor(mx, 4, 64));
  float sum = 0.f;
#pragma unroll
  for (int j = 0; j < 8; j++){ sv[j] = __expf(sv[j] - mx); sum += sv[j]; }
  sum += __shfl_xor(sum, 1, 64);
  sum += __shfl_xor(sum, 2, 64);
  sum += __shfl_xor(sum, 4, 64);
  float inv = 1.0f/sum;
#pragma unroll
  for (int j = 0; j < 8; j++) S[r][g8*8 + j] = sv[j]*inv;
  __syncthreads();
  const int d0 = g8*4;
  float4 o = make_float4(0.f, 0.f, 0.f, 0.f);
  for (int c = 0; c < 64; c++){
    float p = S[r][c];
    float4 v = *(const float4*)&vs[c][d0];
    o.x += p*v.x; o.y += p*v.y; o.z += p*v.z; o.w += p*v.w;
  }
  *(float4*)(outp + ((size_t)(b*NLAT + r0 + r))*DIMD + h*32 + d0) = o;
}

// Fused heads: blockIdx.y==0 -> behavior decoder attn+proj; ==1 -> spike logits.
// Disjoint output ranges (out[0..31] vs out[32..]), independent inputs.
__global__ void k_heads(const float* __restrict__ qb, const float* __restrict__ kv,
                        const float* __restrict__ wo, const float* __restrict__ lat,
                        const float* __restrict__ spw, const float* __restrict__ spb,
                        float* __restrict__ outp){
  int b = blockIdx.x;
  int t = threadIdx.x;
  if (blockIdx.y == 1){
    __shared__ float m[256];
    float s = 0.f;
    for (int l = 0; l < NLAT; l++) s += lat[((size_t)(b*NLAT + l))*DIMD + t];
    m[t] = s*(1.0f/NLAT);
    __syncthreads();
    if (t < 64){
      float o = spb[t];
      for (int c = 0; c < 256; c++) o += m[c]*spw[c*64 + t];
      outp[32 + b*64 + t] = o;
    }
    return;
  }
  __shared__ float S[16][65];
  __shared__ float O2[2][256];
  __shared__ float red[256];
  const float scale = 0.1767766952966369f;
#pragma unroll
  for (int i = 0; i < 4; i++){
    int idx = t + i*256;
    int row = idx >> 6, c = idx & 63;
    int iq = row >> 3, h = row & 7;
    const float* qp = qb + iq*DIMD + h*32;
    const float* kp = kv + ((size_t)(b*NLAT + c))*512 + h*32;
    float s = 0.f;
#pragma unroll
    for (int d = 0; d < 32; d++) s += qp[d]*kp[d];
    S[row][c] = s*scale;
  }
  __syncthreads();
  if (t < 16){
    float mx = -1e30f;
    for (int c = 0; c < 64; c++) mx = fmaxf(mx, S[t][c]);
    float sum = 0.f;
    for (int c = 0; c < 64; c++){ float p = expf(S[t][c] - mx); S[t][c] = p; sum += p; }
    float inv = 1.0f/sum;
    for (int c = 0; c < 64; c++) S[t][c] *= inv;
  }
  __syncthreads();
#pragma unroll
  for (int i = 0; i < 2; i++){
    int idx = t + i*256;
    int iq = idx >> 8, c2 = idx & 255;
    int h = c2 >> 5, d = c2 & 31;
    float o = 0.f;
    for (int c = 0; c < 64; c++)
      o += S[iq*8 + h][c]*kv[((size_t)(b*NLAT + c))*512 + 256 + h*32 + d];
    O2[iq][c2] = o;
  }
  __syncthreads();
  for (int iq = 0; iq < 2; iq++){
    red[t] = O2[iq][t]*wo[t];
    __syncthreads();
    for (int off = 128; off > 0; off >>= 1){
      if (t < off) red[t] += red[t + off];
      __syncthreads();
    }
    if (t == 0) outp[b*2 + iq] = red[0];
    __syncthreads();
  }
}

extern "C" void kernel_launch(void* const* d_in, const int* in_sizes, int n_in,
                              void* d_out, int out_size, void* d_ws, size_t ws_size,
                              hipStream_t stream){
  const int* nid      = (const int*)d_in[0];
  const int* tbin     = (const int*)d_in[1];
  const int* vval     = (const int*)d_in[2];
  const int* bidx     = (const int*)d_in[3];
  const float* ne     = (const float*)d_in[6];
  const float* te     = (const float*)d_in[7];
  const float* ve     = (const float*)d_in[8];
  const float* lat_i  = (const float*)d_in[9];
  const float* Wq_c   = (const float*)d_in[10];
  const float* Wkv_c  = (const float*)d_in[11];
  const float* Wo_c   = (const float*)d_in[12];
  const float* W1_c   = (const float*)d_in[13];
  const float* W2_c   = (const float*)d_in[14];
  const float* Wqkv_s = (const float*)d_in[15];
  const float* Wo_s   = (const float*)d_in[16];
  const float* W1_s   = (const float*)d_in[17];
  const float* W2_s   = (const float*)d_in[18];
  const float* bh_query = (const float*)d_in[19];
  const float* bh_wq    = (const float*)d_in[20];
  const float* bh_wkv   = (const float*)d_in[21];
  const float* bh_wo    = (const float*)d_in[22];
  const float* bh_ln_w  = (const float*)d_in[23];
  const float* bh_ln_b  = (const float*)d_in[24];
  const float* sp_w     = (const float*)d_in[25];
  const float* sp_b     = (const float*)d_in[26];
  float* out = (float*)d_out;
  int E = in_sizes[0];
  (void)n_in; (void)out_size;

  const size_t MBf = (size_t)1 << 20;
  size_t per_gb = (size_t)18*MBf;
  size_t fixed  = (size_t)31*MBf;
  int gb = 1;
  if      (fixed + 16*per_gb <= ws_size) gb = 16;
  else if (fixed +  8*per_gb <= ws_size) gb = 8;
  else if (fixed +  4*per_gb <= ws_size) gb = 4;
  else if (fixed +  2*per_gb <= ws_size) gb = 2;

  char* wsb = (char*)d_ws;
  size_t o = 0;
  auto alloc = [&](size_t bytes)->char*{
    char* p = wsb + o; o = (o + bytes + 255) & ~(size_t)255; return p;
  };
  int*   cnt    = (int*)  alloc((size_t)NB*4);
  int*   sorted = (int*)  alloc((size_t)NB*EMAXC*4);
  float* tq     = (float*)alloc((size_t)64*256*4);
  float* qc     = (float*)alloc((size_t)64*256*4);
  float* qb     = (float*)alloc((size_t)2*256*4);
  u16*   Wt     = (u16*)  alloc((size_t)768*256*2);
  f16t*  WT     = (f16t*) alloc((size_t)WT_TOTAL*2);
  u16*   XLN    = (u16*)  alloc((size_t)gb*EMAXC*256*2);
  u8*    PT     = (u8*)   alloc((size_t)gb*512*EPAD);
  u8*    VT     = (u8*)   alloc((size_t)gb*256*EPAD);
  float* pnum   = (float*)alloc((size_t)NB*NHH*NCH2*2048*4);
  float* pden   = (float*)alloc((size_t)NB*NHH*NCH2*64*4);
  float* OC     = (float*)alloc((size_t)NB*64*256*4);
  float* lat    = (float*)alloc((size_t)NB*64*256*4);
  float* qkv    = (float*)alloc((size_t)NB*64*768*4);
  float* ffh    = (float*)alloc((size_t)NB*64*1024*4);

  // ---- prep ----
  k_zero<<<1, 64, 0, stream>>>(cnt);
  k_sort<<<(E + 1023)/1024, 256, 0, stream>>>(bidx, cnt, sorted, E);
  k_ln<<<16, 256, 0, stream>>>(lat_i, tq, 64);
  k_gemm<<<dim3(8,1), 256, 0, stream>>>(tq, Wq_c, qc, 64, 256, 256);
  k_qw<<<768, 256, 0, stream>>>(Wkv_c, qc, Wt);
  k_gemm<<<dim3(1,1), 256, 0, stream>>>(bh_query, bh_wq, qb, 2, 256, 256);
  k_wt<<<dim3(64,12), 256, 0, stream>>>(Wo_c, W1_c, W2_c, Wqkv_s, Wo_s, W1_s,
                                        W2_s, bh_wkv, WT);

  // ---- event cross-attention, runtime-sized batch groups ----
  for (int b0 = 0; b0 < NB; b0 += gb){
    k_a0<<<dim3(EMAXC/4, gb), 256, 0, stream>>>(sorted, cnt, nid, tbin, vval,
                                                ne, te, ve, XLN, b0);
    k_a<<<dim3(48, 14, gb), 256, 0, stream>>>(XLN, Wt, cnt, PT, VT, b0);
    k_b<<<dim3(NCH2, NHH, gb), 256, 0, stream>>>(PT, VT, cnt, pnum, pden, b0);
  }
  k_red<<<1024, 256, 0, stream>>>(pnum, pden, OC);

  // ---- latent chain (f16 MFMA GEMMs; LN fused as prologue where K=256) ----
  const int M = NB*NLAT;  // 1024
  k_init<<<M, 256, 0, stream>>>(lat_i, lat);
  k_gemm3<<<dim3(16,4,4), 256, 0, stream>>>(OC, WT + WTO_WOC, lat, nullptr, nullptr,
                                            M, 256, 256, 2, 0);
  k_gemm3<<<dim3(16,16,1), 256, 0, stream>>>(lat, WT + WTO_W1C, ffh, nullptr, nullptr,
                                             M, 256, 1024, 1, 1);
  k_gemm3<<<dim3(16,4,4), 256, 0, stream>>>(ffh, WT + WTO_W2C, lat, nullptr, nullptr,
                                            M, 1024, 256, 2, 0);

  for (int i = 0; i < 2; i++){
    k_gemm3<<<dim3(16,12,1), 256, 0, stream>>>(lat, WT + (i ? WTO_QKV1 : WTO_QKV0), qkv,
                                               nullptr, nullptr, M, 256, 768, 0, 1);
    k_attn<<<dim3(NB, NHH, 2), 256, 0, stream>>>(qkv, ffh);
    k_gemm3<<<dim3(16,4,4), 256, 0, stream>>>(ffh, WT + (i ? WTO_WOS1 : WTO_WOS0), lat,
                                              nullptr, nullptr, M, 256, 256, 2, 0);
    k_gemm3<<<dim3(16,16,1), 256, 0, stream>>>(lat, WT + (i ? WTO_W1S1 : WTO_W1S0), ffh,
                                               nullptr, nullptr, M, 256, 1024, 1, 1);
    k_gemm3<<<dim3(16,4,4), 256, 0, stream>>>(ffh, WT + (i ? WTO_W2S1 : WTO_W2S0), lat,
                                              nullptr, nullptr, M, 1024, 256, 2, 0);
  }

  // ---- heads ----
  k_gemm3<<<dim3(16,8,1), 256, 0, stream>>>(lat, WT + WTO_BH, qkv, bh_ln_w, bh_ln_b,
                                            M, 256, 512, 0, 1);
  k_heads<<<dim3(NB, 2), 256, 0, stream>>>(qb, qkv, bh_wo, lat, sp_w, sp_b, out);
}

// Round 15
// 501.609 us; speedup vs baseline: 1.1477x; 1.0416x over previous
//
#include <hip/hip_runtime.h>
#include <math.h>

#define NB 16
#define DIMD 256
#define NHH 8
#define NLAT 64
#define EMAXC 13568
#define NCH2 14            /* chunks of 1024 events (last partial) */
#define EPAD (NCH2*1024)   /* 14336: padded event stride (bytes for fp8 PT/VT) */

typedef float f32x4 __attribute__((ext_vector_type(4)));
typedef __bf16 bf16x8 __attribute__((ext_vector_type(8)));
typedef _Float16 f16t;
typedef __attribute__((ext_vector_type(8))) _Float16 f16x8;
typedef unsigned short u16;
typedef unsigned char u8;
typedef unsigned int u32;
typedef __attribute__((ext_vector_type(4))) unsigned int u32x4;
typedef __attribute__((ext_vector_type(8))) unsigned short u16x8;
typedef __attribute__((ext_vector_type(2))) long longx2;

/* f16 transposed-weight pool offsets (elements), layout [N][K] */
#define WTO_WOC   0u
#define WTO_W1C   65536u
#define WTO_W2C   327680u
#define WTO_QKV0  589824u
#define WTO_WOS0  786432u
#define WTO_W1S0  851968u
#define WTO_W2S0  1114112u
#define WTO_QKV1  1376256u
#define WTO_WOS1  1572864u
#define WTO_W1S1  1638400u
#define WTO_W2S1  1900544u
#define WTO_BH    2162688u
#define WT_TOTAL  2293760u

static __device__ __forceinline__ float wave_sum(float v){
#pragma unroll
  for (int off = 32; off > 0; off >>= 1) v += __shfl_xor(v, off, 64);
  return v;
}

static __device__ __forceinline__ u16 f2bf(float x){
  unsigned u = __float_as_uint(x);
  u += 0x7fffu + ((u >> 16) & 1u);
  return (u16)(u >> 16);
}

static __device__ __forceinline__ float gelu_tanh(float x){
  float x3 = x*x*x;
  return 0.5f*x*(1.0f + tanhf(0.7978845608028654f*(x + 0.044715f*x3)));
}

static __device__ __forceinline__ float dot4(float4 a, float4 b){
  return a.x*b.x + a.y*b.y + a.z*b.z + a.w*b.w;
}

// Async global->LDS DMA, 16B per lane. LDS dest is wave-uniform base + lane*16.
static __device__ __forceinline__ void gl_lds16(const void* g, void* l){
  __builtin_amdgcn_global_load_lds((const __attribute__((address_space(1))) void*)g,
                                   (__attribute__((address_space(3))) void*)l,
                                   16, 0, 0);
}

// LDS-histogram bucket sort: 16 global atomics per 1024-event block.
__global__ void k_sort(const int* __restrict__ bidx, int* __restrict__ cnt,
                       int* __restrict__ sorted, int E){
  __shared__ int h[NB], base[NB];
  int t = threadIdx.x;
  if (t < NB) h[t] = 0;
  __syncthreads();
  int e0 = blockIdx.x*1024;
  int myb[4], myp[4];
#pragma unroll
  for (int i = 0; i < 4; i++){
    int e = e0 + i*256 + t;
    myb[i] = -1;
    if (e < E){ myb[i] = bidx[e]; myp[i] = atomicAdd(&h[myb[i]], 1); }
  }
  __syncthreads();
  if (t < NB) base[t] = atomicAdd(&cnt[t], h[t]);
  __syncthreads();
#pragma unroll
  for (int i = 0; i < 4; i++){
    if (myb[i] >= 0){
      int p = base[myb[i]] + myp[i];
      if (p < EMAXC) sorted[myb[i]*EMAXC + p] = e0 + i*256 + t;
    }
  }
}

// LayerNorm over rows of 256 (lat_init prep). Block 0 also zeroes cnt
// (r15: k_zero launch folded in; k_ln runs first in the stream).
__global__ void k_ln(const float* __restrict__ X, float* __restrict__ Y, int rows,
                     int* __restrict__ cnt){
  if (blockIdx.x == 0 && (int)threadIdx.x < NB) cnt[threadIdx.x] = 0;
  int wave = threadIdx.x >> 6, lane = threadIdx.x & 63;
  int row = blockIdx.x*4 + wave;
  if (row >= rows) return;
  float4 x = ((const float4*)(X + (size_t)row*DIMD))[lane];
  float s = wave_sum(x.x + x.y + x.z + x.w);
  float m = s * (1.0f/DIMD);
  float d0 = x.x-m, d1 = x.y-m, d2 = x.z-m, d3 = x.w-m;
  float v = wave_sum(d0*d0 + d1*d1 + d2*d2 + d3*d3) * (1.0f/DIMD);
  float rs = rsqrtf(v + 1e-5f);
  ((float4*)(Y + (size_t)row*DIMD))[lane] = make_float4(d0*rs, d1*rs, d2*rs, d3*rs);
}

// Small prep GEMM (tiny M): C[M,N] = A[M,K] @ W[K,N]
__global__ __launch_bounds__(256) void k_gemm(
    const float* __restrict__ A, const float* __restrict__ W,
    float* __restrict__ C, int M, int K, int N){
  __shared__ float As[8][1024];
  int t = threadIdx.x;
  int row0 = blockIdx.x*8;
  int col = blockIdx.y*256 + t;
  int kq = K >> 2;
  for (int idx = t; idx < 8*kq; idx += 256){
    int r = idx / kq, kc = idx % kq;
    float4 v = make_float4(0.f,0.f,0.f,0.f);
    if (row0 + r < M) v = ((const float4*)(A + (size_t)(row0+r)*K))[kc];
    ((float4*)&As[r][0])[kc] = v;
  }
  __syncthreads();
  float acc[8] = {0,0,0,0,0,0,0,0};
  for (int k = 0; k < K; k += 4){
    float w0 = W[(size_t)(k+0)*N + col];
    float w1 = W[(size_t)(k+1)*N + col];
    float w2 = W[(size_t)(k+2)*N + col];
    float w3 = W[(size_t)(k+3)*N + col];
#pragma unroll
    for (int r = 0; r < 8; r++){
      float4 a = *((const float4*)&As[r][k]);
      acc[r] += a.x*w0 + a.y*w1 + a.z*w2 + a.w*w3;
    }
  }
#pragma unroll
  for (int r = 0; r < 8; r++){
    int row = row0 + r;
    if (row < M) C[(size_t)row*N + col] = acc[r];
  }
}

// Transpose all latent-chain weights to f16 [N][K] pool (runs once per launch).
// 64x64 LDS-tile transpose; grid (64, 12); out-of-range tiles return.
__global__ __launch_bounds__(256) void k_wt(
    const float* __restrict__ Wo_c, const float* __restrict__ W1_c,
    const float* __restrict__ W2_c, const float* __restrict__ Wqkv_s,
    const float* __restrict__ Wo_s, const float* __restrict__ W1_s,
    const float* __restrict__ W2_s, const float* __restrict__ bh_wkv,
    f16t* __restrict__ WT){
  const int mid = blockIdx.y;
  const float* src; int K, N; unsigned off;
  switch (mid){
    case 0:  src = Wo_c;            K = 256;  N = 256;  off = WTO_WOC;  break;
    case 1:  src = W1_c;            K = 256;  N = 1024; off = WTO_W1C;  break;
    case 2:  src = W2_c;            K = 1024; N = 256;  off = WTO_W2C;  break;
    case 3:  src = Wqkv_s;          K = 256;  N = 768;  off = WTO_QKV0; break;
    case 4:  src = Wo_s;            K = 256;  N = 256;  off = WTO_WOS0; break;
    case 5:  src = W1_s;            K = 256;  N = 1024; off = WTO_W1S0; break;
    case 6:  src = W2_s;            K = 1024; N = 256;  off = WTO_W2S0; break;
    case 7:  src = Wqkv_s + 196608; K = 256;  N = 768;  off = WTO_QKV1; break;
    case 8:  src = Wo_s + 65536;    K = 256;  N = 256;  off = WTO_WOS1; break;
    case 9:  src = W1_s + 262144;   K = 256;  N = 1024; off = WTO_W1S1; break;
    case 10: src = W2_s + 262144;   K = 1024; N = 256;  off = WTO_W2S1; break;
    default: src = bh_wkv;          K = 256;  N = 512;  off = WTO_BH;   break;
  }
  const int ntiles = N >> 6;
  const int tiles = ntiles * (K >> 6);
  if ((int)blockIdx.x >= tiles) return;
  const int kt = blockIdx.x / ntiles, nt = blockIdx.x % ntiles;
  __shared__ float tile[64][65];
  const int t = threadIdx.x;
  const int k0 = kt*64, n0 = nt*64;
#pragma unroll
  for (int i = 0; i < 16; i++){
    int k = i*4 + (t >> 6);
    tile[k][t & 63] = src[(size_t)(k0 + k)*N + n0 + (t & 63)];
  }
  __syncthreads();
  const int n = t >> 2, ks = (t & 3)*16;
  f16t* d = WT + off + (size_t)(n0 + n)*K + k0 + ks;
#pragma unroll
  for (int j = 0; j < 16; j++) d[j] = (f16t)tile[ks + j][n];
}

// MFMA latent-chain GEMM: C[M,N] (+)= A[M,K] @ W, W given as f16 WT[N][K].
// 64x64 tile, BK=64, 4 waves. A staged f32->f16 via LDS pitch-72; B via
// global_load_lds with 8-chunk XOR swizzle kc=c'^(r&7) (involution).
// modes: 0 plain / 1 gelu / 2 atomicAdd; K split over gridDim.z.
// do_ln (K==256, S==1): LayerNorm rows of A, optional affine lnw/lnb.
__global__ __launch_bounds__(256) void k_gemm3(
    const float* __restrict__ A, const f16t* __restrict__ WT, float* __restrict__ C,
    const float* __restrict__ lnw, const float* __restrict__ lnb,
    int M, int K, int N, int mode, int do_ln){
  __shared__ f16t Xs[64][72];
  __shared__ f16t Ws[64][64];
  __shared__ float lnm[64], lnr[64];
  const int t = threadIdx.x;
  const int wv = t >> 6, lane = t & 63;
  const int quad = lane >> 4, lane15 = lane & 15;
  const int m0 = blockIdx.x*64, n0 = blockIdx.y*64;
  const int Kc = K / gridDim.z;
  const int k0b = blockIdx.z*Kc;

  f32x4 acc[4];
#pragma unroll
  for (int j = 0; j < 4; j++) acc[j] = (f32x4){0.f,0.f,0.f,0.f};

  if (do_ln){
    int r = t >> 2, seg = (t & 3)*64;
    const float* Ar = A + (size_t)(m0 + r)*K + seg;
    float s = 0.f, s2 = 0.f;
#pragma unroll
    for (int j = 0; j < 64; j += 4){
      float4 v = *(const float4*)(Ar + j);
      s  += v.x + v.y + v.z + v.w;
      s2 += v.x*v.x + v.y*v.y + v.z*v.z + v.w*v.w;
    }
    s += __shfl_xor(s, 1, 64); s2 += __shfl_xor(s2, 1, 64);
    s += __shfl_xor(s, 2, 64); s2 += __shfl_xor(s2, 2, 64);
    if ((t & 3) == 0){
      float m = s*(1.0f/256.0f);
      float var = s2*(1.0f/256.0f) - m*m;
      lnm[r] = m; lnr[r] = rsqrtf(var + 1e-5f);
    }
    __syncthreads();
  }

  const int ar = t >> 2;                        // A stage row (0..63)
  const int as16 = (t & 3)*16;                  // A stage k-offset (16 f16)
  f16t* wdst0 = &Ws[0][0] + (size_t)(wv*64)*8;          // p=0 wave base
  f16t* wdst1 = &Ws[0][0] + (size_t)(256 + wv*64)*8;    // p=1 wave base

  for (int k0 = k0b; k0 < k0b + Kc; k0 += 64){
    __syncthreads();                  // prior frag reads done; buffers free
#pragma unroll
    for (int p = 0; p < 2; p++){
      int li = p*256 + t;
      int r = li >> 3;
      int kc = (li & 7) ^ (r & 7);
      gl_lds16(WT + (size_t)(n0 + r)*K + k0 + kc*8, p ? wdst1 : wdst0);
    }
    const float* Arow = A + (size_t)(m0 + ar)*K + k0 + as16;
    float4 v0 = *(const float4*)(Arow + 0);
    float4 v1 = *(const float4*)(Arow + 4);
    float4 v2 = *(const float4*)(Arow + 8);
    float4 v3 = *(const float4*)(Arow + 12);
    if (do_ln){
      float mm = lnm[ar], rs = lnr[ar];
      v0.x=(v0.x-mm)*rs; v0.y=(v0.y-mm)*rs; v0.z=(v0.z-mm)*rs; v0.w=(v0.w-mm)*rs;
      v1.x=(v1.x-mm)*rs; v1.y=(v1.y-mm)*rs; v1.z=(v1.z-mm)*rs; v1.w=(v1.w-mm)*rs;
      v2.x=(v2.x-mm)*rs; v2.y=(v2.y-mm)*rs; v2.z=(v2.z-mm)*rs; v2.w=(v2.w-mm)*rs;
      v3.x=(v3.x-mm)*rs; v3.y=(v3.y-mm)*rs; v3.z=(v3.z-mm)*rs; v3.w=(v3.w-mm)*rs;
      if (lnw){
        int k = k0 + as16;
        v0.x=v0.x*lnw[k+0]+lnb[k+0];  v0.y=v0.y*lnw[k+1]+lnb[k+1];
        v0.z=v0.z*lnw[k+2]+lnb[k+2];  v0.w=v0.w*lnw[k+3]+lnb[k+3];
        v1.x=v1.x*lnw[k+4]+lnb[k+4];  v1.y=v1.y*lnw[k+5]+lnb[k+5];
        v1.z=v1.z*lnw[k+6]+lnb[k+6];  v1.w=v1.w*lnw[k+7]+lnb[k+7];
        v2.x=v2.x*lnw[k+8]+lnb[k+8];  v2.y=v2.y*lnw[k+9]+lnb[k+9];
        v2.z=v2.z*lnw[k+10]+lnb[k+10]; v2.w=v2.w*lnw[k+11]+lnb[k+11];
        v3.x=v3.x*lnw[k+12]+lnb[k+12]; v3.y=v3.y*lnw[k+13]+lnb[k+13];
        v3.z=v3.z*lnw[k+14]+lnb[k+14]; v3.w=v3.w*lnw[k+15]+lnb[k+15];
      }
    }
    f16x8 h0 = {(f16t)v0.x,(f16t)v0.y,(f16t)v0.z,(f16t)v0.w,
                (f16t)v1.x,(f16t)v1.y,(f16t)v1.z,(f16t)v1.w};
    f16x8 h1 = {(f16t)v2.x,(f16t)v2.y,(f16t)v2.z,(f16t)v2.w,
                (f16t)v3.x,(f16t)v3.y,(f16t)v3.z,(f16t)v3.w};
    *(f16x8*)&Xs[ar][as16]     = h0;
    *(f16x8*)&Xs[ar][as16 + 8] = h1;
    __syncthreads();                  // drains vmcnt (DMA) + lgkm (ds_write)
#pragma unroll
    for (int ks = 0; ks < 2; ks++){
      f16x8 a = *(const f16x8*)&Xs[wv*16 + lane15][ks*32 + quad*8];
#pragma unroll
      for (int nt = 0; nt < 4; nt++){
        int ch = (ks*4 + quad) ^ (lane15 & 7);
        f16x8 bw = *(const f16x8*)&Ws[nt*16 + lane15][ch*8];
        acc[nt] = __builtin_amdgcn_mfma_f32_16x16x32_f16(a, bw, acc[nt], 0, 0, 0);
      }
    }
  }
#pragma unroll
  for (int nt = 0; nt < 4; nt++){
    int col = n0 + nt*16 + lane15;
#pragma unroll
    for (int j = 0; j < 4; j++){
      int row = m0 + wv*16 + quad*4 + j;
      float v = acc[nt][j];
      if (mode == 1) v = gelu_tanh(v);
      float* cp = C + (size_t)row*N + col;
      if (mode == 2) atomicAdd(cp, v);
      else *cp = v;
    }
  }
}

// Build Wt[768][256] bf16 (transposed, column-reordered). Blocks 768/769
// additionally compute qb = bh_query @ bh_wq (r15: k_gemm(qb) launch folded
// in; coalesced 1KB row reads of bh_wq per k-iteration). grid 770.
__global__ void k_qw(const float* __restrict__ Wkv, const float* __restrict__ qc,
                     const float* __restrict__ bhq, const float* __restrict__ bhwq,
                     float* __restrict__ qb, u16* __restrict__ Wt){
  int n = blockIdx.x;
  int k = threadIdx.x;
  if (n >= 768){
    int iq = n - 768;
    const float* qrow = bhq + iq*DIMD;
    float s = 0.f;
    for (int d = 0; d < 256; d++) s += qrow[d]*bhwq[(size_t)d*256 + k];
    qb[iq*DIMD + k] = s;
    return;
  }
  float v;
  if (n < 256){
    v = Wkv[(size_t)k*512 + 256 + n];
  } else {
    int h = (n - 256) >> 6, l = (n - 256) & 63;
    const float* wk = Wkv + (size_t)k*512 + h*32;
    const float* qr = qc + (size_t)l*256 + h*32;
    float s = 0.f;
#pragma unroll
    for (int dd = 0; dd < 32; dd++) s += wk[dd]*qr[dd];
    v = s*0.1767766952966369f;
  }
  Wt[(size_t)n*256 + k] = f2bf(v);
}

// Gather+LN -> XLN bf16 (group-local), zero pad rows. One wave per event row.
__global__ void k_a0(const int* __restrict__ sorted, const int* __restrict__ cnt,
                     const int* __restrict__ nid, const int* __restrict__ tbin,
                     const int* __restrict__ vval,
                     const float* __restrict__ ne, const float* __restrict__ te,
                     const float* __restrict__ ve, u16* __restrict__ XLN, int b0){
  int wv = threadIdx.x >> 6, lane = threadIdx.x & 63;
  int e = blockIdx.x*4 + wv;
  int bg = blockIdx.y, b = b0 + bg;
  int cn = min(cnt[b], EMAXC);
  ushort4 pk; pk.x = 0; pk.y = 0; pk.z = 0; pk.w = 0;
  if (e < cn){
    int ev = sorted[b*EMAXC + e];
    float4 aa = ((const float4*)(ne + (size_t)nid[ev]*DIMD))[lane];
    float4 bb = ((const float4*)(te + (size_t)tbin[ev]*DIMD))[lane];
    float4 cc = ((const float4*)(ve + (size_t)vval[ev]*DIMD))[lane];
    float x0 = aa.x+bb.x+cc.x, x1 = aa.y+bb.y+cc.y;
    float x2 = aa.z+bb.z+cc.z, x3 = aa.w+bb.w+cc.w;
    float s = wave_sum(x0 + x1 + x2 + x3);
    float m = s*(1.0f/DIMD);
    x0 -= m; x1 -= m; x2 -= m; x3 -= m;
    float v = wave_sum(x0*x0 + x1*x1 + x2*x2 + x3*x3)*(1.0f/DIMD);
    float rs = rsqrtf(v + 1e-5f);
    pk.x = f2bf(x0*rs); pk.y = f2bf(x1*rs); pk.z = f2bf(x2*rs); pk.w = f2bf(x3*rs);
  }
  *(ushort4*)(XLN + ((size_t)bg*EMAXC + e)*DIMD + lane*4) = pk;
}

// Dense MFMA GEMM: [PT|VT] (transposed, fp8 e4m3) = exp?(XLN @ Wt^T).
// 128x128 tile, BK=32, THREE-buffer (X and W both) global_load_lds pipeline
// with counted vmcnt (T3/T4): joint X+W stage (4 ops), vmcnt(8) retires
// exactly stage(it) with stage(it+1), stage(it+2) in flight (r14-verified;
// r13's split X3/W2 ladder retired X(it+2) early -> reverted).
// Chunk XOR-swizzle (r4-verified, conflict-free). NO setprio (r6: -8.7%).
// GRID LAYOUT IS LOAD-BEARING (r10): nidx=x>>3, rtile=y*8+(x&7) keeps the 6
// column-tile blocks sharing an X row-panel at blockIdx stride 8 = XCD
// round-robin period -> same per-XCD L2. Flat grid cost 6x FETCH (r10).
// LDS 48KB -> 3 blocks/CU. grid (48, 14, gb).
__global__ __launch_bounds__(256) void k_a(
    const u16* __restrict__ XLN, const u16* __restrict__ Wt,
    const int* __restrict__ cnt, u8* __restrict__ PT, u8* __restrict__ VT, int b0)
{
  __shared__ union ShMem {
    struct { u16 Xs[3][128][32]; u16 Ws[3][128][32]; } s;
    u8 Tr[128][136];
  } sh;
  const int t = threadIdx.x;
  const int wv = t >> 6, lane = t & 63;
  const int quad = lane >> 4, lane15 = lane & 15;
  const int nidx = blockIdx.x >> 3;
  const int rtile = blockIdx.y*8 + (blockIdx.x & 7);
  if (nidx >= 6 || rtile >= EMAXC/128) return;
  const int bg = blockIdx.z;
  const int b = b0 + bg;
  const int cn = min(cnt[b], EMAXC);
  const int row0 = rtile * 128;
  if (row0 >= cn) return;
  const int n0 = nidx * 128;
  const int eh = (wv >> 1) * 64, nh = (wv & 1) * 64;

  f32x4 acc[4][4];
#pragma unroll
  for (int i = 0; i < 4; i++)
#pragma unroll
    for (int j = 0; j < 4; j++) acc[i][j] = (f32x4){0.f,0.f,0.f,0.f};

  const u16* Xbase = XLN + ((size_t)bg*EMAXC + row0)*DIMD;
  const u16* Wbase = Wt + (size_t)n0*256;

  auto stage = [&](int buf, int k0){
#pragma unroll
    for (int p = 0; p < 2; p++){
      int li = p*256 + wv*64 + lane;
      int r = li >> 2;
      int kc = (li & 3) ^ ((r >> 1) & 3);
      u16* xd = &sh.s.Xs[buf][0][0] + (size_t)(p*256 + wv*64)*8;
      u16* wd = &sh.s.Ws[buf][0][0] + (size_t)(p*256 + wv*64)*8;
      gl_lds16(Xbase + (size_t)r*DIMD + k0 + kc*8, xd);
      gl_lds16(Wbase + (size_t)r*256  + k0 + kc*8, wd);
    }
  };
  const int cswz = quad ^ ((lane15 >> 1) & 3);   // read-side chunk swizzle
  auto compute = [&](int buf){
    bf16x8 a[4], bw[4];
#pragma unroll
    for (int mt = 0; mt < 4; mt++)
      a[mt] = *(const bf16x8*)&sh.s.Xs[buf][eh + mt*16 + lane15][cswz*8];
#pragma unroll
    for (int nt = 0; nt < 4; nt++)
      bw[nt] = *(const bf16x8*)&sh.s.Ws[buf][nh + nt*16 + lane15][cswz*8];
#pragma unroll
    for (int mt = 0; mt < 4; mt++)
#pragma unroll
      for (int nt = 0; nt < 4; nt++)
        acc[mt][nt] = __builtin_amdgcn_mfma_f32_16x16x32_bf16(a[mt], bw[nt], acc[mt][nt], 0, 0, 0);
  };

  stage(0, 0);
  stage(1, 32);
#pragma unroll
  for (int it = 0; it < 8; it++){
    __builtin_amdgcn_s_barrier();              // A: compute(it-1) done; buf (it+2)%3 free
    if (it + 2 < 8) stage((it + 2) % 3, (it + 2)*32);
    if (it <= 5)      asm volatile("s_waitcnt vmcnt(8)" ::: "memory");
    else if (it == 6) asm volatile("s_waitcnt vmcnt(4)" ::: "memory");
    else              asm volatile("s_waitcnt vmcnt(0)" ::: "memory");
    __builtin_amdgcn_s_barrier();              // B: everyone's stage(it) landed
    __builtin_amdgcn_sched_barrier(0);
    compute(it % 3);
  }
  const int is_p = (n0 >= 256);
  __syncthreads();   // buffers dead from here; Tr takes over the storage
#pragma unroll
  for (int mt = 0; mt < 4; mt++){
    int e0 = eh + mt*16 + quad*4;
#pragma unroll
    for (int nt = 0; nt < 4; nt++){
      int c = nh + nt*16 + lane15;
      f32x4 v = acc[mt][nt];
      if (is_p){ v.x = __expf(v.x); v.y = __expf(v.y); v.z = __expf(v.z); v.w = __expf(v.w); }
      int p01 = __builtin_amdgcn_cvt_pk_fp8_f32(v.x, v.y, 0, false);
      int p23 = __builtin_amdgcn_cvt_pk_fp8_f32(v.z, v.w, 0, false);
      unsigned pk = ((unsigned)p01 & 0xFFFFu) | ((unsigned)p23 << 16);
      *(unsigned*)&sh.Tr[c][e0] = pk;
    }
  }
  __syncthreads();
  u8* dst = is_p ? (PT + ((size_t)bg*512 + (n0 - 256))*EPAD)
                 : (VT + ((size_t)bg*256 + n0)*EPAD);
  const int chalf = lane >> 5;
  const int e4 = (lane & 31) * 4;
#pragma unroll
  for (int i = 0; i < 16; i++){
    int c = wv*32 + i*2 + chalf;
    unsigned val = *(const unsigned*)&sh.Tr[c][e4];
    *(unsigned*)(dst + (size_t)c*EPAD + row0 + e4) = val;
  }
}

// PV reduction (fp8 MFMA): O^T[dh][l] = sum_e V[dh][e]*P[l][e]; den via ones-MFMA.
// grid (NCH2, 8, gb), 256 thr; each wave owns a 256-event K-slice.
// 16B-per-lane loads (longx2, r13: -25us): PV/den are event-order-invariant,
// so the lo/hi 8B halves feed two MFMA K-blocks; halves VMEM instruction
// count. Tail mask on P only. No main-loop barriers: phase-diverse waves ->
// s_setprio around MFMA (T5).
__global__ __launch_bounds__(256) void k_b(
    const u8* __restrict__ PT, const u8* __restrict__ VT,
    const int* __restrict__ cnt, float* __restrict__ pnum, float* __restrict__ pden, int b0)
{
  __shared__ float red[4][2048];
  __shared__ float redd[4][64];
  const int t = threadIdx.x;
  const int wv = t >> 6, lane = t & 63;
  const int quad = lane >> 4, lane15 = lane & 15;
  const int chunk = blockIdx.x, h = blockIdx.y, bg = blockIdx.z;
  const int b = b0 + bg;
  const int cn = min(cnt[b], EMAXC);
  const u8* PTg = PT + ((size_t)bg*512 + h*64)*EPAD;
  const u8* VTg = VT + ((size_t)bg*256 + h*32)*EPAD;

  f32x4 acc[3][4];
#pragma unroll
  for (int i = 0; i < 3; i++)
#pragma unroll
    for (int j = 0; j < 4; j++) acc[i][j] = (f32x4){0.f,0.f,0.f,0.f};

  const long ones = 0x3838383838383838L;

  const int e0w = chunk*1024 + wv*256;
#pragma unroll
  for (int ks = 0; ks < 4; ks++){
    int eb = e0w + ks*64 + quad*16;
    longx2 a0 = *(const longx2*)(VTg + (size_t)(lane15     )*EPAD + eb);
    longx2 a1 = *(const longx2*)(VTg + (size_t)(16 + lane15)*EPAD + eb);
    longx2 bp[4];
#pragma unroll
    for (int nt = 0; nt < 4; nt++){
      union { longx2 v; u8 c[16]; } m;
      m.v = *(const longx2*)(PTg + (size_t)(nt*16 + lane15)*EPAD + eb);
      if (eb + 16 > cn){
#pragma unroll
        for (int j = 0; j < 16; j++) if (eb + j >= cn) m.c[j] = 0;
      }
      bp[nt] = m.v;
    }
    __builtin_amdgcn_s_setprio(1);
#pragma unroll
    for (int nt = 0; nt < 4; nt++){
      acc[0][nt] = __builtin_amdgcn_mfma_f32_16x16x32_fp8_fp8(a0[0], bp[nt][0], acc[0][nt], 0, 0, 0);
      acc[1][nt] = __builtin_amdgcn_mfma_f32_16x16x32_fp8_fp8(a1[0], bp[nt][0], acc[1][nt], 0, 0, 0);
      acc[2][nt] = __builtin_amdgcn_mfma_f32_16x16x32_fp8_fp8(ones,  bp[nt][0], acc[2][nt], 0, 0, 0);
    }
#pragma unroll
    for (int nt = 0; nt < 4; nt++){
      acc[0][nt] = __builtin_amdgcn_mfma_f32_16x16x32_fp8_fp8(a0[1], bp[nt][1], acc[0][nt], 0, 0, 0);
      acc[1][nt] = __builtin_amdgcn_mfma_f32_16x16x32_fp8_fp8(a1[1], bp[nt][1], acc[1][nt], 0, 0, 0);
      acc[2][nt] = __builtin_amdgcn_mfma_f32_16x16x32_fp8_fp8(ones,  bp[nt][1], acc[2][nt], 0, 0, 0);
    }
    __builtin_amdgcn_s_setprio(0);
  }
#pragma unroll
  for (int mt = 0; mt < 2; mt++)
#pragma unroll
    for (int nt = 0; nt < 4; nt++){
      int l = nt*16 + lane15;
#pragma unroll
      for (int j = 0; j < 4; j++)
        red[wv][l*32 + mt*16 + quad*4 + j] = acc[mt][nt][j];
    }
  if (quad == 0){
#pragma unroll
    for (int nt = 0; nt < 4; nt++) redd[wv][nt*16 + lane15] = acc[2][nt][0];
  }
  __syncthreads();
  size_t obase = ((size_t)(b*NHH + h)*NCH2 + chunk);
  for (int i = t; i < 2048; i += 256)
    pnum[obase*2048 + i] = red[0][i] + red[1][i] + red[2][i] + red[3][i];
  if (t < 64)
    pden[obase*64 + t] = redd[0][t] + redd[1][t] + redd[2][t] + redd[3][t];
}

// Reduce partials over chunks, divide, write OC[b][l][h*32+dh]. Also performs
// the lat row-broadcast init (r15: k_init launch folded in; same 262144-elem
// index space, lat[g] = lat_i[g mod 16384]).
__global__ void k_red(const float* __restrict__ pnum, const float* __restrict__ pden,
                      float* __restrict__ OC,
                      const float* __restrict__ lat_i, float* __restrict__ lat){
  int g = blockIdx.x*256 + threadIdx.x;
  lat[g] = lat_i[g & 16383];
  int b = g >> 14, r = g & 16383;
  int h = r >> 11, idx = r & 2047;
  int l = idx >> 5, dh = idx & 31;
  float ns = 0.f, ds = 0.f;
  for (int c = 0; c < NCH2; c++){
    size_t ob = ((size_t)(b*NHH + h)*NCH2 + c);
    ns += pnum[ob*2048 + idx];
    ds += pden[ob*64 + l];
  }
  OC[((size_t)(b*NLAT + l))*DIMD + h*32 + dh] = ns/ds;
}

// Self-attention over 64 latents. grid (NB, NHH, 2): z halves the Q rows so
// 256 blocks cover all CUs. float4 loads; S via register-blocked dot4 with
// broadcast LDS reads; wave-parallel softmax (8 lanes/row, shfl_xor 1/2/4);
// PV float4 over V rows.
__global__ __launch_bounds__(256) void k_attn(const float* __restrict__ qkv,
                                              float* __restrict__ outp){
  int b = blockIdx.x, h = blockIdx.y;
  int r0 = blockIdx.z*32;
  __shared__ float qs[32][33], ks[64][33], vs[64][33];
  __shared__ float S[32][65];
  int t = threadIdx.x;
  {
    int l = t >> 3, d4 = (t & 7)*4;     // qs: 32 rows x 8 float4
    const float* qp = qkv + ((size_t)(b*NLAT + r0 + l))*768 + h*32 + d4;
    *(float4*)&qs[l][d4] = *(const float4*)qp;
  }
#pragma unroll
  for (int i = 0; i < 2; i++){
    int idx = i*256 + t;
    int l = idx >> 3, d4 = (idx & 7)*4; // ks/vs: 64 rows x 8 float4
    const float* kp = qkv + ((size_t)(b*NLAT + l))*768 + h*32 + 256 + d4;
    *(float4*)&ks[l][d4] = *(const float4*)kp;
    *(float4*)&vs[l][d4] = *(const float4*)(kp + 256);
  }
  __syncthreads();
  const float scale = 0.1767766952966369f;
  const int r = t >> 3, g8 = t & 7;
  float4 q0 = *(const float4*)&qs[r][0],  q1 = *(const float4*)&qs[r][4],
         q2 = *(const float4*)&qs[r][8],  q3 = *(const float4*)&qs[r][12],
         q4 = *(const float4*)&qs[r][16], q5 = *(const float4*)&qs[r][20],
         q6 = *(const float4*)&qs[r][24], q7 = *(const float4*)&qs[r][28];
  float sv[8];
#pragma unroll
  for (int j = 0; j < 8; j++){
    const float* kr = &ks[g8*8 + j][0];
    float s = dot4(q0, *(const float4*)(kr+0))  + dot4(q1, *(const float4*)(kr+4))
            + dot4(q2, *(const float4*)(kr+8))  + dot4(q3, *(const float4*)(kr+12))
            + dot4(q4, *(const float4*)(kr+16)) + dot4(q5, *(const float4*)(kr+20))
            + dot4(q6, *(const float4*)(kr+24)) + dot4(q7, *(const float4*)(kr+28));
    sv[j] = s*scale;
  }
  float mx = sv[0];
#pragma unroll
  for (int j = 1; j < 8; j++) mx = fmaxf(mx, sv[j]);
  mx = fmaxf(mx, __shfl_xor(mx, 1, 64));
  mx = fmaxf(mx, __shfl_xor(mx, 2, 64));
  mx = fmaxf(mx, __shfl_xor(mx, 4, 64));
  float sum = 0.f;
#pragma unroll
  for (int j = 0; j < 8; j++){ sv[j] = __expf(sv[j] - mx); sum += sv[j]; }
  sum += __shfl_xor(sum, 1, 64);
  sum += __shfl_xor(sum, 2, 64);
  sum += __shfl_xor(sum, 4, 64);
  float inv = 1.0f/sum;
#pragma unroll
  for (int j = 0; j < 8; j++) S[r][g8*8 + j] = sv[j]*inv;
  __syncthreads();
  const int d0 = g8*4;
  float4 o = make_float4(0.f, 0.f, 0.f, 0.f);
  for (int c = 0; c < 64; c++){
    float p = S[r][c];
    float4 v = *(const float4*)&vs[c][d0];
    o.x += p*v.x; o.y += p*v.y; o.z += p*v.z; o.w += p*v.w;
  }
  *(float4*)(outp + ((size_t)(b*NLAT + r0 + r))*DIMD + h*32 + d0) = o;
}

// Fused heads: blockIdx.y==0 -> behavior decoder attn+proj; ==1 -> spike logits.
// Disjoint output ranges (out[0..31] vs out[32..]), independent inputs.
__global__ void k_heads(const float* __restrict__ qb, const float* __restrict__ kv,
                        const float* __restrict__ wo, const float* __restrict__ lat,
                        const float* __restrict__ spw, const float* __restrict__ spb,
                        float* __restrict__ outp){
  int b = blockIdx.x;
  int t = threadIdx.x;
  if (blockIdx.y == 1){
    __shared__ float m[256];
    float s = 0.f;
    for (int l = 0; l < NLAT; l++) s += lat[((size_t)(b*NLAT + l))*DIMD + t];
    m[t] = s*(1.0f/NLAT);
    __syncthreads();
    if (t < 64){
      float o = spb[t];
      for (int c = 0; c < 256; c++) o += m[c]*spw[c*64 + t];
      outp[32 + b*64 + t] = o;
    }
    return;
  }
  __shared__ float S[16][65];
  __shared__ float O2[2][256];
  __shared__ float red[256];
  const float scale = 0.1767766952966369f;
#pragma unroll
  for (int i = 0; i < 4; i++){
    int idx = t + i*256;
    int row = idx >> 6, c = idx & 63;
    int iq = row >> 3, h = row & 7;
    const float* qp = qb + iq*DIMD + h*32;
    const float* kp = kv + ((size_t)(b*NLAT + c))*512 + h*32;
    float s = 0.f;
#pragma unroll
    for (int d = 0; d < 32; d++) s += qp[d]*kp[d];
    S[row][c] = s*scale;
  }
  __syncthreads();
  if (t < 16){
    float mx = -1e30f;
    for (int c = 0; c < 64; c++) mx = fmaxf(mx, S[t][c]);
    float sum = 0.f;
    for (int c = 0; c < 64; c++){ float p = expf(S[t][c] - mx); S[t][c] = p; sum += p; }
    float inv = 1.0f/sum;
    for (int c = 0; c < 64; c++) S[t][c] *= inv;
  }
  __syncthreads();
#pragma unroll
  for (int i = 0; i < 2; i++){
    int idx = t + i*256;
    int iq = idx >> 8, c2 = idx & 255;
    int h = c2 >> 5, d = c2 & 31;
    float o = 0.f;
    for (int c = 0; c < 64; c++)
      o += S[iq*8 + h][c]*kv[((size_t)(b*NLAT + c))*512 + 256 + h*32 + d];
    O2[iq][c2] = o;
  }
  __syncthreads();
  for (int iq = 0; iq < 2; iq++){
    red[t] = O2[iq][t]*wo[t];
    __syncthreads();
    for (int off = 128; off > 0; off >>= 1){
      if (t < off) red[t] += red[t + off];
      __syncthreads();
    }
    if (t == 0) outp[b*2 + iq] = red[0];
    __syncthreads();
  }
}

extern "C" void kernel_launch(void* const* d_in, const int* in_sizes, int n_in,
                              void* d_out, int out_size, void* d_ws, size_t ws_size,
                              hipStream_t stream){
  const int* nid      = (const int*)d_in[0];
  const int* tbin     = (const int*)d_in[1];
  const int* vval     = (const int*)d_in[2];
  const int* bidx     = (const int*)d_in[3];
  const float* ne     = (const float*)d_in[6];
  const float* te     = (const float*)d_in[7];
  const float* ve     = (const float*)d_in[8];
  const float* lat_i  = (const float*)d_in[9];
  const float* Wq_c   = (const float*)d_in[10];
  const float* Wkv_c  = (const float*)d_in[11];
  const float* Wo_c   = (const float*)d_in[12];
  const float* W1_c   = (const float*)d_in[13];
  const float* W2_c   = (const float*)d_in[14];
  const float* Wqkv_s = (const float*)d_in[15];
  const float* Wo_s   = (const float*)d_in[16];
  const float* W1_s   = (const float*)d_in[17];
  const float* W2_s   = (const float*)d_in[18];
  const float* bh_query = (const float*)d_in[19];
  const float* bh_wq    = (const float*)d_in[20];
  const float* bh_wkv   = (const float*)d_in[21];
  const float* bh_wo    = (const float*)d_in[22];
  const float* bh_ln_w  = (const float*)d_in[23];
  const float* bh_ln_b  = (const float*)d_in[24];
  const float* sp_w     = (const float*)d_in[25];
  const float* sp_b     = (const float*)d_in[26];
  float* out = (float*)d_out;
  int E = in_sizes[0];
  (void)n_in; (void)out_size;

  const size_t MBf = (size_t)1 << 20;
  size_t per_gb = (size_t)18*MBf;
  size_t fixed  = (size_t)31*MBf;
  int gb = 1;
  if      (fixed + 16*per_gb <= ws_size) gb = 16;
  else if (fixed +  8*per_gb <= ws_size) gb = 8;
  else if (fixed +  4*per_gb <= ws_size) gb = 4;
  else if (fixed +  2*per_gb <= ws_size) gb = 2;

  char* wsb = (char*)d_ws;
  size_t o = 0;
  auto alloc = [&](size_t bytes)->char*{
    char* p = wsb + o; o = (o + bytes + 255) & ~(size_t)255; return p;
  };
  int*   cnt    = (int*)  alloc((size_t)NB*4);
  int*   sorted = (int*)  alloc((size_t)NB*EMAXC*4);
  float* tq     = (float*)alloc((size_t)64*256*4);
  float* qc     = (float*)alloc((size_t)64*256*4);
  float* qb     = (float*)alloc((size_t)2*256*4);
  u16*   Wt     = (u16*)  alloc((size_t)768*256*2);
  f16t*  WT     = (f16t*) alloc((size_t)WT_TOTAL*2);
  u16*   XLN    = (u16*)  alloc((size_t)gb*EMAXC*256*2);
  u8*    PT     = (u8*)   alloc((size_t)gb*512*EPAD);
  u8*    VT     = (u8*)   alloc((size_t)gb*256*EPAD);
  float* pnum   = (float*)alloc((size_t)NB*NHH*NCH2*2048*4);
  float* pden   = (float*)alloc((size_t)NB*NHH*NCH2*64*4);
  float* OC     = (float*)alloc((size_t)NB*64*256*4);
  float* lat    = (float*)alloc((size_t)NB*64*256*4);
  float* qkv    = (float*)alloc((size_t)NB*64*768*4);
  float* ffh    = (float*)alloc((size_t)NB*64*1024*4);

  // ---- prep (r15: k_zero folded into k_ln; qb GEMM folded into k_qw) ----
  k_ln<<<16, 256, 0, stream>>>(lat_i, tq, 64, cnt);
  k_sort<<<(E + 1023)/1024, 256, 0, stream>>>(bidx, cnt, sorted, E);
  k_gemm<<<dim3(8,1), 256, 0, stream>>>(tq, Wq_c, qc, 64, 256, 256);
  k_qw<<<770, 256, 0, stream>>>(Wkv_c, qc, bh_query, bh_wq, qb, Wt);
  k_wt<<<dim3(64,12), 256, 0, stream>>>(Wo_c, W1_c, W2_c, Wqkv_s, Wo_s, W1_s,
                                        W2_s, bh_wkv, WT);

  // ---- event cross-attention, runtime-sized batch groups ----
  for (int b0 = 0; b0 < NB; b0 += gb){
    k_a0<<<dim3(EMAXC/4, gb), 256, 0, stream>>>(sorted, cnt, nid, tbin, vval,
                                                ne, te, ve, XLN, b0);
    k_a<<<dim3(48, 14, gb), 256, 0, stream>>>(XLN, Wt, cnt, PT, VT, b0);
    k_b<<<dim3(NCH2, NHH, gb), 256, 0, stream>>>(PT, VT, cnt, pnum, pden, b0);
  }
  k_red<<<1024, 256, 0, stream>>>(pnum, pden, OC, lat_i, lat);  // + lat init

  // ---- latent chain (f16 MFMA GEMMs; LN fused as prologue where K=256) ----
  const int M = NB*NLAT;  // 1024
  k_gemm3<<<dim3(16,4,4), 256, 0, stream>>>(OC, WT + WTO_WOC, lat, nullptr, nullptr,
                                            M, 256, 256, 2, 0);
  k_gemm3<<<dim3(16,16,1), 256, 0, stream>>>(lat, WT + WTO_W1C, ffh, nullptr, nullptr,
                                             M, 256, 1024, 1, 1);
  k_gemm3<<<dim3(16,4,4), 256, 0, stream>>>(ffh, WT + WTO_W2C, lat, nullptr, nullptr,
                                            M, 1024, 256, 2, 0);

  for (int i = 0; i < 2; i++){
    k_gemm3<<<dim3(16,12,1), 256, 0, stream>>>(lat, WT + (i ? WTO_QKV1 : WTO_QKV0), qkv,
                                               nullptr, nullptr, M, 256, 768, 0, 1);
    k_attn<<<dim3(NB, NHH, 2), 256, 0, stream>>>(qkv, ffh);
    k_gemm3<<<dim3(16,4,4), 256, 0, stream>>>(ffh, WT + (i ? WTO_WOS1 : WTO_WOS0), lat,
                                              nullptr, nullptr, M, 256, 256, 2, 0);
    k_gemm3<<<dim3(16,16,1), 256, 0, stream>>>(lat, WT + (i ? WTO_W1S1 : WTO_W1S0), ffh,
                                               nullptr, nullptr, M, 256, 1024, 1, 1);
    k_gemm3<<<dim3(16,4,4), 256, 0, stream>>>(ffh, WT + (i ? WTO_W2S1 : WTO_W2S0), lat,
                                              nullptr, nullptr, M, 1024, 256, 2, 0);
  }

  // ---- heads ----
  k_gemm3<<<dim3(16,8,1), 256, 0, stream>>>(lat, WT + WTO_BH, qkv, bh_ln_w, bh_ln_b,
                                            M, 256, 512, 0, 1);
  k_heads<<<dim3(NB, 2), 256, 0, stream>>>(qb, qkv, bh_wo, lat, sp_w, sp_b, out);
}